// Round 8
// baseline (498.993 us; speedup 1.0000x reference)
//
#include <hip/hip_runtime.h>
#include <hip/hip_bf16.h>

#define QW 64
#define KW 128
#define PADW 32
#define DEPTH 3
#define HEADS 4
#define B_ 2
#define N_ 8192
#define DS 128
#define DP 16
#define DT 384
#define NT 1024
#define NWIN (N_ / QW)   // 128
#define DH (DS / HEADS)  // 32

typedef unsigned short u16;
typedef __attribute__((ext_vector_type(8))) short short8;
typedef __attribute__((ext_vector_type(4))) float f32x4v;
typedef __attribute__((ext_vector_type(4))) unsigned short us4;

__device__ __forceinline__ u16 f2b(float x) {
    union { float f; unsigned u; } v; v.f = x;
    unsigned r = v.u + 0x7fffu + ((v.u >> 16) & 1u);
    return (u16)(r >> 16);
}
__device__ __forceinline__ float b2f(u16 h) {
    union { unsigned u; float f; } v; v.u = ((unsigned)h) << 16; return v.f;
}
__device__ __forceinline__ unsigned f2b2(float a, float b) {
    __hip_bfloat162 h = __float22bfloat162_rn(make_float2(a, b));
    union { __hip_bfloat162 h; unsigned u; } c; c.h = h; return c.u;
}
__device__ __forceinline__ us4 pack4(float a, float b, float c, float d) {
    union { us4 v; unsigned u[2]; } o;
    o.u[0] = f2b2(a, b);
    o.u[1] = f2b2(c, d);
    return o.v;
}

// ---------------------------------------------------------------------------
// Weight prep (unchanged).
// ---------------------------------------------------------------------------
__global__ __launch_bounds__(256) void convw_kernel(
    const float* __restrict__ Wq, const float* __restrict__ Wk,
    const float* __restrict__ Wv, const float* __restrict__ Wo,
    const float* __restrict__ Wff1, const float* __restrict__ Wff2,
    const float* __restrict__ Wout, const float* __restrict__ Wpff1,
    const float* __restrict__ Wpff2, const float* __restrict__ Wb,
    const float* __restrict__ Wsingle, const float* __restrict__ Wouter,
    u16* __restrict__ qkvT, u16* __restrict__ woT, u16* __restrict__ ff1T,
    u16* __restrict__ ff2T, u16* __restrict__ woutT,
    u16* __restrict__ w1T32, u16* __restrict__ wcatT,
    u16* __restrict__ wsT, u16* __restrict__ woutrT)
{
    int idx = blockIdx.x * 256 + threadIdx.x;
    if (idx < 3 * 384 * 128) {
        int l = idx / (384 * 128), r = idx % (384 * 128);
        int n = r / 128, k = r % 128;
        const float* W = (n < 128) ? Wq : (n < 256) ? Wk : Wv;
        qkvT[idx] = f2b(W[(size_t)l * 16384 + k * 128 + (n & 127)]);
    }
    if (idx < 3 * 128 * 128) {
        int l = idx / 16384, r = idx % 16384;
        int n = r / 128, k = r % 128;
        woT[idx] = f2b(Wo[(size_t)l * 16384 + k * 128 + n]);
    }
    if (idx < 3 * 512 * 128) {
        int l = idx / 65536, r = idx % 65536;
        int n = r / 128, k = r % 128;
        ff1T[idx] = f2b(Wff1[(size_t)l * 65536 + k * 512 + n]);
    }
    if (idx < 3 * 128 * 512) {
        int l = idx / 65536, r = idx % 65536;
        int n = r / 512, k = r % 512;
        ff2T[idx] = f2b(Wff2[(size_t)l * 65536 + k * 128 + n]);
    }
    if (idx < 384 * 128) {
        int n = idx / 128, k = idx % 128;
        woutT[idx] = f2b(Wout[(size_t)k * 384 + n]);
    }
    if (idx < 64 * 32) {
        int n = idx >> 5, k = idx & 31;
        w1T32[idx] = (k < 16) ? f2b(Wpff1[k * 64 + n]) : (u16)0;
    }
    if (idx < 16 * 96) {
        int h = idx / 96, k = idx % 96;
        float s = 0.f;
        if (h < 4) {
            if (k < 16) s = Wb[k * 4 + h];
            else if (k < 80) {
                int j = k - 16;
                for (int c = 0; c < 16; ++c) s += Wpff2[j * 16 + c] * Wb[c * 4 + h];
            }
        }
        wcatT[idx] = f2b(s);
    }
    if (idx < 128 * 416) {
        int n = idx / 416, k = idx % 416;
        float v = 0.f;
        if (k < 128)       v = Wsingle[(5 + k) * 128 + n];
        else if (k < 384)  v = Wsingle[(133 + k - 128) * 128 + n];
        else if (k < 387)  v = Wsingle[(k - 384) * 128 + n];
        else if (k == 387) v = Wsingle[3 * 128 + n];
        else if (k == 388) v = Wsingle[4 * 128 + n];
        wsT[idx] = f2b(v);
    }
    if (idx < 32 * 128) {
        int n = idx >> 7, k = idx & 127;
        woutrT[idx] = f2b(Wouter[k * 32 + n]);
    }
}

// ---------------------------------------------------------------------------
// Embed GEMM + fused LN + fused P-GEMM (unchanged).
// ---------------------------------------------------------------------------
__global__ __launch_bounds__(256) void embed_gemm(
    const float* __restrict__ pos, const float* __restrict__ charge,
    const float* __restrict__ mask, const float* __restrict__ elem,
    const float* __restrict__ chars, const u16* __restrict__ wsT,
    const u16* __restrict__ woutrT,
    float* __restrict__ X, u16* __restrict__ LNb, float* __restrict__ P)
{
    __shared__ __align__(16) u16 As[64 * 424];
    __shared__ float redS[64][4];
    int tid = threadIdx.x;
    int row0 = blockIdx.x * 64;

    #pragma unroll
    for (int it = 0; it < 8; ++it) {
        int idx = tid + it * 256;
        int r = idx >> 5, c4 = idx & 31;
        f32x4v v = *(const f32x4v*)(elem + (size_t)(row0 + r) * 128 + c4 * 4);
        *(us4*)&As[r * 424 + c4 * 4] = pack4(v[0], v[1], v[2], v[3]);
    }
    #pragma unroll
    for (int it = 0; it < 16; ++it) {
        int idx = tid + it * 256;
        int r = idx >> 6, c4 = idx & 63;
        f32x4v v = *(const f32x4v*)(chars + (size_t)(row0 + r) * 256 + c4 * 4);
        *(us4*)&As[r * 424 + 128 + c4 * 4] = pack4(v[0], v[1], v[2], v[3]);
    }
    if (tid < 64) {
        int g = row0 + tid;
        As[tid * 424 + 384] = f2b(pos[g * 3]);
        As[tid * 424 + 385] = f2b(pos[g * 3 + 1]);
        As[tid * 424 + 386] = f2b(pos[g * 3 + 2]);
        As[tid * 424 + 387] = f2b(charge[g]);
        As[tid * 424 + 388] = f2b(mask[g]);
        for (int c = 389; c < 416; ++c) As[tid * 424 + c] = 0;
    }
    __syncthreads();

    int wv = tid >> 6, lane = tid & 63, quad = lane >> 4, l16 = lane & 15;
    int wm = (wv & 1) * 32, wn = (wv >> 1) * 64;
    f32x4v acc[2][4];
    #pragma unroll
    for (int i = 0; i < 2; ++i)
        #pragma unroll
        for (int j = 0; j < 4; ++j) acc[i][j] = (f32x4v){0.f, 0.f, 0.f, 0.f};

    #pragma unroll
    for (int kk = 0; kk < 13; ++kk) {
        short8 a0 = *(short8*)&As[(wm + l16) * 424 + kk * 32 + quad * 8];
        short8 a1 = *(short8*)&As[(wm + 16 + l16) * 424 + kk * 32 + quad * 8];
        #pragma unroll
        for (int nt = 0; nt < 4; ++nt) {
            short8 bw = *(const short8*)&wsT[(size_t)(wn + nt * 16 + l16) * 416 +
                                             kk * 32 + quad * 8];
            acc[0][nt] = __builtin_amdgcn_mfma_f32_16x16x32_bf16(a0, bw, acc[0][nt], 0, 0, 0);
            acc[1][nt] = __builtin_amdgcn_mfma_f32_16x16x32_bf16(a1, bw, acc[1][nt], 0, 0, 0);
        }
    }
    __syncthreads();

    #pragma unroll
    for (int mt = 0; mt < 2; ++mt) {
        #pragma unroll
        for (int r = 0; r < 4; ++r) {
            int lrow = wm + mt * 16 + quad * 4 + r;
            int row = row0 + lrow;
            float s = 0.f, ss = 0.f;
            #pragma unroll
            for (int nt = 0; nt < 4; ++nt) {
                float v = acc[mt][nt][r];
                int col = wn + nt * 16 + l16;
                X[(size_t)row * DS + col] = v;
                As[lrow * 136 + col] = f2b(fmaxf(v, 0.f));
                s += v; ss += v * v;
            }
            #pragma unroll
            for (int o = 1; o < 16; o <<= 1) {
                s  += __shfl_xor(s, o);
                ss += __shfl_xor(ss, o);
            }
            if (l16 == 0) {
                redS[lrow][(wv >> 1) * 2]     = s;
                redS[lrow][(wv >> 1) * 2 + 1] = ss;
            }
        }
    }
    __syncthreads();

    #pragma unroll
    for (int mt = 0; mt < 2; ++mt)
        #pragma unroll
        for (int r = 0; r < 4; ++r) {
            int lrow = wm + mt * 16 + quad * 4 + r;
            int row = row0 + lrow;
            f32x4v rv = *(f32x4v*)&redS[lrow][0];
            float s = rv[0] + rv[2], ss = rv[1] + rv[3];
            float m = s * (1.f / 128.f);
            float var = ss * (1.f / 128.f) - m * m;
            float rs = rsqrtf(var + 1e-5f);
            #pragma unroll
            for (int nt = 0; nt < 4; ++nt) {
                int col = wn + nt * 16 + l16;
                LNb[(size_t)row * DS + col] = f2b((acc[mt][nt][r] - m) * rs);
            }
        }

    {
        f32x4v pacc[2];
        pacc[0] = (f32x4v){0.f, 0.f, 0.f, 0.f};
        pacc[1] = (f32x4v){0.f, 0.f, 0.f, 0.f};
        #pragma unroll
        for (int ks = 0; ks < 4; ++ks) {
            short8 a = *(short8*)&As[(wv * 16 + l16) * 136 + ks * 32 + quad * 8];
            #pragma unroll
            for (int nt = 0; nt < 2; ++nt) {
                short8 bw = *(const short8*)&woutrT[(size_t)(nt * 16 + l16) * 128 +
                                                    ks * 32 + quad * 8];
                pacc[nt] = __builtin_amdgcn_mfma_f32_16x16x32_bf16(a, bw, pacc[nt], 0, 0, 0);
            }
        }
        #pragma unroll
        for (int nt = 0; nt < 2; ++nt)
            #pragma unroll
            for (int r = 0; r < 4; ++r) {
                int row = row0 + wv * 16 + quad * 4 + r;
                P[(size_t)row * 32 + nt * 16 + l16] = pacc[nt][r];
            }
    }
}

// ---------------------------------------------------------------------------
// Bias kernel (unchanged from round 7).
// ---------------------------------------------------------------------------
__global__ __launch_bounds__(256) void bias_kernel(
    const float* __restrict__ pos, const int* __restrict__ uid,
    const float* __restrict__ P, const float* __restrict__ Wpair,
    const u16* __restrict__ w1T32, const u16* __restrict__ wcatT,
    u16* __restrict__ BIASb)
{
    __shared__ __align__(16) float pjS[128][20];
    __shared__ __align__(16) float posjS[128][4];
    __shared__ __align__(16) u16 lpS[4][16 * 24];
    __shared__ __align__(16) u16 A2S[4][16 * 104];

    int tid = threadIdx.x;
    int b  = blockIdx.x >> 11;
    int w  = (blockIdx.x >> 4) & 127;
    int qg = blockIdx.x & 15;

    {
        int r = tid >> 1, half = tid & 1;
        int jk = w * QW + r - PADW;
        bool valid = (jk >= 0) && (jk < N_);
        int gk = b * N_ + jk;
        f32x4v z = (f32x4v){0.f, 0.f, 0.f, 0.f};
        f32x4v v0 = z, v1 = z;
        if (valid) {
            v0 = *(const f32x4v*)(P + (size_t)gk * 32 + 16 + half * 8);
            v1 = *(const f32x4v*)(P + (size_t)gk * 32 + 20 + half * 8);
        }
        *(f32x4v*)&pjS[r][half * 8]     = v0;
        *(f32x4v*)&pjS[r][half * 8 + 4] = v1;
        if (half == 0) {
            float x = 0.f, y = 0.f, zz = 0.f; int u = 0;
            if (valid) { x = pos[gk * 3]; y = pos[gk * 3 + 1]; zz = pos[gk * 3 + 2]; u = uid[gk]; }
            posjS[r][0] = x; posjS[r][1] = y; posjS[r][2] = zz;
            ((int*)posjS[r])[3] = u;
        }
    }

    int wv = tid >> 6, lane = tid & 63, quad = lane >> 4, l16 = lane & 15;
    int cl = lane >> 2, cg = lane & 3;
    int q = qg * 4 + wv;
    int gq = b * N_ + w * QW + q;

    float xi = pos[gq * 3], yi = pos[gq * 3 + 1], zi = pos[gq * 3 + 2];
    int ui = uid[gq];
    f32x4v pi4 = *(const f32x4v*)(P + (size_t)gq * 32 + cg * 4);
    f32x4v wp[5];
    #pragma unroll
    for (int f = 0; f < 5; ++f)
        wp[f] = *(const f32x4v*)(Wpair + f * 16 + cg * 4);
    short8 w1f[4], wcat[3];
    #pragma unroll
    for (int nt = 0; nt < 4; ++nt)
        w1f[nt] = *(const short8*)&w1T32[(nt * 16 + l16) * 32 + quad * 8];
    #pragma unroll
    for (int ks = 0; ks < 3; ++ks)
        wcat[ks] = *(const short8*)&wcatT[l16 * 96 + ks * 32 + quad * 8];
    *(us4*)&A2S[wv][l16 * 104 + 80 + quad * 4] = (us4){0, 0, 0, 0};
    __syncthreads();

    size_t bbase = ((size_t)(b * NWIN + w) * HEADS) * (QW * KW);
    const short8 zero8 = (short8){0, 0, 0, 0, 0, 0, 0, 0};

    for (int t = 0; t < 8; ++t) {
        int kk1 = t * 16 + cl;
        f32x4v pjv = *(f32x4v*)&pjS[kk1][cg * 4];
        float xj = posjS[kk1][0], yj = posjS[kk1][1], zj = posjS[kk1][2];
        int uj = ((int*)posjS[kk1])[3];
        float dx = xi - xj, dy = yi - yj, dz = zi - zj;
        float inv = 1.f / (1.f + dx * dx + dy * dy + dz * dz);
        float bf = (ui == uj) ? 1.f : 0.f;
        float pr[4];
        #pragma unroll
        for (int j = 0; j < 4; ++j) {
            float s = fmaf(dx, wp[0][j], fmaf(dy, wp[1][j],
                      fmaf(dz, wp[2][j], fmaf(inv, wp[3][j], wp[4][j]))));
            pr[j] = fmaf(bf, s, pi4[j] + pjv[j]);
        }
        float sum = pr[0] + pr[1] + pr[2] + pr[3];
        sum += __shfl_xor(sum, 1); sum += __shfl_xor(sum, 2);
        float m = sum * (1.f / 16.f);
        float d0 = pr[0] - m, d1 = pr[1] - m, d2 = pr[2] - m, d3 = pr[3] - m;
        float vs = d0 * d0 + d1 * d1 + d2 * d2 + d3 * d3;
        vs += __shfl_xor(vs, 1); vs += __shfl_xor(vs, 2);
        float rstd = rsqrtf(vs * (1.f / 16.f) + 1e-5f);
        *(us4*)&lpS[wv][cl * 24 + cg * 4] =
            pack4(d0 * rstd, d1 * rstd, d2 * rstd, d3 * rstd);
        *(us4*)&A2S[wv][cl * 104 + cg * 4] = pack4(pr[0], pr[1], pr[2], pr[3]);

        short8 blp = zero8;
        if (quad < 2) blp = *(short8*)&lpS[wv][l16 * 24 + quad * 8];
        #pragma unroll
        for (int nt = 0; nt < 4; ++nt) {
            f32x4v z4 = (f32x4v){0.f, 0.f, 0.f, 0.f};
            z4 = __builtin_amdgcn_mfma_f32_16x16x32_bf16(w1f[nt], blp, z4, 0, 0, 0);
            *(us4*)&A2S[wv][l16 * 104 + 16 + nt * 16 + quad * 4] =
                pack4(fmaxf(z4[0], 0.f), fmaxf(z4[1], 0.f),
                      fmaxf(z4[2], 0.f), fmaxf(z4[3], 0.f));
        }
        f32x4v acc = (f32x4v){0.f, 0.f, 0.f, 0.f};
        #pragma unroll
        for (int ks = 0; ks < 3; ++ks) {
            short8 a2 = *(short8*)&A2S[wv][l16 * 104 + ks * 32 + quad * 8];
            acc = __builtin_amdgcn_mfma_f32_16x16x32_bf16(a2, wcat[ks], acc, 0, 0, 0);
        }
        if (l16 < 4) {
            *(us4*)&BIASb[bbase + (size_t)l16 * (QW * KW) + q * KW +
                          t * 16 + quad * 4] = pack4(acc[0], acc[1], acc[2], acc[3]);
        }
    }
}

// ---------------------------------------------------------------------------
// gemm_bf32: 32-row M-tile, wave tile 16x64. Out bf16 = (relu)(A[.,128]@WT^T).
// grid = (M/32, N/128). LDS 8.5 KB -> high occupancy.
// ---------------------------------------------------------------------------
template <bool RELU>
__global__ __launch_bounds__(256) void gemm_bf32(
    const u16* __restrict__ A, const u16* __restrict__ WT,
    u16* __restrict__ OutB, int N)
{
    __shared__ __align__(16) u16 As[32 * 136];
    int tid = threadIdx.x;
    int row0 = blockIdx.x * 32, n0 = blockIdx.y * 128;

    #pragma unroll
    for (int it = 0; it < 2; ++it) {
        int idx = tid + it * 256;
        int r = idx >> 4, c8 = idx & 15;
        *(short8*)&As[r * 136 + c8 * 8] =
            *(const short8*)&A[(size_t)(row0 + r) * 128 + c8 * 8];
    }
    __syncthreads();

    int wv = tid >> 6, lane = tid & 63, quad = lane >> 4, l16 = lane & 15;
    int wm = (wv & 1) * 16, wn = (wv >> 1) * 64;
    f32x4v acc[4];
    #pragma unroll
    for (int j = 0; j < 4; ++j) acc[j] = (f32x4v){0.f, 0.f, 0.f, 0.f};

    #pragma unroll
    for (int kk = 0; kk < 4; ++kk) {
        short8 a = *(short8*)&As[(wm + l16) * 136 + kk * 32 + quad * 8];
        #pragma unroll
        for (int nt = 0; nt < 4; ++nt) {
            short8 bw = *(const short8*)&WT[(size_t)(n0 + wn + nt * 16 + l16) * 128 +
                                            kk * 32 + quad * 8];
            acc[nt] = __builtin_amdgcn_mfma_f32_16x16x32_bf16(a, bw, acc[nt], 0, 0, 0);
        }
    }
    #pragma unroll
    for (int nt = 0; nt < 4; ++nt)
        #pragma unroll
        for (int r = 0; r < 4; ++r) {
            int row = row0 + wm + quad * 4 + r;
            int col = n0 + wn + nt * 16 + l16;
            float v = acc[nt][r];
            if (RELU) v = fmaxf(v, 0.f);
            OutB[(size_t)row * N + col] = f2b(v);
        }
}

// ---------------------------------------------------------------------------
// gemm_addln32: 32-row tile; X += A@W (N=128); LNb = LN(X) bf16.
// grid = M/32. LDS ~5 KB.
// ---------------------------------------------------------------------------
__global__ __launch_bounds__(256) void gemm_addln32(
    const u16* __restrict__ A, const u16* __restrict__ WT,
    float* __restrict__ X, u16* __restrict__ LNb, int K)
{
    __shared__ __align__(16) u16 As[32 * 72];
    __shared__ float redS[32][4];
    const int row0 = blockIdx.x * 32;
    const int tid = threadIdx.x;
    const int wv = tid >> 6, lane = tid & 63, quad = lane >> 4, l16 = lane & 15;
    const int wm = (wv & 1) * 16, wn = (wv >> 1) * 64;

    f32x4v acc[4];
    #pragma unroll
    for (int j = 0; j < 4; ++j) acc[j] = (f32x4v){0.f, 0.f, 0.f, 0.f};

    for (int k0 = 0; k0 < K; k0 += 64) {
        __syncthreads();
        {
            int r = tid >> 3, c = tid & 7;
            *(short8*)&As[r * 72 + c * 8] =
                *(const short8*)&A[(size_t)(row0 + r) * K + k0 + c * 8];
        }
        __syncthreads();
        #pragma unroll
        for (int kk = 0; kk < 64; kk += 32) {
            short8 a = *(const short8*)&As[(wm + l16) * 72 + kk + quad * 8];
            #pragma unroll
            for (int nt = 0; nt < 4; ++nt) {
                short8 b = *(const short8*)&WT[(size_t)(wn + nt * 16 + l16) * K +
                                               k0 + kk + quad * 8];
                acc[nt] = __builtin_amdgcn_mfma_f32_16x16x32_bf16(a, b, acc[nt], 0, 0, 0);
            }
        }
    }

    // residual add + X store + LN partials
    #pragma unroll
    for (int r = 0; r < 4; ++r) {
        int lrow = wm + quad * 4 + r;
        int row = row0 + lrow;
        float s = 0.f, ss = 0.f;
        #pragma unroll
        for (int nt = 0; nt < 4; ++nt) {
            int col = wn + nt * 16 + l16;
            size_t o = (size_t)row * DS + col;
            float v = acc[nt][r] + X[o];
            acc[nt][r] = v;
            X[o] = v;
            s += v; ss += v * v;
        }
        #pragma unroll
        for (int o2 = 1; o2 < 16; o2 <<= 1) {
            s  += __shfl_xor(s, o2);
            ss += __shfl_xor(ss, o2);
        }
        if (l16 == 0) {
            redS[lrow][(wv >> 1) * 2]     = s;
            redS[lrow][(wv >> 1) * 2 + 1] = ss;
        }
    }
    __syncthreads();

    #pragma unroll
    for (int r = 0; r < 4; ++r) {
        int lrow = wm + quad * 4 + r;
        int row = row0 + lrow;
        f32x4v rv = *(f32x4v*)&redS[lrow][0];
        float s = rv[0] + rv[2], ss = rv[1] + rv[3];
        float m = s * (1.f / 128.f);
        float var = ss * (1.f / 128.f) - m * m;
        float rs = rsqrtf(var + 1e-5f);
        #pragma unroll
        for (int nt = 0; nt < 4; ++nt) {
            int col = wn + nt * 16 + l16;
            LNb[(size_t)row * DS + col] = f2b((acc[nt][r] - m) * rs);
        }
    }
}

// ---------------------------------------------------------------------------
// gemm_fin32: final W_out (fp32 A -> bf16 relu out), 32-row tile.
// grid = (M/32, N/128).
// ---------------------------------------------------------------------------
__global__ __launch_bounds__(256) void gemm_fin32(
    const float* __restrict__ A, const u16* __restrict__ WT,
    u16* __restrict__ OutB, int K, int N)
{
    __shared__ __align__(16) u16 As[32 * 72];
    const int row0 = blockIdx.x * 32, n0 = blockIdx.y * 128;
    const int tid = threadIdx.x;
    const int wv = tid >> 6, lane = tid & 63, quad = lane >> 4, l16 = lane & 15;
    const int wm = (wv & 1) * 16, wn = (wv >> 1) * 64;

    f32x4v acc[4];
    #pragma unroll
    for (int j = 0; j < 4; ++j) acc[j] = (f32x4v){0.f, 0.f, 0.f, 0.f};

    for (int k0 = 0; k0 < K; k0 += 64) {
        __syncthreads();
        #pragma unroll
        for (int it = 0; it < 2; ++it) {
            int idx = tid + it * 256;
            int r = idx >> 4, c = idx & 15;
            f32x4v v = *(const f32x4v*)(A + (size_t)(row0 + r) * K + k0 + c * 4);
            *(us4*)&As[r * 72 + c * 4] = pack4(v[0], v[1], v[2], v[3]);
        }
        __syncthreads();
        #pragma unroll
        for (int kk = 0; kk < 64; kk += 32) {
            short8 a = *(const short8*)&As[(wm + l16) * 72 + kk + quad * 8];
            #pragma unroll
            for (int nt = 0; nt < 4; ++nt) {
                short8 b = *(const short8*)&WT[(size_t)(n0 + wn + nt * 16 + l16) * K + k0 + kk + quad * 8];
                acc[nt] = __builtin_amdgcn_mfma_f32_16x16x32_bf16(a, b, acc[nt], 0, 0, 0);
            }
        }
    }
    #pragma unroll
    for (int nt = 0; nt < 4; ++nt)
        #pragma unroll
        for (int r = 0; r < 4; ++r) {
            int row = row0 + wm + quad * 4 + r;
            int col = n0 + wn + nt * 16 + l16;
            OutB[(size_t)row * N + col] = f2b(fmaxf(acc[nt][r], 0.f));
        }
}

// ---------------------------------------------------------------------------
// Windowed attention (unchanged).
// ---------------------------------------------------------------------------
__global__ __launch_bounds__(256) void attn_kernel(
    const u16* __restrict__ QKV, const u16* __restrict__ BIASb,
    u16* __restrict__ O)
{
    __shared__ __align__(16) u16 sQ[64 * 40];
    __shared__ __align__(16) u16 sK[128 * 40];
    __shared__ __align__(16) u16 sVt[32 * 152];
    __shared__ __align__(16) u16 sP[64 * 136];
    __shared__ float pmax[4][64];
    __shared__ float psum[4][64];
    __shared__ float gfac[4][64];

    int tid = threadIdx.x;
    int h = blockIdx.x & 3, w = (blockIdx.x >> 2) & 127, b = blockIdx.x >> 9;
    size_t rowbase = (size_t)b * N_ + w * QW;
    const short8 zero8 = (short8){0, 0, 0, 0, 0, 0, 0, 0};

    {
        int r = tid >> 2, d8 = (tid & 3) * 8;
        *(short8*)&sQ[r * 40 + d8] =
            *(const short8*)&QKV[(rowbase + r) * 384 + h * DH + d8];
    }
    #pragma unroll
    for (int i = 0; i < 2; ++i) {
        int idx = tid + i * 256;
        int r = idx >> 2, d8 = (idx & 3) * 8;
        int jk = w * QW + r - PADW;
        short8 v = zero8;
        if (jk >= 0 && jk < N_)
            v = *(const short8*)&QKV[((size_t)b * N_ + jk) * 384 + 128 + h * DH + d8];
        *(short8*)&sK[r * 40 + d8] = v;
    }
    {
        int kk = tid >> 1, d0 = (tid & 1) * 16;
        int jk = w * QW + kk - PADW;
        short8 v0 = zero8, v1 = zero8;
        if (jk >= 0 && jk < N_) {
            const u16* src = &QKV[((size_t)b * N_ + jk) * 384 + 256 + h * DH + d0];
            v0 = *(const short8*)src;
            v1 = *(const short8*)(src + 8);
        }
        #pragma unroll
        for (int j = 0; j < 8; ++j) {
            sVt[(d0 + j) * 152 + kk] = (u16)v0[j];
            sVt[(d0 + 8 + j) * 152 + kk] = (u16)v1[j];
        }
    }
    __syncthreads();

    int wv = tid >> 6, lane = tid & 63, quad = lane >> 4, l16 = lane & 15;
    const float scale = 0.17677669529663687f;
    size_t bbase = ((size_t)(b * NWIN + w) * HEADS + h) * (QW * KW);

    short8 aq[4];
    #pragma unroll
    for (int mt = 0; mt < 4; ++mt)
        aq[mt] = *(short8*)&sQ[(mt * 16 + l16) * 40 + quad * 8];
    float e[2][4][4];
    #pragma unroll
    for (int ni = 0; ni < 2; ++ni) {
        int nt = wv * 2 + ni;
        short8 bk = *(short8*)&sK[(nt * 16 + l16) * 40 + quad * 8];
        int kk = nt * 16 + l16;
        int jk = w * QW + kk - PADW;
        float msk = (jk >= 0 && jk < N_) ? 0.f : -1e9f;
        #pragma unroll
        for (int mt = 0; mt < 4; ++mt) {
            f32x4v acc = (f32x4v){0.f, 0.f, 0.f, 0.f};
            acc = __builtin_amdgcn_mfma_f32_16x16x32_bf16(aq[mt], bk, acc, 0, 0, 0);
            #pragma unroll
            for (int r = 0; r < 4; ++r) {
                int q = mt * 16 + quad * 4 + r;
                e[ni][mt][r] = acc[r] * scale + b2f(BIASb[bbase + q * KW + kk]) + msk;
            }
        }
    }

    #pragma unroll
    for (int mt = 0; mt < 4; ++mt)
        #pragma unroll
        for (int r = 0; r < 4; ++r) {
            float m = fmaxf(e[0][mt][r], e[1][mt][r]);
            m = fmaxf(m, __shfl_xor(m, 1));
            m = fmaxf(m, __shfl_xor(m, 2));
            m = fmaxf(m, __shfl_xor(m, 4));
            m = fmaxf(m, __shfl_xor(m, 8));
            float e0 = __expf(e[0][mt][r] - m);
            float e1 = __expf(e[1][mt][r] - m);
            e[0][mt][r] = e0; e[1][mt][r] = e1;
            float s = e0 + e1;
            s += __shfl_xor(s, 1);
            s += __shfl_xor(s, 2);
            s += __shfl_xor(s, 4);
            s += __shfl_xor(s, 8);
            if (l16 == 0) {
                int q = mt * 16 + quad * 4 + r;
                pmax[wv][q] = m;
                psum[wv][q] = s;
            }
        }
    __syncthreads();

    if (tid < 64) {
        float m0 = pmax[0][tid], m1 = pmax[1][tid], m2 = pmax[2][tid], m3 = pmax[3][tid];
        float M = fmaxf(fmaxf(m0, m1), fmaxf(m2, m3));
        float g0 = __expf(m0 - M), g1 = __expf(m1 - M),
              g2 = __expf(m2 - M), g3 = __expf(m3 - M);
        float T = psum[0][tid] * g0 + psum[1][tid] * g1 +
                  psum[2][tid] * g2 + psum[3][tid] * g3;
        float inv = 1.f / T;
        gfac[0][tid] = g0 * inv; gfac[1][tid] = g1 * inv;
        gfac[2][tid] = g2 * inv; gfac[3][tid] = g3 * inv;
    }
    __syncthreads();

    #pragma unroll
    for (int mt = 0; mt < 4; ++mt)
        #pragma unroll
        for (int r = 0; r < 4; ++r) {
            int q = mt * 16 + quad * 4 + r;
            float f = gfac[wv][q];
            #pragma unroll
            for (int ni = 0; ni < 2; ++ni) {
                int kk = (wv * 2 + ni) * 16 + l16;
                sP[q * 136 + kk] = f2b(e[ni][mt][r] * f);
            }
        }
    __syncthreads();

    {
        int mt = wv;
        short8 ap[4];
        #pragma unroll
        for (int ks = 0; ks < 4; ++ks)
            ap[ks] = *(short8*)&sP[(mt * 16 + l16) * 136 + ks * 32 + quad * 8];
        #pragma unroll
        for (int nt = 0; nt < 2; ++nt) {
            f32x4v acc = (f32x4v){0.f, 0.f, 0.f, 0.f};
            #pragma unroll
            for (int ks = 0; ks < 4; ++ks) {
                short8 bv = *(short8*)&sVt[(nt * 16 + l16) * 152 + ks * 32 + quad * 8];
                acc = __builtin_amdgcn_mfma_f32_16x16x32_bf16(ap[ks], bv, acc, 0, 0, 0);
            }
            int d = nt * 16 + l16;
            #pragma unroll
            for (int r = 0; r < 4; ++r) {
                int q = mt * 16 + quad * 4 + r;
                O[(rowbase + q) * DS + h * DH + d] = f2b(acc[r]);
            }
        }
    }
}

// ---------------------------------------------------------------------------
// Segment mean (unchanged).
// ---------------------------------------------------------------------------
__global__ __launch_bounds__(128) void seg_kernel(
    const u16* __restrict__ TOKb, const int* __restrict__ idx,
    float* __restrict__ out)
{
    int t = blockIdx.x & (NT - 1);
    int b = blockIdx.x >> 10;
    const int* id = idx + (size_t)b * N_;

    int lo = 0, hi = N_;
    while (lo < hi) { int mid = (lo + hi) >> 1; if (id[mid] < t) lo = mid + 1; else hi = mid; }
    int start = lo;
    hi = N_;
    while (lo < hi) { int mid = (lo + hi) >> 1; if (id[mid] < t + 1) lo = mid + 1; else hi = mid; }
    int end = lo;

    float inv = 1.f / fmaxf((float)(end - start), 1.f);
    for (int c = threadIdx.x; c < DT; c += 128) {
        float s = 0.f;
        for (int r = start; r < end; ++r) s += b2f(TOKb[((size_t)b * N_ + r) * DT + c]);
        out[((size_t)b * NT + t) * DT + c] = s * inv;
    }
}

// ---------------------------------------------------------------------------
extern "C" void kernel_launch(void* const* d_in, const int* in_sizes, int n_in,
                              void* d_out, int out_size, void* d_ws, size_t ws_size,
                              hipStream_t stream)
{
    const float* ref_pos    = (const float*)d_in[0];
    const float* ref_charge = (const float*)d_in[1];
    const float* ref_mask   = (const float*)d_in[2];
    const float* ref_elem   = (const float*)d_in[3];
    const float* ref_chars  = (const float*)d_in[4];
    const float* W_single   = (const float*)d_in[5];
    const float* W_pair     = (const float*)d_in[6];
    const float* W_outer    = (const float*)d_in[7];
    const float* Wp_ff1     = (const float*)d_in[8];
    const float* Wp_ff2     = (const float*)d_in[9];
    const float* Wq         = (const float*)d_in[10];
    const float* Wk         = (const float*)d_in[11];
    const float* Wv         = (const float*)d_in[12];
    const float* Wo         = (const float*)d_in[13];
    const float* Wb         = (const float*)d_in[14];
    const float* Wff1       = (const float*)d_in[15];
    const float* Wff2       = (const float*)d_in[16];
    const float* W_out      = (const float*)d_in[17];
    const int*   uid        = (const int*)d_in[18];
    const int*   a2t        = (const int*)d_in[19];
    float* out = (float*)d_out;

    const size_t ROWS = (size_t)B_ * N_;  // 16384
    float* ws = (float*)d_ws;
    float* X    = ws;
    float* P    = X + ROWS * DS;
    u16* QKVb   = (u16*)(P + ROWS * 32);
    u16* Ob     = QKVb + ROWS * 384;
    u16* FFb    = Ob + ROWS * DS;
    u16* BIASb  = FFb + ROWS * 512;
    u16* TOKb   = BIASb + (size_t)B_ * NWIN * HEADS * QW * KW;
    u16* LNb    = TOKb + ROWS * DT;
    u16* qkvT   = LNb + ROWS * DS;
    u16* woT    = qkvT + 3 * 384 * 128;
    u16* ff1T   = woT + 3 * 128 * 128;
    u16* ff2T   = ff1T + 3 * 512 * 128;
    u16* woutT  = ff2T + 3 * 128 * 512;
    u16* w1T32  = woutT + 384 * 128;
    u16* wcatT  = w1T32 + 64 * 32;
    u16* wsT    = wcatT + 16 * 96;
    u16* woutrT = wsT + 128 * 416;

    convw_kernel<<<768, 256, 0, stream>>>(Wq, Wk, Wv, Wo, Wff1, Wff2, W_out,
                                          Wp_ff1, Wp_ff2, Wb, W_single, W_outer,
                                          qkvT, woT, ff1T, ff2T, woutT,
                                          w1T32, wcatT, wsT, woutrT);
    embed_gemm<<<ROWS / 64, 256, 0, stream>>>(ref_pos, ref_charge, ref_mask,
                                              ref_elem, ref_chars, wsT, woutrT,
                                              X, LNb, P);
    bias_kernel<<<4096, 256, 0, stream>>>(ref_pos, uid, P, W_pair,
                                          w1T32, wcatT, BIASb);

    for (int l = 0; l < DEPTH; ++l) {
        gemm_bf32<false><<<dim3(ROWS / 32, 3), 256, 0, stream>>>(
            LNb, qkvT + (size_t)l * 384 * 128, QKVb, 384);
        attn_kernel<<<B_ * NWIN * HEADS, 256, 0, stream>>>(QKVb, BIASb, Ob);
        gemm_addln32<<<dim3(ROWS / 32, 1), 256, 0, stream>>>(
            Ob, woT + (size_t)l * 128 * 128, X, LNb, 128);
        gemm_bf32<true><<<dim3(ROWS / 32, 4), 256, 0, stream>>>(
            LNb, ff1T + (size_t)l * 512 * 128, FFb, 512);
        gemm_addln32<<<dim3(ROWS / 32, 1), 256, 0, stream>>>(
            FFb, ff2T + (size_t)l * 128 * 512, X, LNb, 512);
    }

    gemm_fin32<<<dim3(ROWS / 32, 3), 256, 0, stream>>>(X, woutT, TOKb, DS, DT);
    seg_kernel<<<B_ * NT, 128, 0, stream>>>(TOKb, a2t, out);
}

// Round 9
// 481.882 us; speedup vs baseline: 1.0355x; 1.0355x over previous
//
#include <hip/hip_runtime.h>
#include <hip/hip_bf16.h>

#define QW 64
#define KW 128
#define PADW 32
#define DEPTH 3
#define HEADS 4
#define B_ 2
#define N_ 8192
#define DS 128
#define DP 16
#define DT 384
#define NT 1024
#define NWIN (N_ / QW)   // 128
#define DH (DS / HEADS)  // 32

typedef unsigned short u16;
typedef __attribute__((ext_vector_type(8))) short short8;
typedef __attribute__((ext_vector_type(4))) float f32x4v;
typedef __attribute__((ext_vector_type(4))) unsigned short us4;

__device__ __forceinline__ u16 f2b(float x) {
    union { float f; unsigned u; } v; v.f = x;
    unsigned r = v.u + 0x7fffu + ((v.u >> 16) & 1u);
    return (u16)(r >> 16);
}
__device__ __forceinline__ float b2f(u16 h) {
    union { unsigned u; float f; } v; v.u = ((unsigned)h) << 16; return v.f;
}
__device__ __forceinline__ unsigned f2b2(float a, float b) {
    __hip_bfloat162 h = __float22bfloat162_rn(make_float2(a, b));
    union { __hip_bfloat162 h; unsigned u; } c; c.h = h; return c.u;
}
__device__ __forceinline__ us4 pack4(float a, float b, float c, float d) {
    union { us4 v; unsigned u[2]; } o;
    o.u[0] = f2b2(a, b);
    o.u[1] = f2b2(c, d);
    return o.v;
}

// ---------------------------------------------------------------------------
// Weight prep (unchanged).
// ---------------------------------------------------------------------------
__global__ __launch_bounds__(256) void convw_kernel(
    const float* __restrict__ Wq, const float* __restrict__ Wk,
    const float* __restrict__ Wv, const float* __restrict__ Wo,
    const float* __restrict__ Wff1, const float* __restrict__ Wff2,
    const float* __restrict__ Wout, const float* __restrict__ Wpff1,
    const float* __restrict__ Wpff2, const float* __restrict__ Wb,
    const float* __restrict__ Wsingle, const float* __restrict__ Wouter,
    u16* __restrict__ qkvT, u16* __restrict__ woT, u16* __restrict__ ff1T,
    u16* __restrict__ ff2T, u16* __restrict__ woutT,
    u16* __restrict__ w1T32, u16* __restrict__ wcatT,
    u16* __restrict__ wsT, u16* __restrict__ woutrT)
{
    int idx = blockIdx.x * 256 + threadIdx.x;
    if (idx < 3 * 384 * 128) {
        int l = idx / (384 * 128), r = idx % (384 * 128);
        int n = r / 128, k = r % 128;
        const float* W = (n < 128) ? Wq : (n < 256) ? Wk : Wv;
        qkvT[idx] = f2b(W[(size_t)l * 16384 + k * 128 + (n & 127)]);
    }
    if (idx < 3 * 128 * 128) {
        int l = idx / 16384, r = idx % 16384;
        int n = r / 128, k = r % 128;
        woT[idx] = f2b(Wo[(size_t)l * 16384 + k * 128 + n]);
    }
    if (idx < 3 * 512 * 128) {
        int l = idx / 65536, r = idx % 65536;
        int n = r / 128, k = r % 128;
        ff1T[idx] = f2b(Wff1[(size_t)l * 65536 + k * 512 + n]);
    }
    if (idx < 3 * 128 * 512) {
        int l = idx / 65536, r = idx % 65536;
        int n = r / 512, k = r % 512;
        ff2T[idx] = f2b(Wff2[(size_t)l * 65536 + k * 128 + n]);
    }
    if (idx < 384 * 128) {
        int n = idx / 128, k = idx % 128;
        woutT[idx] = f2b(Wout[(size_t)k * 384 + n]);
    }
    if (idx < 64 * 32) {
        int n = idx >> 5, k = idx & 31;
        w1T32[idx] = (k < 16) ? f2b(Wpff1[k * 64 + n]) : (u16)0;
    }
    if (idx < 16 * 96) {
        int h = idx / 96, k = idx % 96;
        float s = 0.f;
        if (h < 4) {
            if (k < 16) s = Wb[k * 4 + h];
            else if (k < 80) {
                int j = k - 16;
                for (int c = 0; c < 16; ++c) s += Wpff2[j * 16 + c] * Wb[c * 4 + h];
            }
        }
        wcatT[idx] = f2b(s);
    }
    if (idx < 128 * 416) {
        int n = idx / 416, k = idx % 416;
        float v = 0.f;
        if (k < 128)       v = Wsingle[(5 + k) * 128 + n];
        else if (k < 384)  v = Wsingle[(133 + k - 128) * 128 + n];
        else if (k < 387)  v = Wsingle[(k - 384) * 128 + n];
        else if (k == 387) v = Wsingle[3 * 128 + n];
        else if (k == 388) v = Wsingle[4 * 128 + n];
        wsT[idx] = f2b(v);
    }
    if (idx < 32 * 128) {
        int n = idx >> 7, k = idx & 127;
        woutrT[idx] = f2b(Wouter[k * 32 + n]);
    }
}

// ---------------------------------------------------------------------------
// Embed GEMM + fused LN + fused P-GEMM (unchanged).
// ---------------------------------------------------------------------------
__global__ __launch_bounds__(256) void embed_gemm(
    const float* __restrict__ pos, const float* __restrict__ charge,
    const float* __restrict__ mask, const float* __restrict__ elem,
    const float* __restrict__ chars, const u16* __restrict__ wsT,
    const u16* __restrict__ woutrT,
    float* __restrict__ X, u16* __restrict__ LNb, float* __restrict__ P)
{
    __shared__ __align__(16) u16 As[64 * 424];
    __shared__ float redS[64][4];
    int tid = threadIdx.x;
    int row0 = blockIdx.x * 64;

    #pragma unroll
    for (int it = 0; it < 8; ++it) {
        int idx = tid + it * 256;
        int r = idx >> 5, c4 = idx & 31;
        f32x4v v = *(const f32x4v*)(elem + (size_t)(row0 + r) * 128 + c4 * 4);
        *(us4*)&As[r * 424 + c4 * 4] = pack4(v[0], v[1], v[2], v[3]);
    }
    #pragma unroll
    for (int it = 0; it < 16; ++it) {
        int idx = tid + it * 256;
        int r = idx >> 6, c4 = idx & 63;
        f32x4v v = *(const f32x4v*)(chars + (size_t)(row0 + r) * 256 + c4 * 4);
        *(us4*)&As[r * 424 + 128 + c4 * 4] = pack4(v[0], v[1], v[2], v[3]);
    }
    if (tid < 64) {
        int g = row0 + tid;
        As[tid * 424 + 384] = f2b(pos[g * 3]);
        As[tid * 424 + 385] = f2b(pos[g * 3 + 1]);
        As[tid * 424 + 386] = f2b(pos[g * 3 + 2]);
        As[tid * 424 + 387] = f2b(charge[g]);
        As[tid * 424 + 388] = f2b(mask[g]);
        for (int c = 389; c < 416; ++c) As[tid * 424 + c] = 0;
    }
    __syncthreads();

    int wv = tid >> 6, lane = tid & 63, quad = lane >> 4, l16 = lane & 15;
    int wm = (wv & 1) * 32, wn = (wv >> 1) * 64;
    f32x4v acc[2][4];
    #pragma unroll
    for (int i = 0; i < 2; ++i)
        #pragma unroll
        for (int j = 0; j < 4; ++j) acc[i][j] = (f32x4v){0.f, 0.f, 0.f, 0.f};

    #pragma unroll
    for (int kk = 0; kk < 13; ++kk) {
        short8 a0 = *(short8*)&As[(wm + l16) * 424 + kk * 32 + quad * 8];
        short8 a1 = *(short8*)&As[(wm + 16 + l16) * 424 + kk * 32 + quad * 8];
        #pragma unroll
        for (int nt = 0; nt < 4; ++nt) {
            short8 bw = *(const short8*)&wsT[(size_t)(wn + nt * 16 + l16) * 416 +
                                             kk * 32 + quad * 8];
            acc[0][nt] = __builtin_amdgcn_mfma_f32_16x16x32_bf16(a0, bw, acc[0][nt], 0, 0, 0);
            acc[1][nt] = __builtin_amdgcn_mfma_f32_16x16x32_bf16(a1, bw, acc[1][nt], 0, 0, 0);
        }
    }
    __syncthreads();

    #pragma unroll
    for (int mt = 0; mt < 2; ++mt) {
        #pragma unroll
        for (int r = 0; r < 4; ++r) {
            int lrow = wm + mt * 16 + quad * 4 + r;
            int row = row0 + lrow;
            float s = 0.f, ss = 0.f;
            #pragma unroll
            for (int nt = 0; nt < 4; ++nt) {
                float v = acc[mt][nt][r];
                int col = wn + nt * 16 + l16;
                X[(size_t)row * DS + col] = v;
                As[lrow * 136 + col] = f2b(fmaxf(v, 0.f));
                s += v; ss += v * v;
            }
            #pragma unroll
            for (int o = 1; o < 16; o <<= 1) {
                s  += __shfl_xor(s, o);
                ss += __shfl_xor(ss, o);
            }
            if (l16 == 0) {
                redS[lrow][(wv >> 1) * 2]     = s;
                redS[lrow][(wv >> 1) * 2 + 1] = ss;
            }
        }
    }
    __syncthreads();

    #pragma unroll
    for (int mt = 0; mt < 2; ++mt)
        #pragma unroll
        for (int r = 0; r < 4; ++r) {
            int lrow = wm + mt * 16 + quad * 4 + r;
            int row = row0 + lrow;
            f32x4v rv = *(f32x4v*)&redS[lrow][0];
            float s = rv[0] + rv[2], ss = rv[1] + rv[3];
            float m = s * (1.f / 128.f);
            float var = ss * (1.f / 128.f) - m * m;
            float rs = rsqrtf(var + 1e-5f);
            #pragma unroll
            for (int nt = 0; nt < 4; ++nt) {
                int col = wn + nt * 16 + l16;
                LNb[(size_t)row * DS + col] = f2b((acc[mt][nt][r] - m) * rs);
            }
        }

    {
        f32x4v pacc[2];
        pacc[0] = (f32x4v){0.f, 0.f, 0.f, 0.f};
        pacc[1] = (f32x4v){0.f, 0.f, 0.f, 0.f};
        #pragma unroll
        for (int ks = 0; ks < 4; ++ks) {
            short8 a = *(short8*)&As[(wv * 16 + l16) * 136 + ks * 32 + quad * 8];
            #pragma unroll
            for (int nt = 0; nt < 2; ++nt) {
                short8 bw = *(const short8*)&woutrT[(size_t)(nt * 16 + l16) * 128 +
                                                    ks * 32 + quad * 8];
                pacc[nt] = __builtin_amdgcn_mfma_f32_16x16x32_bf16(a, bw, pacc[nt], 0, 0, 0);
            }
        }
        #pragma unroll
        for (int nt = 0; nt < 2; ++nt)
            #pragma unroll
            for (int r = 0; r < 4; ++r) {
                int row = row0 + wv * 16 + quad * 4 + r;
                P[(size_t)row * 32 + nt * 16 + l16] = pacc[nt][r];
            }
    }
}

// ---------------------------------------------------------------------------
// Bias kernel v7: pjS LDS removed — 8 per-tile pj slices preloaded from
// global (independent loads, vmcnt-pipelined). posj/uid stay in LDS.
// ---------------------------------------------------------------------------
__global__ __launch_bounds__(256) void bias_kernel(
    const float* __restrict__ pos, const int* __restrict__ uid,
    const float* __restrict__ P, const float* __restrict__ Wpair,
    const u16* __restrict__ w1T32, const u16* __restrict__ wcatT,
    u16* __restrict__ BIASb)
{
    __shared__ __align__(16) float posjS[128][4];
    __shared__ __align__(16) u16 lpS[4][16 * 24];
    __shared__ __align__(16) u16 A2S[4][16 * 104];

    int tid = threadIdx.x;
    int b  = blockIdx.x >> 11;
    int w  = (blockIdx.x >> 4) & 127;
    int qg = blockIdx.x & 15;

    if (tid < 128) {
        int r = tid;
        int jk = w * QW + r - PADW;
        bool valid = (jk >= 0) && (jk < N_);
        int gk = b * N_ + jk;
        float x = 0.f, y = 0.f, zz = 0.f; int u = 0;
        if (valid) { x = pos[gk * 3]; y = pos[gk * 3 + 1]; zz = pos[gk * 3 + 2]; u = uid[gk]; }
        posjS[r][0] = x; posjS[r][1] = y; posjS[r][2] = zz;
        ((int*)posjS[r])[3] = u;
    }

    int wv = tid >> 6, lane = tid & 63, quad = lane >> 4, l16 = lane & 15;
    int cl = lane >> 2, cg = lane & 3;
    int q = qg * 4 + wv;
    int gq = b * N_ + w * QW + q;

    // i-side (wave-broadcast) + weights in registers
    float xi = pos[gq * 3], yi = pos[gq * 3 + 1], zi = pos[gq * 3 + 2];
    int ui = uid[gq];
    f32x4v pi4 = *(const f32x4v*)(P + (size_t)gq * 32 + cg * 4);
    f32x4v wp[5];
    #pragma unroll
    for (int f = 0; f < 5; ++f)
        wp[f] = *(const f32x4v*)(Wpair + f * 16 + cg * 4);
    short8 w1f[4], wcat[3];
    #pragma unroll
    for (int nt = 0; nt < 4; ++nt)
        w1f[nt] = *(const short8*)&w1T32[(nt * 16 + l16) * 32 + quad * 8];
    #pragma unroll
    for (int ks = 0; ks < 3; ++ks)
        wcat[ks] = *(const short8*)&wcatT[l16 * 96 + ks * 32 + quad * 8];

    // preload all 8 tiles' pj slices (independent global loads)
    f32x4v pjv[8];
    #pragma unroll
    for (int t = 0; t < 8; ++t) {
        int jk = w * QW + t * 16 + cl - PADW;
        bool valid = (jk >= 0) && (jk < N_);
        int gk = b * N_ + jk;
        f32x4v v = (f32x4v){0.f, 0.f, 0.f, 0.f};
        if (valid) v = *(const f32x4v*)(P + (size_t)gk * 32 + 16 + cg * 4);
        pjv[t] = v;
    }

    *(us4*)&A2S[wv][l16 * 104 + 80 + quad * 4] = (us4){0, 0, 0, 0};
    __syncthreads();

    size_t bbase = ((size_t)(b * NWIN + w) * HEADS) * (QW * KW);
    const short8 zero8 = (short8){0, 0, 0, 0, 0, 0, 0, 0};

    for (int t = 0; t < 8; ++t) {
        int kk1 = t * 16 + cl;
        float xj = posjS[kk1][0], yj = posjS[kk1][1], zj = posjS[kk1][2];
        int uj = ((int*)posjS[kk1])[3];
        float dx = xi - xj, dy = yi - yj, dz = zi - zj;
        float inv = 1.f / (1.f + dx * dx + dy * dy + dz * dz);
        float bf = (ui == uj) ? 1.f : 0.f;
        float pr[4];
        #pragma unroll
        for (int j = 0; j < 4; ++j) {
            float s = fmaf(dx, wp[0][j], fmaf(dy, wp[1][j],
                      fmaf(dz, wp[2][j], fmaf(inv, wp[3][j], wp[4][j]))));
            pr[j] = fmaf(bf, s, pi4[j] + pjv[t][j]);
        }
        float sum = pr[0] + pr[1] + pr[2] + pr[3];
        sum += __shfl_xor(sum, 1); sum += __shfl_xor(sum, 2);
        float m = sum * (1.f / 16.f);
        float d0 = pr[0] - m, d1 = pr[1] - m, d2 = pr[2] - m, d3 = pr[3] - m;
        float vs = d0 * d0 + d1 * d1 + d2 * d2 + d3 * d3;
        vs += __shfl_xor(vs, 1); vs += __shfl_xor(vs, 2);
        float rstd = rsqrtf(vs * (1.f / 16.f) + 1e-5f);
        *(us4*)&lpS[wv][cl * 24 + cg * 4] =
            pack4(d0 * rstd, d1 * rstd, d2 * rstd, d3 * rstd);
        *(us4*)&A2S[wv][cl * 104 + cg * 4] = pack4(pr[0], pr[1], pr[2], pr[3]);

        short8 blp = zero8;
        if (quad < 2) blp = *(short8*)&lpS[wv][l16 * 24 + quad * 8];
        #pragma unroll
        for (int nt = 0; nt < 4; ++nt) {
            f32x4v z4 = (f32x4v){0.f, 0.f, 0.f, 0.f};
            z4 = __builtin_amdgcn_mfma_f32_16x16x32_bf16(w1f[nt], blp, z4, 0, 0, 0);
            *(us4*)&A2S[wv][l16 * 104 + 16 + nt * 16 + quad * 4] =
                pack4(fmaxf(z4[0], 0.f), fmaxf(z4[1], 0.f),
                      fmaxf(z4[2], 0.f), fmaxf(z4[3], 0.f));
        }
        f32x4v acc = (f32x4v){0.f, 0.f, 0.f, 0.f};
        #pragma unroll
        for (int ks = 0; ks < 3; ++ks) {
            short8 a2 = *(short8*)&A2S[wv][l16 * 104 + ks * 32 + quad * 8];
            acc = __builtin_amdgcn_mfma_f32_16x16x32_bf16(a2, wcat[ks], acc, 0, 0, 0);
        }
        if (l16 < 4) {
            *(us4*)&BIASb[bbase + (size_t)l16 * (QW * KW) + q * KW +
                          t * 16 + quad * 4] = pack4(acc[0], acc[1], acc[2], acc[3]);
        }
    }
}

// ---------------------------------------------------------------------------
// Plain bf16-A GEMM (K=128), 64-row tile (round-7 version).
// ---------------------------------------------------------------------------
template <bool RELU>
__global__ __launch_bounds__(256) void gemm_bf(
    const u16* __restrict__ A, const u16* __restrict__ WT,
    u16* __restrict__ OutB, int N)
{
    __shared__ __align__(16) u16 As[64 * 136];
    int tid = threadIdx.x;
    int row0 = blockIdx.x * 64, n0 = blockIdx.y * 128;

    #pragma unroll
    for (int it = 0; it < 4; ++it) {
        int idx = tid + it * 256;
        int r = idx >> 4, c8 = idx & 15;
        *(short8*)&As[r * 136 + c8 * 8] =
            *(const short8*)&A[(size_t)(row0 + r) * 128 + c8 * 8];
    }
    __syncthreads();

    int wv = tid >> 6, lane = tid & 63, quad = lane >> 4, l16 = lane & 15;
    int wm = (wv & 1) * 32, wn = (wv >> 1) * 64;
    f32x4v acc[2][4];
    #pragma unroll
    for (int i = 0; i < 2; ++i)
        #pragma unroll
        for (int j = 0; j < 4; ++j) acc[i][j] = (f32x4v){0.f, 0.f, 0.f, 0.f};

    #pragma unroll
    for (int kk = 0; kk < 4; ++kk) {
        short8 a0 = *(short8*)&As[(wm + l16) * 136 + kk * 32 + quad * 8];
        short8 a1 = *(short8*)&As[(wm + 16 + l16) * 136 + kk * 32 + quad * 8];
        #pragma unroll
        for (int nt = 0; nt < 4; ++nt) {
            short8 bw = *(const short8*)&WT[(size_t)(n0 + wn + nt * 16 + l16) * 128 +
                                            kk * 32 + quad * 8];
            acc[0][nt] = __builtin_amdgcn_mfma_f32_16x16x32_bf16(a0, bw, acc[0][nt], 0, 0, 0);
            acc[1][nt] = __builtin_amdgcn_mfma_f32_16x16x32_bf16(a1, bw, acc[1][nt], 0, 0, 0);
        }
    }
    #pragma unroll
    for (int mt = 0; mt < 2; ++mt)
        #pragma unroll
        for (int nt = 0; nt < 4; ++nt)
            #pragma unroll
            for (int r = 0; r < 4; ++r) {
                int row = row0 + wm + mt * 16 + quad * 4 + r;
                int col = n0 + wn + nt * 16 + l16;
                float v = acc[mt][nt][r];
                if (RELU) v = fmaxf(v, 0.f);
                OutB[(size_t)row * N + col] = f2b(v);
            }
}

// ---------------------------------------------------------------------------
// bf16-A GEMM + residual ADD + fused LN (64-row, round-7 version).
// ---------------------------------------------------------------------------
__global__ __launch_bounds__(256) void gemm_addln(
    const u16* __restrict__ A, const u16* __restrict__ WT,
    float* __restrict__ X, u16* __restrict__ LNb, int K)
{
    __shared__ __align__(16) u16 As[64 * 88];
    __shared__ float redS[64][4];
    const int row0 = blockIdx.x * 64;
    const int tid = threadIdx.x;
    const int wv = tid >> 6, lane = tid & 63, quad = lane >> 4, l16 = lane & 15;
    const int wm = (wv & 1) * 32, wn = (wv >> 1) * 64;

    f32x4v acc[2][4];
    #pragma unroll
    for (int i = 0; i < 2; ++i)
        #pragma unroll
        for (int j = 0; j < 4; ++j) acc[i][j] = (f32x4v){0.f, 0.f, 0.f, 0.f};

    for (int k0 = 0; k0 < K; k0 += 64) {
        __syncthreads();
        #pragma unroll
        for (int it = 0; it < 2; ++it) {
            int idx = tid + it * 256;
            int r = idx >> 3, c = idx & 7;
            *(short8*)&As[r * 88 + c * 8] =
                *(const short8*)&A[(size_t)(row0 + r) * K + k0 + c * 8];
        }
        __syncthreads();
        #pragma unroll
        for (int kk = 0; kk < 64; kk += 32) {
            short8 a0 = *(const short8*)&As[(wm + l16) * 88 + kk + quad * 8];
            short8 a1 = *(const short8*)&As[(wm + 16 + l16) * 88 + kk + quad * 8];
            #pragma unroll
            for (int nt = 0; nt < 4; ++nt) {
                short8 b = *(const short8*)&WT[(size_t)(wn + nt * 16 + l16) * K +
                                               k0 + kk + quad * 8];
                acc[0][nt] = __builtin_amdgcn_mfma_f32_16x16x32_bf16(a0, b, acc[0][nt], 0, 0, 0);
                acc[1][nt] = __builtin_amdgcn_mfma_f32_16x16x32_bf16(a1, b, acc[1][nt], 0, 0, 0);
            }
        }
    }

    #pragma unroll
    for (int mt = 0; mt < 2; ++mt) {
        #pragma unroll
        for (int r = 0; r < 4; ++r) {
            int lrow = wm + mt * 16 + quad * 4 + r;
            int row = row0 + lrow;
            float s = 0.f, ss = 0.f;
            #pragma unroll
            for (int nt = 0; nt < 4; ++nt) {
                int col = wn + nt * 16 + l16;
                size_t o = (size_t)row * DS + col;
                float v = acc[mt][nt][r] + X[o];
                acc[mt][nt][r] = v;
                X[o] = v;
                s += v; ss += v * v;
            }
            #pragma unroll
            for (int o2 = 1; o2 < 16; o2 <<= 1) {
                s  += __shfl_xor(s, o2);
                ss += __shfl_xor(ss, o2);
            }
            if (l16 == 0) {
                redS[lrow][(wv >> 1) * 2]     = s;
                redS[lrow][(wv >> 1) * 2 + 1] = ss;
            }
        }
    }
    __syncthreads();

    #pragma unroll
    for (int mt = 0; mt < 2; ++mt)
        #pragma unroll
        for (int r = 0; r < 4; ++r) {
            int lrow = wm + mt * 16 + quad * 4 + r;
            int row = row0 + lrow;
            f32x4v rv = *(f32x4v*)&redS[lrow][0];
            float s = rv[0] + rv[2], ss = rv[1] + rv[3];
            float m = s * (1.f / 128.f);
            float var = ss * (1.f / 128.f) - m * m;
            float rs = rsqrtf(var + 1e-5f);
            #pragma unroll
            for (int nt = 0; nt < 4; ++nt) {
                int col = wn + nt * 16 + l16;
                LNb[(size_t)row * DS + col] = f2b((acc[mt][nt][r] - m) * rs);
            }
        }
}

// ---------------------------------------------------------------------------
// Final W_out GEMM (fp32 A -> bf16 relu out), 64-row tile (round-7 version).
// ---------------------------------------------------------------------------
__global__ __launch_bounds__(256) void gemm_fin(
    const float* __restrict__ A, const u16* __restrict__ WT,
    u16* __restrict__ OutB, int K, int N)
{
    __shared__ __align__(16) u16 As[64 * 88];
    const int row0 = blockIdx.x * 64, n0 = blockIdx.y * 128;
    const int tid = threadIdx.x;
    const int w = tid >> 6, lane = tid & 63, quad = lane >> 4, l16 = lane & 15;
    const int wm = (w & 1) * 32, wn = (w >> 1) * 64;

    f32x4v acc[2][4];
    #pragma unroll
    for (int i = 0; i < 2; ++i)
        #pragma unroll
        for (int j = 0; j < 4; ++j) acc[i][j] = (f32x4v){0.f, 0.f, 0.f, 0.f};

    for (int k0 = 0; k0 < K; k0 += 64) {
        __syncthreads();
        #pragma unroll
        for (int it = 0; it < 4; ++it) {
            int idx = tid + it * 256;
            int r = idx >> 4, c = idx & 15;
            f32x4v v = *(const f32x4v*)(A + (size_t)(row0 + r) * K + k0 + c * 4);
            *(us4*)&As[r * 88 + c * 4] = pack4(v[0], v[1], v[2], v[3]);
        }
        __syncthreads();
        #pragma unroll
        for (int kk = 0; kk < 64; kk += 32) {
            short8 a0 = *(const short8*)&As[(wm + l16) * 88 + kk + quad * 8];
            short8 a1 = *(const short8*)&As[(wm + 16 + l16) * 88 + kk + quad * 8];
            #pragma unroll
            for (int nt = 0; nt < 4; ++nt) {
                short8 b = *(const short8*)&WT[(size_t)(n0 + wn + nt * 16 + l16) * K + k0 + kk + quad * 8];
                acc[0][nt] = __builtin_amdgcn_mfma_f32_16x16x32_bf16(a0, b, acc[0][nt], 0, 0, 0);
                acc[1][nt] = __builtin_amdgcn_mfma_f32_16x16x32_bf16(a1, b, acc[1][nt], 0, 0, 0);
            }
        }
    }
    #pragma unroll
    for (int mt = 0; mt < 2; ++mt)
        #pragma unroll
        for (int nt = 0; nt < 4; ++nt)
            #pragma unroll
            for (int r = 0; r < 4; ++r) {
                int row = row0 + wm + mt * 16 + quad * 4 + r;
                int col = n0 + wn + nt * 16 + l16;
                OutB[(size_t)row * N + col] = f2b(fmaxf(acc[mt][nt][r], 0.f));
            }
}

// ---------------------------------------------------------------------------
// Windowed attention v6: bias tile staged into sP via coalesced short8 loads;
// e-loop reads bias from LDS (was 32 scalar global loads per lane).
// ---------------------------------------------------------------------------
__global__ __launch_bounds__(256) void attn_kernel(
    const u16* __restrict__ QKV, const u16* __restrict__ BIASb,
    u16* __restrict__ O)
{
    __shared__ __align__(16) u16 sQ[64 * 40];
    __shared__ __align__(16) u16 sK[128 * 40];
    __shared__ __align__(16) u16 sVt[32 * 152];
    __shared__ __align__(16) u16 sP[64 * 136];   // bias tile, then P
    __shared__ float pmax[4][64];
    __shared__ float psum[4][64];
    __shared__ float gfac[4][64];

    int tid = threadIdx.x;
    int h = blockIdx.x & 3, w = (blockIdx.x >> 2) & 127, b = blockIdx.x >> 9;
    size_t rowbase = (size_t)b * N_ + w * QW;
    size_t bbase = ((size_t)(b * NWIN + w) * HEADS + h) * (QW * KW);
    const short8 zero8 = (short8){0, 0, 0, 0, 0, 0, 0, 0};

    {   // Q
        int r = tid >> 2, d8 = (tid & 3) * 8;
        *(short8*)&sQ[r * 40 + d8] =
            *(const short8*)&QKV[(rowbase + r) * 384 + h * DH + d8];
    }
    #pragma unroll
    for (int i = 0; i < 2; ++i) {  // K
        int idx = tid + i * 256;
        int r = idx >> 2, d8 = (idx & 3) * 8;
        int jk = w * QW + r - PADW;
        short8 v = zero8;
        if (jk >= 0 && jk < N_)
            v = *(const short8*)&QKV[((size_t)b * N_ + jk) * 384 + 128 + h * DH + d8];
        *(short8*)&sK[r * 40 + d8] = v;
    }
    {   // V transposed
        int kk = tid >> 1, d0 = (tid & 1) * 16;
        int jk = w * QW + kk - PADW;
        short8 v0 = zero8, v1 = zero8;
        if (jk >= 0 && jk < N_) {
            const u16* src = &QKV[((size_t)b * N_ + jk) * 384 + 256 + h * DH + d0];
            v0 = *(const short8*)src;
            v1 = *(const short8*)(src + 8);
        }
        #pragma unroll
        for (int j = 0; j < 8; ++j) {
            sVt[(d0 + j) * 152 + kk] = (u16)v0[j];
            sVt[(d0 + 8 + j) * 152 + kk] = (u16)v1[j];
        }
    }
    #pragma unroll
    for (int i = 0; i < 4; ++i) {  // bias tile -> sP ([q][kk], stride 136)
        int idx = tid + i * 256;
        int q = idx >> 4, c8 = idx & 15;
        *(short8*)&sP[q * 136 + c8 * 8] =
            *(const short8*)&BIASb[bbase + (size_t)q * KW + c8 * 8];
    }
    __syncthreads();

    int wv = tid >> 6, lane = tid & 63, quad = lane >> 4, l16 = lane & 15;
    const float scale = 0.17677669529663687f;

    short8 aq[4];
    #pragma unroll
    for (int mt = 0; mt < 4; ++mt)
        aq[mt] = *(short8*)&sQ[(mt * 16 + l16) * 40 + quad * 8];
    float e[2][4][4];
    #pragma unroll
    for (int ni = 0; ni < 2; ++ni) {
        int nt = wv * 2 + ni;
        short8 bk = *(short8*)&sK[(nt * 16 + l16) * 40 + quad * 8];
        int kk = nt * 16 + l16;
        int jk = w * QW + kk - PADW;
        float msk = (jk >= 0 && jk < N_) ? 0.f : -1e9f;
        #pragma unroll
        for (int mt = 0; mt < 4; ++mt) {
            f32x4v acc = (f32x4v){0.f, 0.f, 0.f, 0.f};
            acc = __builtin_amdgcn_mfma_f32_16x16x32_bf16(aq[mt], bk, acc, 0, 0, 0);
            #pragma unroll
            for (int r = 0; r < 4; ++r) {
                int q = mt * 16 + quad * 4 + r;
                e[ni][mt][r] = acc[r] * scale + b2f(sP[q * 136 + kk]) + msk;
            }
        }
    }

    #pragma unroll
    for (int mt = 0; mt < 4; ++mt)
        #pragma unroll
        for (int r = 0; r < 4; ++r) {
            float m = fmaxf(e[0][mt][r], e[1][mt][r]);
            m = fmaxf(m, __shfl_xor(m, 1));
            m = fmaxf(m, __shfl_xor(m, 2));
            m = fmaxf(m, __shfl_xor(m, 4));
            m = fmaxf(m, __shfl_xor(m, 8));
            float e0 = __expf(e[0][mt][r] - m);
            float e1 = __expf(e[1][mt][r] - m);
            e[0][mt][r] = e0; e[1][mt][r] = e1;
            float s = e0 + e1;
            s += __shfl_xor(s, 1);
            s += __shfl_xor(s, 2);
            s += __shfl_xor(s, 4);
            s += __shfl_xor(s, 8);
            if (l16 == 0) {
                int q = mt * 16 + quad * 4 + r;
                pmax[wv][q] = m;
                psum[wv][q] = s;
            }
        }
    __syncthreads();

    if (tid < 64) {
        float m0 = pmax[0][tid], m1 = pmax[1][tid], m2 = pmax[2][tid], m3 = pmax[3][tid];
        float M = fmaxf(fmaxf(m0, m1), fmaxf(m2, m3));
        float g0 = __expf(m0 - M), g1 = __expf(m1 - M),
              g2 = __expf(m2 - M), g3 = __expf(m3 - M);
        float T = psum[0][tid] * g0 + psum[1][tid] * g1 +
                  psum[2][tid] * g2 + psum[3][tid] * g3;
        float inv = 1.f / T;
        gfac[0][tid] = g0 * inv; gfac[1][tid] = g1 * inv;
        gfac[2][tid] = g2 * inv; gfac[3][tid] = g3 * inv;
    }
    __syncthreads();

    #pragma unroll
    for (int mt = 0; mt < 4; ++mt)
        #pragma unroll
        for (int r = 0; r < 4; ++r) {
            int q = mt * 16 + quad * 4 + r;
            float f = gfac[wv][q];
            #pragma unroll
            for (int ni = 0; ni < 2; ++ni) {
                int kk = (wv * 2 + ni) * 16 + l16;
                sP[q * 136 + kk] = f2b(e[ni][mt][r] * f);
            }
        }
    __syncthreads();

    {
        int mt = wv;
        short8 ap[4];
        #pragma unroll
        for (int ks = 0; ks < 4; ++ks)
            ap[ks] = *(short8*)&sP[(mt * 16 + l16) * 136 + ks * 32 + quad * 8];
        #pragma unroll
        for (int nt = 0; nt < 2; ++nt) {
            f32x4v acc = (f32x4v){0.f, 0.f, 0.f, 0.f};
            #pragma unroll
            for (int ks = 0; ks < 4; ++ks) {
                short8 bv = *(short8*)&sVt[(nt * 16 + l16) * 152 + ks * 32 + quad * 8];
                acc = __builtin_amdgcn_mfma_f32_16x16x32_bf16(ap[ks], bv, acc, 0, 0, 0);
            }
            int d = nt * 16 + l16;
            #pragma unroll
            for (int r = 0; r < 4; ++r) {
                int q = mt * 16 + quad * 4 + r;
                O[(rowbase + q) * DS + h * DH + d] = f2b(acc[r]);
            }
        }
    }
}

// ---------------------------------------------------------------------------
// Segment mean (unchanged).
// ---------------------------------------------------------------------------
__global__ __launch_bounds__(128) void seg_kernel(
    const u16* __restrict__ TOKb, const int* __restrict__ idx,
    float* __restrict__ out)
{
    int t = blockIdx.x & (NT - 1);
    int b = blockIdx.x >> 10;
    const int* id = idx + (size_t)b * N_;

    int lo = 0, hi = N_;
    while (lo < hi) { int mid = (lo + hi) >> 1; if (id[mid] < t) lo = mid + 1; else hi = mid; }
    int start = lo;
    hi = N_;
    while (lo < hi) { int mid = (lo + hi) >> 1; if (id[mid] < t + 1) lo = mid + 1; else hi = mid; }
    int end = lo;

    float inv = 1.f / fmaxf((float)(end - start), 1.f);
    for (int c = threadIdx.x; c < DT; c += 128) {
        float s = 0.f;
        for (int r = start; r < end; ++r) s += b2f(TOKb[((size_t)b * N_ + r) * DT + c]);
        out[((size_t)b * NT + t) * DT + c] = s * inv;
    }
}

// ---------------------------------------------------------------------------
extern "C" void kernel_launch(void* const* d_in, const int* in_sizes, int n_in,
                              void* d_out, int out_size, void* d_ws, size_t ws_size,
                              hipStream_t stream)
{
    const float* ref_pos    = (const float*)d_in[0];
    const float* ref_charge = (const float*)d_in[1];
    const float* ref_mask   = (const float*)d_in[2];
    const float* ref_elem   = (const float*)d_in[3];
    const float* ref_chars  = (const float*)d_in[4];
    const float* W_single   = (const float*)d_in[5];
    const float* W_pair     = (const float*)d_in[6];
    const float* W_outer    = (const float*)d_in[7];
    const float* Wp_ff1     = (const float*)d_in[8];
    const float* Wp_ff2     = (const float*)d_in[9];
    const float* Wq         = (const float*)d_in[10];
    const float* Wk         = (const float*)d_in[11];
    const float* Wv         = (const float*)d_in[12];
    const float* Wo         = (const float*)d_in[13];
    const float* Wb         = (const float*)d_in[14];
    const float* Wff1       = (const float*)d_in[15];
    const float* Wff2       = (const float*)d_in[16];
    const float* W_out      = (const float*)d_in[17];
    const int*   uid        = (const int*)d_in[18];
    const int*   a2t        = (const int*)d_in[19];
    float* out = (float*)d_out;

    const size_t ROWS = (size_t)B_ * N_;  // 16384
    float* ws = (float*)d_ws;
    float* X    = ws;
    float* P    = X + ROWS * DS;
    u16* QKVb   = (u16*)(P + ROWS * 32);
    u16* Ob     = QKVb + ROWS * 384;
    u16* FFb    = Ob + ROWS * DS;
    u16* BIASb  = FFb + ROWS * 512;
    u16* TOKb   = BIASb + (size_t)B_ * NWIN * HEADS * QW * KW;
    u16* LNb    = TOKb + ROWS * DT;
    u16* qkvT   = LNb + ROWS * DS;
    u16* woT    = qkvT + 3 * 384 * 128;
    u16* ff1T   = woT + 3 * 128 * 128;
    u16* ff2T   = ff1T + 3 * 512 * 128;
    u16* woutT  = ff2T + 3 * 128 * 512;
    u16* w1T32  = woutT + 384 * 128;
    u16* wcatT  = w1T32 + 64 * 32;
    u16* wsT    = wcatT + 16 * 96;
    u16* woutrT = wsT + 128 * 416;

    convw_kernel<<<768, 256, 0, stream>>>(Wq, Wk, Wv, Wo, Wff1, Wff2, W_out,
                                          Wp_ff1, Wp_ff2, Wb, W_single, W_outer,
                                          qkvT, woT, ff1T, ff2T, woutT,
                                          w1T32, wcatT, wsT, woutrT);
    embed_gemm<<<ROWS / 64, 256, 0, stream>>>(ref_pos, ref_charge, ref_mask,
                                              ref_elem, ref_chars, wsT, woutrT,
                                              X, LNb, P);
    bias_kernel<<<4096, 256, 0, stream>>>(ref_pos, uid, P, W_pair,
                                          w1T32, wcatT, BIASb);

    for (int l = 0; l < DEPTH; ++l) {
        gemm_bf<false><<<dim3(ROWS / 64, 3), 256, 0, stream>>>(
            LNb, qkvT + (size_t)l * 384 * 128, QKVb, 384);
        attn_kernel<<<B_ * NWIN * HEADS, 256, 0, stream>>>(QKVb, BIASb, Ob);
        gemm_addln<<<dim3(ROWS / 64, 1), 256, 0, stream>>>(
            Ob, woT + (size_t)l * 128 * 128, X, LNb, 128);
        gemm_bf<true><<<dim3(ROWS / 64, 4), 256, 0, stream>>>(
            LNb, ff1T + (size_t)l * 512 * 128, FFb, 512);
        gemm_addln<<<dim3(ROWS / 64, 1), 256, 0, stream>>>(
            FFb, ff2T + (size_t)l * 128 * 512, X, LNb, 512);
    }

    gemm_fin<<<dim3(ROWS / 64, 3), 256, 0, stream>>>(X, woutT, TOKb, DS, DT);
    seg_kernel<<<B_ * NT, 128, 0, stream>>>(TOKb, a2t, out);
}

// Round 10
// 443.454 us; speedup vs baseline: 1.1252x; 1.0867x over previous
//
#include <hip/hip_runtime.h>
#include <hip/hip_bf16.h>

#define QW 64
#define KW 128
#define PADW 32
#define DEPTH 3
#define HEADS 4
#define B_ 2
#define N_ 8192
#define DS 128
#define DP 16
#define DT 384
#define NT 1024
#define NWIN (N_ / QW)   // 128
#define DH (DS / HEADS)  // 32

typedef unsigned short u16;
typedef __attribute__((ext_vector_type(8))) short short8;
typedef __attribute__((ext_vector_type(4))) float f32x4v;
typedef __attribute__((ext_vector_type(4))) unsigned short us4;

__device__ __forceinline__ u16 f2b(float x) {
    union { float f; unsigned u; } v; v.f = x;
    unsigned r = v.u + 0x7fffu + ((v.u >> 16) & 1u);
    return (u16)(r >> 16);
}
__device__ __forceinline__ float b2f(u16 h) {
    union { unsigned u; float f; } v; v.u = ((unsigned)h) << 16; return v.f;
}
__device__ __forceinline__ unsigned f2b2(float a, float b) {
    __hip_bfloat162 h = __float22bfloat162_rn(make_float2(a, b));
    union { __hip_bfloat162 h; unsigned u; } c; c.h = h; return c.u;
}
__device__ __forceinline__ us4 pack4(float a, float b, float c, float d) {
    union { us4 v; unsigned u[2]; } o;
    o.u[0] = f2b2(a, b);
    o.u[1] = f2b2(c, d);
    return o.v;
}

// ---------------------------------------------------------------------------
// Weight prep (unchanged).
// ---------------------------------------------------------------------------
__global__ __launch_bounds__(256) void convw_kernel(
    const float* __restrict__ Wq, const float* __restrict__ Wk,
    const float* __restrict__ Wv, const float* __restrict__ Wo,
    const float* __restrict__ Wff1, const float* __restrict__ Wff2,
    const float* __restrict__ Wout, const float* __restrict__ Wpff1,
    const float* __restrict__ Wpff2, const float* __restrict__ Wb,
    const float* __restrict__ Wsingle, const float* __restrict__ Wouter,
    u16* __restrict__ qkvT, u16* __restrict__ woT, u16* __restrict__ ff1T,
    u16* __restrict__ ff2T, u16* __restrict__ woutT,
    u16* __restrict__ w1T32, u16* __restrict__ wcatT,
    u16* __restrict__ wsT, u16* __restrict__ woutrT)
{
    int idx = blockIdx.x * 256 + threadIdx.x;
    if (idx < 3 * 384 * 128) {
        int l = idx / (384 * 128), r = idx % (384 * 128);
        int n = r / 128, k = r % 128;
        const float* W = (n < 128) ? Wq : (n < 256) ? Wk : Wv;
        qkvT[idx] = f2b(W[(size_t)l * 16384 + k * 128 + (n & 127)]);
    }
    if (idx < 3 * 128 * 128) {
        int l = idx / 16384, r = idx % 16384;
        int n = r / 128, k = r % 128;
        woT[idx] = f2b(Wo[(size_t)l * 16384 + k * 128 + n]);
    }
    if (idx < 3 * 512 * 128) {
        int l = idx / 65536, r = idx % 65536;
        int n = r / 128, k = r % 128;
        ff1T[idx] = f2b(Wff1[(size_t)l * 65536 + k * 512 + n]);
    }
    if (idx < 3 * 128 * 512) {
        int l = idx / 65536, r = idx % 65536;
        int n = r / 512, k = r % 512;
        ff2T[idx] = f2b(Wff2[(size_t)l * 65536 + k * 128 + n]);
    }
    if (idx < 384 * 128) {
        int n = idx / 128, k = idx % 128;
        woutT[idx] = f2b(Wout[(size_t)k * 384 + n]);
    }
    if (idx < 64 * 32) {
        int n = idx >> 5, k = idx & 31;
        w1T32[idx] = (k < 16) ? f2b(Wpff1[k * 64 + n]) : (u16)0;
    }
    if (idx < 16 * 96) {
        int h = idx / 96, k = idx % 96;
        float s = 0.f;
        if (h < 4) {
            if (k < 16) s = Wb[k * 4 + h];
            else if (k < 80) {
                int j = k - 16;
                for (int c = 0; c < 16; ++c) s += Wpff2[j * 16 + c] * Wb[c * 4 + h];
            }
        }
        wcatT[idx] = f2b(s);
    }
    if (idx < 128 * 416) {
        int n = idx / 416, k = idx % 416;
        float v = 0.f;
        if (k < 128)       v = Wsingle[(5 + k) * 128 + n];
        else if (k < 384)  v = Wsingle[(133 + k - 128) * 128 + n];
        else if (k < 387)  v = Wsingle[(k - 384) * 128 + n];
        else if (k == 387) v = Wsingle[3 * 128 + n];
        else if (k == 388) v = Wsingle[4 * 128 + n];
        wsT[idx] = f2b(v);
    }
    if (idx < 32 * 128) {
        int n = idx >> 7, k = idx & 127;
        woutrT[idx] = f2b(Wouter[k * 32 + n]);
    }
}

// ---------------------------------------------------------------------------
// Embed GEMM + fused LN + fused P-GEMM (unchanged).
// ---------------------------------------------------------------------------
__global__ __launch_bounds__(256) void embed_gemm(
    const float* __restrict__ pos, const float* __restrict__ charge,
    const float* __restrict__ mask, const float* __restrict__ elem,
    const float* __restrict__ chars, const u16* __restrict__ wsT,
    const u16* __restrict__ woutrT,
    float* __restrict__ X, u16* __restrict__ LNb, float* __restrict__ P)
{
    __shared__ __align__(16) u16 As[64 * 424];
    __shared__ float redS[64][4];
    int tid = threadIdx.x;
    int row0 = blockIdx.x * 64;

    #pragma unroll
    for (int it = 0; it < 8; ++it) {
        int idx = tid + it * 256;
        int r = idx >> 5, c4 = idx & 31;
        f32x4v v = *(const f32x4v*)(elem + (size_t)(row0 + r) * 128 + c4 * 4);
        *(us4*)&As[r * 424 + c4 * 4] = pack4(v[0], v[1], v[2], v[3]);
    }
    #pragma unroll
    for (int it = 0; it < 16; ++it) {
        int idx = tid + it * 256;
        int r = idx >> 6, c4 = idx & 63;
        f32x4v v = *(const f32x4v*)(chars + (size_t)(row0 + r) * 256 + c4 * 4);
        *(us4*)&As[r * 424 + 128 + c4 * 4] = pack4(v[0], v[1], v[2], v[3]);
    }
    if (tid < 64) {
        int g = row0 + tid;
        As[tid * 424 + 384] = f2b(pos[g * 3]);
        As[tid * 424 + 385] = f2b(pos[g * 3 + 1]);
        As[tid * 424 + 386] = f2b(pos[g * 3 + 2]);
        As[tid * 424 + 387] = f2b(charge[g]);
        As[tid * 424 + 388] = f2b(mask[g]);
        for (int c = 389; c < 416; ++c) As[tid * 424 + c] = 0;
    }
    __syncthreads();

    int wv = tid >> 6, lane = tid & 63, quad = lane >> 4, l16 = lane & 15;
    int wm = (wv & 1) * 32, wn = (wv >> 1) * 64;
    f32x4v acc[2][4];
    #pragma unroll
    for (int i = 0; i < 2; ++i)
        #pragma unroll
        for (int j = 0; j < 4; ++j) acc[i][j] = (f32x4v){0.f, 0.f, 0.f, 0.f};

    #pragma unroll
    for (int kk = 0; kk < 13; ++kk) {
        short8 a0 = *(short8*)&As[(wm + l16) * 424 + kk * 32 + quad * 8];
        short8 a1 = *(short8*)&As[(wm + 16 + l16) * 424 + kk * 32 + quad * 8];
        #pragma unroll
        for (int nt = 0; nt < 4; ++nt) {
            short8 bw = *(const short8*)&wsT[(size_t)(wn + nt * 16 + l16) * 416 +
                                             kk * 32 + quad * 8];
            acc[0][nt] = __builtin_amdgcn_mfma_f32_16x16x32_bf16(a0, bw, acc[0][nt], 0, 0, 0);
            acc[1][nt] = __builtin_amdgcn_mfma_f32_16x16x32_bf16(a1, bw, acc[1][nt], 0, 0, 0);
        }
    }
    __syncthreads();

    #pragma unroll
    for (int mt = 0; mt < 2; ++mt) {
        #pragma unroll
        for (int r = 0; r < 4; ++r) {
            int lrow = wm + mt * 16 + quad * 4 + r;
            int row = row0 + lrow;
            float s = 0.f, ss = 0.f;
            #pragma unroll
            for (int nt = 0; nt < 4; ++nt) {
                float v = acc[mt][nt][r];
                int col = wn + nt * 16 + l16;
                X[(size_t)row * DS + col] = v;
                As[lrow * 136 + col] = f2b(fmaxf(v, 0.f));
                s += v; ss += v * v;
            }
            #pragma unroll
            for (int o = 1; o < 16; o <<= 1) {
                s  += __shfl_xor(s, o);
                ss += __shfl_xor(ss, o);
            }
            if (l16 == 0) {
                redS[lrow][(wv >> 1) * 2]     = s;
                redS[lrow][(wv >> 1) * 2 + 1] = ss;
            }
        }
    }
    __syncthreads();

    #pragma unroll
    for (int mt = 0; mt < 2; ++mt)
        #pragma unroll
        for (int r = 0; r < 4; ++r) {
            int lrow = wm + mt * 16 + quad * 4 + r;
            int row = row0 + lrow;
            f32x4v rv = *(f32x4v*)&redS[lrow][0];
            float s = rv[0] + rv[2], ss = rv[1] + rv[3];
            float m = s * (1.f / 128.f);
            float var = ss * (1.f / 128.f) - m * m;
            float rs = rsqrtf(var + 1e-5f);
            #pragma unroll
            for (int nt = 0; nt < 4; ++nt) {
                int col = wn + nt * 16 + l16;
                LNb[(size_t)row * DS + col] = f2b((acc[mt][nt][r] - m) * rs);
            }
        }

    {
        f32x4v pacc[2];
        pacc[0] = (f32x4v){0.f, 0.f, 0.f, 0.f};
        pacc[1] = (f32x4v){0.f, 0.f, 0.f, 0.f};
        #pragma unroll
        for (int ks = 0; ks < 4; ++ks) {
            short8 a = *(short8*)&As[(wv * 16 + l16) * 136 + ks * 32 + quad * 8];
            #pragma unroll
            for (int nt = 0; nt < 2; ++nt) {
                short8 bw = *(const short8*)&woutrT[(size_t)(nt * 16 + l16) * 128 +
                                                    ks * 32 + quad * 8];
                pacc[nt] = __builtin_amdgcn_mfma_f32_16x16x32_bf16(a, bw, pacc[nt], 0, 0, 0);
            }
        }
        #pragma unroll
        for (int nt = 0; nt < 2; ++nt)
            #pragma unroll
            for (int r = 0; r < 4; ++r) {
                int row = row0 + wv * 16 + quad * 4 + r;
                P[(size_t)row * 32 + nt * 16 + l16] = pacc[nt][r];
            }
    }
}

// ---------------------------------------------------------------------------
// Bias kernel v7 (unchanged from round 9).
// ---------------------------------------------------------------------------
__global__ __launch_bounds__(256) void bias_kernel(
    const float* __restrict__ pos, const int* __restrict__ uid,
    const float* __restrict__ P, const float* __restrict__ Wpair,
    const u16* __restrict__ w1T32, const u16* __restrict__ wcatT,
    u16* __restrict__ BIASb)
{
    __shared__ __align__(16) float posjS[128][4];
    __shared__ __align__(16) u16 lpS[4][16 * 24];
    __shared__ __align__(16) u16 A2S[4][16 * 104];

    int tid = threadIdx.x;
    int b  = blockIdx.x >> 11;
    int w  = (blockIdx.x >> 4) & 127;
    int qg = blockIdx.x & 15;

    if (tid < 128) {
        int r = tid;
        int jk = w * QW + r - PADW;
        bool valid = (jk >= 0) && (jk < N_);
        int gk = b * N_ + jk;
        float x = 0.f, y = 0.f, zz = 0.f; int u = 0;
        if (valid) { x = pos[gk * 3]; y = pos[gk * 3 + 1]; zz = pos[gk * 3 + 2]; u = uid[gk]; }
        posjS[r][0] = x; posjS[r][1] = y; posjS[r][2] = zz;
        ((int*)posjS[r])[3] = u;
    }

    int wv = tid >> 6, lane = tid & 63, quad = lane >> 4, l16 = lane & 15;
    int cl = lane >> 2, cg = lane & 3;
    int q = qg * 4 + wv;
    int gq = b * N_ + w * QW + q;

    float xi = pos[gq * 3], yi = pos[gq * 3 + 1], zi = pos[gq * 3 + 2];
    int ui = uid[gq];
    f32x4v pi4 = *(const f32x4v*)(P + (size_t)gq * 32 + cg * 4);
    f32x4v wp[5];
    #pragma unroll
    for (int f = 0; f < 5; ++f)
        wp[f] = *(const f32x4v*)(Wpair + f * 16 + cg * 4);
    short8 w1f[4], wcat[3];
    #pragma unroll
    for (int nt = 0; nt < 4; ++nt)
        w1f[nt] = *(const short8*)&w1T32[(nt * 16 + l16) * 32 + quad * 8];
    #pragma unroll
    for (int ks = 0; ks < 3; ++ks)
        wcat[ks] = *(const short8*)&wcatT[l16 * 96 + ks * 32 + quad * 8];

    f32x4v pjv[8];
    #pragma unroll
    for (int t = 0; t < 8; ++t) {
        int jk = w * QW + t * 16 + cl - PADW;
        bool valid = (jk >= 0) && (jk < N_);
        int gk = b * N_ + jk;
        f32x4v v = (f32x4v){0.f, 0.f, 0.f, 0.f};
        if (valid) v = *(const f32x4v*)(P + (size_t)gk * 32 + 16 + cg * 4);
        pjv[t] = v;
    }

    *(us4*)&A2S[wv][l16 * 104 + 80 + quad * 4] = (us4){0, 0, 0, 0};
    __syncthreads();

    size_t bbase = ((size_t)(b * NWIN + w) * HEADS) * (QW * KW);
    const short8 zero8 = (short8){0, 0, 0, 0, 0, 0, 0, 0};

    for (int t = 0; t < 8; ++t) {
        int kk1 = t * 16 + cl;
        float xj = posjS[kk1][0], yj = posjS[kk1][1], zj = posjS[kk1][2];
        int uj = ((int*)posjS[kk1])[3];
        float dx = xi - xj, dy = yi - yj, dz = zi - zj;
        float inv = 1.f / (1.f + dx * dx + dy * dy + dz * dz);
        float bf = (ui == uj) ? 1.f : 0.f;
        float pr[4];
        #pragma unroll
        for (int j = 0; j < 4; ++j) {
            float s = fmaf(dx, wp[0][j], fmaf(dy, wp[1][j],
                      fmaf(dz, wp[2][j], fmaf(inv, wp[3][j], wp[4][j]))));
            pr[j] = fmaf(bf, s, pi4[j] + pjv[t][j]);
        }
        float sum = pr[0] + pr[1] + pr[2] + pr[3];
        sum += __shfl_xor(sum, 1); sum += __shfl_xor(sum, 2);
        float m = sum * (1.f / 16.f);
        float d0 = pr[0] - m, d1 = pr[1] - m, d2 = pr[2] - m, d3 = pr[3] - m;
        float vs = d0 * d0 + d1 * d1 + d2 * d2 + d3 * d3;
        vs += __shfl_xor(vs, 1); vs += __shfl_xor(vs, 2);
        float rstd = rsqrtf(vs * (1.f / 16.f) + 1e-5f);
        *(us4*)&lpS[wv][cl * 24 + cg * 4] =
            pack4(d0 * rstd, d1 * rstd, d2 * rstd, d3 * rstd);
        *(us4*)&A2S[wv][cl * 104 + cg * 4] = pack4(pr[0], pr[1], pr[2], pr[3]);

        short8 blp = zero8;
        if (quad < 2) blp = *(short8*)&lpS[wv][l16 * 24 + quad * 8];
        #pragma unroll
        for (int nt = 0; nt < 4; ++nt) {
            f32x4v z4 = (f32x4v){0.f, 0.f, 0.f, 0.f};
            z4 = __builtin_amdgcn_mfma_f32_16x16x32_bf16(w1f[nt], blp, z4, 0, 0, 0);
            *(us4*)&A2S[wv][l16 * 104 + 16 + nt * 16 + quad * 4] =
                pack4(fmaxf(z4[0], 0.f), fmaxf(z4[1], 0.f),
                      fmaxf(z4[2], 0.f), fmaxf(z4[3], 0.f));
        }
        f32x4v acc = (f32x4v){0.f, 0.f, 0.f, 0.f};
        #pragma unroll
        for (int ks = 0; ks < 3; ++ks) {
            short8 a2 = *(short8*)&A2S[wv][l16 * 104 + ks * 32 + quad * 8];
            acc = __builtin_amdgcn_mfma_f32_16x16x32_bf16(a2, wcat[ks], acc, 0, 0, 0);
        }
        if (l16 < 4) {
            *(us4*)&BIASb[bbase + (size_t)l16 * (QW * KW) + q * KW +
                          t * 16 + quad * 4] = pack4(acc[0], acc[1], acc[2], acc[3]);
        }
    }
}

// ---------------------------------------------------------------------------
// Plain bf16-A GEMM (K=128), 64-row tile — QKV only.
// ---------------------------------------------------------------------------
template <bool RELU>
__global__ __launch_bounds__(256) void gemm_bf(
    const u16* __restrict__ A, const u16* __restrict__ WT,
    u16* __restrict__ OutB, int N)
{
    __shared__ __align__(16) u16 As[64 * 136];
    int tid = threadIdx.x;
    int row0 = blockIdx.x * 64, n0 = blockIdx.y * 128;

    #pragma unroll
    for (int it = 0; it < 4; ++it) {
        int idx = tid + it * 256;
        int r = idx >> 4, c8 = idx & 15;
        *(short8*)&As[r * 136 + c8 * 8] =
            *(const short8*)&A[(size_t)(row0 + r) * 128 + c8 * 8];
    }
    __syncthreads();

    int wv = tid >> 6, lane = tid & 63, quad = lane >> 4, l16 = lane & 15;
    int wm = (wv & 1) * 32, wn = (wv >> 1) * 64;
    f32x4v acc[2][4];
    #pragma unroll
    for (int i = 0; i < 2; ++i)
        #pragma unroll
        for (int j = 0; j < 4; ++j) acc[i][j] = (f32x4v){0.f, 0.f, 0.f, 0.f};

    #pragma unroll
    for (int kk = 0; kk < 4; ++kk) {
        short8 a0 = *(short8*)&As[(wm + l16) * 136 + kk * 32 + quad * 8];
        short8 a1 = *(short8*)&As[(wm + 16 + l16) * 136 + kk * 32 + quad * 8];
        #pragma unroll
        for (int nt = 0; nt < 4; ++nt) {
            short8 bw = *(const short8*)&WT[(size_t)(n0 + wn + nt * 16 + l16) * 128 +
                                            kk * 32 + quad * 8];
            acc[0][nt] = __builtin_amdgcn_mfma_f32_16x16x32_bf16(a0, bw, acc[0][nt], 0, 0, 0);
            acc[1][nt] = __builtin_amdgcn_mfma_f32_16x16x32_bf16(a1, bw, acc[1][nt], 0, 0, 0);
        }
    }
    #pragma unroll
    for (int mt = 0; mt < 2; ++mt)
        #pragma unroll
        for (int nt = 0; nt < 4; ++nt)
            #pragma unroll
            for (int r = 0; r < 4; ++r) {
                int row = row0 + wm + mt * 16 + quad * 4 + r;
                int col = n0 + wn + nt * 16 + l16;
                float v = acc[mt][nt][r];
                if (RELU) v = fmaxf(v, 0.f);
                OutB[(size_t)row * N + col] = f2b(v);
            }
}

// ---------------------------------------------------------------------------
// bf16-A GEMM + residual ADD + fused LN (64-row) — WO only (K=128).
// ---------------------------------------------------------------------------
__global__ __launch_bounds__(256) void gemm_addln(
    const u16* __restrict__ A, const u16* __restrict__ WT,
    float* __restrict__ X, u16* __restrict__ LNb, int K)
{
    __shared__ __align__(16) u16 As[64 * 88];
    __shared__ float redS[64][4];
    const int row0 = blockIdx.x * 64;
    const int tid = threadIdx.x;
    const int wv = tid >> 6, lane = tid & 63, quad = lane >> 4, l16 = lane & 15;
    const int wm = (wv & 1) * 32, wn = (wv >> 1) * 64;

    f32x4v acc[2][4];
    #pragma unroll
    for (int i = 0; i < 2; ++i)
        #pragma unroll
        for (int j = 0; j < 4; ++j) acc[i][j] = (f32x4v){0.f, 0.f, 0.f, 0.f};

    for (int k0 = 0; k0 < K; k0 += 64) {
        __syncthreads();
        #pragma unroll
        for (int it = 0; it < 2; ++it) {
            int idx = tid + it * 256;
            int r = idx >> 3, c = idx & 7;
            *(short8*)&As[r * 88 + c * 8] =
                *(const short8*)&A[(size_t)(row0 + r) * K + k0 + c * 8];
        }
        __syncthreads();
        #pragma unroll
        for (int kk = 0; kk < 64; kk += 32) {
            short8 a0 = *(const short8*)&As[(wm + l16) * 88 + kk + quad * 8];
            short8 a1 = *(const short8*)&As[(wm + 16 + l16) * 88 + kk + quad * 8];
            #pragma unroll
            for (int nt = 0; nt < 4; ++nt) {
                short8 b = *(const short8*)&WT[(size_t)(wn + nt * 16 + l16) * K +
                                               k0 + kk + quad * 8];
                acc[0][nt] = __builtin_amdgcn_mfma_f32_16x16x32_bf16(a0, b, acc[0][nt], 0, 0, 0);
                acc[1][nt] = __builtin_amdgcn_mfma_f32_16x16x32_bf16(a1, b, acc[1][nt], 0, 0, 0);
            }
        }
    }

    #pragma unroll
    for (int mt = 0; mt < 2; ++mt) {
        #pragma unroll
        for (int r = 0; r < 4; ++r) {
            int lrow = wm + mt * 16 + quad * 4 + r;
            int row = row0 + lrow;
            float s = 0.f, ss = 0.f;
            #pragma unroll
            for (int nt = 0; nt < 4; ++nt) {
                int col = wn + nt * 16 + l16;
                size_t o = (size_t)row * DS + col;
                float v = acc[mt][nt][r] + X[o];
                acc[mt][nt][r] = v;
                X[o] = v;
                s += v; ss += v * v;
            }
            #pragma unroll
            for (int o2 = 1; o2 < 16; o2 <<= 1) {
                s  += __shfl_xor(s, o2);
                ss += __shfl_xor(ss, o2);
            }
            if (l16 == 0) {
                redS[lrow][(wv >> 1) * 2]     = s;
                redS[lrow][(wv >> 1) * 2 + 1] = ss;
            }
        }
    }
    __syncthreads();

    #pragma unroll
    for (int mt = 0; mt < 2; ++mt)
        #pragma unroll
        for (int r = 0; r < 4; ++r) {
            int lrow = wm + mt * 16 + quad * 4 + r;
            int row = row0 + lrow;
            f32x4v rv = *(f32x4v*)&redS[lrow][0];
            float s = rv[0] + rv[2], ss = rv[1] + rv[3];
            float m = s * (1.f / 128.f);
            float var = ss * (1.f / 128.f) - m * m;
            float rs = rsqrtf(var + 1e-5f);
            #pragma unroll
            for (int nt = 0; nt < 4; ++nt) {
                int col = wn + nt * 16 + l16;
                LNb[(size_t)row * DS + col] = f2b((acc[mt][nt][r] - m) * rs);
            }
        }
}

// ---------------------------------------------------------------------------
// ff_fused: X += relu(LNin @ W1) @ W2 ; LNb = LN(X).  32-row blocks (512).
// Hidden 32x512 bf16 lives in LDS (stride 520). FF1 uses swapped operands
// so relu output packs into us4 LDS stores; FF2 reads hidden as A-frags.
// ---------------------------------------------------------------------------
__global__ __launch_bounds__(256) void ff_fused(
    const u16* __restrict__ LNin, const u16* __restrict__ w1T,
    const u16* __restrict__ w2T, float* __restrict__ X,
    u16* __restrict__ LNb)
{
    __shared__ __align__(16) u16 As[32 * 136];   // 8.5 KB
    __shared__ __align__(16) u16 Hs[32 * 520];   // 32.5 KB
    __shared__ float redS[32][4];
    int tid = threadIdx.x;
    int row0 = blockIdx.x * 32;
    int wv = tid >> 6, lane = tid & 63, quad = lane >> 4, l16 = lane & 15;

    #pragma unroll
    for (int it = 0; it < 2; ++it) {
        int idx = tid + it * 256;
        int r = idx >> 4, c8 = idx & 15;
        *(short8*)&As[r * 136 + c8 * 8] =
            *(const short8*)&LNin[(size_t)(row0 + r) * 128 + c8 * 8];
    }
    __syncthreads();

    // FF1 (swapped): wave wv owns hidden [wv*128, wv*128+128), all 32 rows.
    {
        short8 brow[2][4];
        #pragma unroll
        for (int nt = 0; nt < 2; ++nt)
            #pragma unroll
            for (int ks = 0; ks < 4; ++ks)
                brow[nt][ks] = *(short8*)&As[(nt * 16 + l16) * 136 + ks * 32 + quad * 8];
        #pragma unroll
        for (int mt = 0; mt < 8; ++mt) {
            int j0 = wv * 128 + mt * 16;   // hidden tile base
            f32x4v c0 = (f32x4v){0.f, 0.f, 0.f, 0.f};
            f32x4v c1 = (f32x4v){0.f, 0.f, 0.f, 0.f};
            #pragma unroll
            for (int ks = 0; ks < 4; ++ks) {
                short8 aw = *(const short8*)&w1T[(size_t)(j0 + l16) * 128 +
                                                 ks * 32 + quad * 8];
                c0 = __builtin_amdgcn_mfma_f32_16x16x32_bf16(aw, brow[0][ks], c0, 0, 0, 0);
                c1 = __builtin_amdgcn_mfma_f32_16x16x32_bf16(aw, brow[1][ks], c1, 0, 0, 0);
            }
            // C rows = hidden j (quad*4+r), cols = atom row (l16)
            *(us4*)&Hs[l16 * 520 + j0 + quad * 4] =
                pack4(fmaxf(c0[0], 0.f), fmaxf(c0[1], 0.f),
                      fmaxf(c0[2], 0.f), fmaxf(c0[3], 0.f));
            *(us4*)&Hs[(16 + l16) * 520 + j0 + quad * 4] =
                pack4(fmaxf(c1[0], 0.f), fmaxf(c1[1], 0.f),
                      fmaxf(c1[2], 0.f), fmaxf(c1[3], 0.f));
        }
    }
    __syncthreads();

    // FF2: wave tile 16(M) x 64(N), K=512 from LDS.
    int wm = (wv & 1) * 16, wn = (wv >> 1) * 64;
    f32x4v acc[4];
    #pragma unroll
    for (int j = 0; j < 4; ++j) acc[j] = (f32x4v){0.f, 0.f, 0.f, 0.f};
    #pragma unroll
    for (int ks = 0; ks < 16; ++ks) {
        short8 a = *(short8*)&Hs[(wm + l16) * 520 + ks * 32 + quad * 8];
        #pragma unroll
        for (int nt = 0; nt < 4; ++nt) {
            short8 b = *(const short8*)&w2T[(size_t)(wn + nt * 16 + l16) * 512 +
                                            ks * 32 + quad * 8];
            acc[nt] = __builtin_amdgcn_mfma_f32_16x16x32_bf16(a, b, acc[nt], 0, 0, 0);
        }
    }

    // residual add + X store + LN partials
    #pragma unroll
    for (int r = 0; r < 4; ++r) {
        int lrow = wm + quad * 4 + r;
        int row = row0 + lrow;
        float s = 0.f, ss = 0.f;
        #pragma unroll
        for (int nt = 0; nt < 4; ++nt) {
            int col = wn + nt * 16 + l16;
            size_t o = (size_t)row * DS + col;
            float v = acc[nt][r] + X[o];
            acc[nt][r] = v;
            X[o] = v;
            s += v; ss += v * v;
        }
        #pragma unroll
        for (int o2 = 1; o2 < 16; o2 <<= 1) {
            s  += __shfl_xor(s, o2);
            ss += __shfl_xor(ss, o2);
        }
        if (l16 == 0) {
            redS[lrow][(wv >> 1) * 2]     = s;
            redS[lrow][(wv >> 1) * 2 + 1] = ss;
        }
    }
    __syncthreads();

    #pragma unroll
    for (int r = 0; r < 4; ++r) {
        int lrow = wm + quad * 4 + r;
        int row = row0 + lrow;
        f32x4v rv = *(f32x4v*)&redS[lrow][0];
        float s = rv[0] + rv[2], ss = rv[1] + rv[3];
        float m = s * (1.f / 128.f);
        float var = ss * (1.f / 128.f) - m * m;
        float rs = rsqrtf(var + 1e-5f);
        #pragma unroll
        for (int nt = 0; nt < 4; ++nt) {
            int col = wn + nt * 16 + l16;
            LNb[(size_t)row * DS + col] = f2b((acc[nt][r] - m) * rs);
        }
    }
}

// ---------------------------------------------------------------------------
// Final W_out GEMM (fp32 A -> bf16 relu out), 64-row tile.
// ---------------------------------------------------------------------------
__global__ __launch_bounds__(256) void gemm_fin(
    const float* __restrict__ A, const u16* __restrict__ WT,
    u16* __restrict__ OutB, int K, int N)
{
    __shared__ __align__(16) u16 As[64 * 88];
    const int row0 = blockIdx.x * 64, n0 = blockIdx.y * 128;
    const int tid = threadIdx.x;
    const int w = tid >> 6, lane = tid & 63, quad = lane >> 4, l16 = lane & 15;
    const int wm = (w & 1) * 32, wn = (w >> 1) * 64;

    f32x4v acc[2][4];
    #pragma unroll
    for (int i = 0; i < 2; ++i)
        #pragma unroll
        for (int j = 0; j < 4; ++j) acc[i][j] = (f32x4v){0.f, 0.f, 0.f, 0.f};

    for (int k0 = 0; k0 < K; k0 += 64) {
        __syncthreads();
        #pragma unroll
        for (int it = 0; it < 4; ++it) {
            int idx = tid + it * 256;
            int r = idx >> 4, c = idx & 15;
            f32x4v v = *(const f32x4v*)(A + (size_t)(row0 + r) * K + k0 + c * 4);
            *(us4*)&As[r * 88 + c * 4] = pack4(v[0], v[1], v[2], v[3]);
        }
        __syncthreads();
        #pragma unroll
        for (int kk = 0; kk < 64; kk += 32) {
            short8 a0 = *(const short8*)&As[(wm + l16) * 88 + kk + quad * 8];
            short8 a1 = *(const short8*)&As[(wm + 16 + l16) * 88 + kk + quad * 8];
            #pragma unroll
            for (int nt = 0; nt < 4; ++nt) {
                short8 b = *(const short8*)&WT[(size_t)(n0 + wn + nt * 16 + l16) * K + k0 + kk + quad * 8];
                acc[0][nt] = __builtin_amdgcn_mfma_f32_16x16x32_bf16(a0, b, acc[0][nt], 0, 0, 0);
                acc[1][nt] = __builtin_amdgcn_mfma_f32_16x16x32_bf16(a1, b, acc[1][nt], 0, 0, 0);
            }
        }
    }
    #pragma unroll
    for (int mt = 0; mt < 2; ++mt)
        #pragma unroll
        for (int nt = 0; nt < 4; ++nt)
            #pragma unroll
            for (int r = 0; r < 4; ++r) {
                int row = row0 + wm + mt * 16 + quad * 4 + r;
                int col = n0 + wn + nt * 16 + l16;
                OutB[(size_t)row * N + col] = f2b(fmaxf(acc[mt][nt][r], 0.f));
            }
}

// ---------------------------------------------------------------------------
// Windowed attention v6 (unchanged from round 9).
// ---------------------------------------------------------------------------
__global__ __launch_bounds__(256) void attn_kernel(
    const u16* __restrict__ QKV, const u16* __restrict__ BIASb,
    u16* __restrict__ O)
{
    __shared__ __align__(16) u16 sQ[64 * 40];
    __shared__ __align__(16) u16 sK[128 * 40];
    __shared__ __align__(16) u16 sVt[32 * 152];
    __shared__ __align__(16) u16 sP[64 * 136];
    __shared__ float pmax[4][64];
    __shared__ float psum[4][64];
    __shared__ float gfac[4][64];

    int tid = threadIdx.x;
    int h = blockIdx.x & 3, w = (blockIdx.x >> 2) & 127, b = blockIdx.x >> 9;
    size_t rowbase = (size_t)b * N_ + w * QW;
    size_t bbase = ((size_t)(b * NWIN + w) * HEADS + h) * (QW * KW);
    const short8 zero8 = (short8){0, 0, 0, 0, 0, 0, 0, 0};

    {
        int r = tid >> 2, d8 = (tid & 3) * 8;
        *(short8*)&sQ[r * 40 + d8] =
            *(const short8*)&QKV[(rowbase + r) * 384 + h * DH + d8];
    }
    #pragma unroll
    for (int i = 0; i < 2; ++i) {
        int idx = tid + i * 256;
        int r = idx >> 2, d8 = (idx & 3) * 8;
        int jk = w * QW + r - PADW;
        short8 v = zero8;
        if (jk >= 0 && jk < N_)
            v = *(const short8*)&QKV[((size_t)b * N_ + jk) * 384 + 128 + h * DH + d8];
        *(short8*)&sK[r * 40 + d8] = v;
    }
    {
        int kk = tid >> 1, d0 = (tid & 1) * 16;
        int jk = w * QW + kk - PADW;
        short8 v0 = zero8, v1 = zero8;
        if (jk >= 0 && jk < N_) {
            const u16* src = &QKV[((size_t)b * N_ + jk) * 384 + 256 + h * DH + d0];
            v0 = *(const short8*)src;
            v1 = *(const short8*)(src + 8);
        }
        #pragma unroll
        for (int j = 0; j < 8; ++j) {
            sVt[(d0 + j) * 152 + kk] = (u16)v0[j];
            sVt[(d0 + 8 + j) * 152 + kk] = (u16)v1[j];
        }
    }
    #pragma unroll
    for (int i = 0; i < 4; ++i) {
        int idx = tid + i * 256;
        int q = idx >> 4, c8 = idx & 15;
        *(short8*)&sP[q * 136 + c8 * 8] =
            *(const short8*)&BIASb[bbase + (size_t)q * KW + c8 * 8];
    }
    __syncthreads();

    int wv = tid >> 6, lane = tid & 63, quad = lane >> 4, l16 = lane & 15;
    const float scale = 0.17677669529663687f;

    short8 aq[4];
    #pragma unroll
    for (int mt = 0; mt < 4; ++mt)
        aq[mt] = *(short8*)&sQ[(mt * 16 + l16) * 40 + quad * 8];
    float e[2][4][4];
    #pragma unroll
    for (int ni = 0; ni < 2; ++ni) {
        int nt = wv * 2 + ni;
        short8 bk = *(short8*)&sK[(nt * 16 + l16) * 40 + quad * 8];
        int kk = nt * 16 + l16;
        int jk = w * QW + kk - PADW;
        float msk = (jk >= 0 && jk < N_) ? 0.f : -1e9f;
        #pragma unroll
        for (int mt = 0; mt < 4; ++mt) {
            f32x4v acc = (f32x4v){0.f, 0.f, 0.f, 0.f};
            acc = __builtin_amdgcn_mfma_f32_16x16x32_bf16(aq[mt], bk, acc, 0, 0, 0);
            #pragma unroll
            for (int r = 0; r < 4; ++r) {
                int q = mt * 16 + quad * 4 + r;
                e[ni][mt][r] = acc[r] * scale + b2f(sP[q * 136 + kk]) + msk;
            }
        }
    }

    #pragma unroll
    for (int mt = 0; mt < 4; ++mt)
        #pragma unroll
        for (int r = 0; r < 4; ++r) {
            float m = fmaxf(e[0][mt][r], e[1][mt][r]);
            m = fmaxf(m, __shfl_xor(m, 1));
            m = fmaxf(m, __shfl_xor(m, 2));
            m = fmaxf(m, __shfl_xor(m, 4));
            m = fmaxf(m, __shfl_xor(m, 8));
            float e0 = __expf(e[0][mt][r] - m);
            float e1 = __expf(e[1][mt][r] - m);
            e[0][mt][r] = e0; e[1][mt][r] = e1;
            float s = e0 + e1;
            s += __shfl_xor(s, 1);
            s += __shfl_xor(s, 2);
            s += __shfl_xor(s, 4);
            s += __shfl_xor(s, 8);
            if (l16 == 0) {
                int q = mt * 16 + quad * 4 + r;
                pmax[wv][q] = m;
                psum[wv][q] = s;
            }
        }
    __syncthreads();

    if (tid < 64) {
        float m0 = pmax[0][tid], m1 = pmax[1][tid], m2 = pmax[2][tid], m3 = pmax[3][tid];
        float M = fmaxf(fmaxf(m0, m1), fmaxf(m2, m3));
        float g0 = __expf(m0 - M), g1 = __expf(m1 - M),
              g2 = __expf(m2 - M), g3 = __expf(m3 - M);
        float T = psum[0][tid] * g0 + psum[1][tid] * g1 +
                  psum[2][tid] * g2 + psum[3][tid] * g3;
        float inv = 1.f / T;
        gfac[0][tid] = g0 * inv; gfac[1][tid] = g1 * inv;
        gfac[2][tid] = g2 * inv; gfac[3][tid] = g3 * inv;
    }
    __syncthreads();

    #pragma unroll
    for (int mt = 0; mt < 4; ++mt)
        #pragma unroll
        for (int r = 0; r < 4; ++r) {
            int q = mt * 16 + quad * 4 + r;
            float f = gfac[wv][q];
            #pragma unroll
            for (int ni = 0; ni < 2; ++ni) {
                int kk = (wv * 2 + ni) * 16 + l16;
                sP[q * 136 + kk] = f2b(e[ni][mt][r] * f);
            }
        }
    __syncthreads();

    {
        int mt = wv;
        short8 ap[4];
        #pragma unroll
        for (int ks = 0; ks < 4; ++ks)
            ap[ks] = *(short8*)&sP[(mt * 16 + l16) * 136 + ks * 32 + quad * 8];
        #pragma unroll
        for (int nt = 0; nt < 2; ++nt) {
            f32x4v acc = (f32x4v){0.f, 0.f, 0.f, 0.f};
            #pragma unroll
            for (int ks = 0; ks < 4; ++ks) {
                short8 bv = *(short8*)&sVt[(nt * 16 + l16) * 152 + ks * 32 + quad * 8];
                acc = __builtin_amdgcn_mfma_f32_16x16x32_bf16(ap[ks], bv, acc, 0, 0, 0);
            }
            int d = nt * 16 + l16;
            #pragma unroll
            for (int r = 0; r < 4; ++r) {
                int q = mt * 16 + quad * 4 + r;
                O[(rowbase + q) * DS + h * DH + d] = f2b(acc[r]);
            }
        }
    }
}

// ---------------------------------------------------------------------------
// Segment mean (unchanged).
// ---------------------------------------------------------------------------
__global__ __launch_bounds__(128) void seg_kernel(
    const u16* __restrict__ TOKb, const int* __restrict__ idx,
    float* __restrict__ out)
{
    int t = blockIdx.x & (NT - 1);
    int b = blockIdx.x >> 10;
    const int* id = idx + (size_t)b * N_;

    int lo = 0, hi = N_;
    while (lo < hi) { int mid = (lo + hi) >> 1; if (id[mid] < t) lo = mid + 1; else hi = mid; }
    int start = lo;
    hi = N_;
    while (lo < hi) { int mid = (lo + hi) >> 1; if (id[mid] < t + 1) lo = mid + 1; else hi = mid; }
    int end = lo;

    float inv = 1.f / fmaxf((float)(end - start), 1.f);
    for (int c = threadIdx.x; c < DT; c += 128) {
        float s = 0.f;
        for (int r = start; r < end; ++r) s += b2f(TOKb[((size_t)b * N_ + r) * DT + c]);
        out[((size_t)b * NT + t) * DT + c] = s * inv;
    }
}

// ---------------------------------------------------------------------------
extern "C" void kernel_launch(void* const* d_in, const int* in_sizes, int n_in,
                              void* d_out, int out_size, void* d_ws, size_t ws_size,
                              hipStream_t stream)
{
    const float* ref_pos    = (const float*)d_in[0];
    const float* ref_charge = (const float*)d_in[1];
    const float* ref_mask   = (const float*)d_in[2];
    const float* ref_elem   = (const float*)d_in[3];
    const float* ref_chars  = (const float*)d_in[4];
    const float* W_single   = (const float*)d_in[5];
    const float* W_pair     = (const float*)d_in[6];
    const float* W_outer    = (const float*)d_in[7];
    const float* Wp_ff1     = (const float*)d_in[8];
    const float* Wp_ff2     = (const float*)d_in[9];
    const float* Wq         = (const float*)d_in[10];
    const float* Wk         = (const float*)d_in[11];
    const float* Wv         = (const float*)d_in[12];
    const float* Wo         = (const float*)d_in[13];
    const float* Wb         = (const float*)d_in[14];
    const float* Wff1       = (const float*)d_in[15];
    const float* Wff2       = (const float*)d_in[16];
    const float* W_out      = (const float*)d_in[17];
    const int*   uid        = (const int*)d_in[18];
    const int*   a2t        = (const int*)d_in[19];
    float* out = (float*)d_out;

    const size_t ROWS = (size_t)B_ * N_;  // 16384
    float* ws = (float*)d_ws;
    float* X    = ws;
    float* P    = X + ROWS * DS;
    u16* QKVb   = (u16*)(P + ROWS * 32);
    u16* Ob     = QKVb + ROWS * 384;
    u16* FFb    = Ob + ROWS * DS;          // unused (kept for layout stability)
    u16* BIASb  = FFb + ROWS * 512;
    u16* TOKb   = BIASb + (size_t)B_ * NWIN * HEADS * QW * KW;
    u16* LNb    = TOKb + ROWS * DT;
    u16* qkvT   = LNb + ROWS * DS;
    u16* woT    = qkvT + 3 * 384 * 128;
    u16* ff1T   = woT + 3 * 128 * 128;
    u16* ff2T   = ff1T + 3 * 512 * 128;
    u16* woutT  = ff2T + 3 * 128 * 512;
    u16* w1T32  = woutT + 384 * 128;
    u16* wcatT  = w1T32 + 64 * 32;
    u16* wsT    = wcatT + 16 * 96;
    u16* woutrT = wsT + 128 * 416;

    convw_kernel<<<768, 256, 0, stream>>>(Wq, Wk, Wv, Wo, Wff1, Wff2, W_out,
                                          Wp_ff1, Wp_ff2, Wb, W_single, W_outer,
                                          qkvT, woT, ff1T, ff2T, woutT,
                                          w1T32, wcatT, wsT, woutrT);
    embed_gemm<<<ROWS / 64, 256, 0, stream>>>(ref_pos, ref_charge, ref_mask,
                                              ref_elem, ref_chars, wsT, woutrT,
                                              X, LNb, P);
    bias_kernel<<<4096, 256, 0, stream>>>(ref_pos, uid, P, W_pair,
                                          w1T32, wcatT, BIASb);

    for (int l = 0; l < DEPTH; ++l) {
        gemm_bf<false><<<dim3(ROWS / 64, 3), 256, 0, stream>>>(
            LNb, qkvT + (size_t)l * 384 * 128, QKVb, 384);
        attn_kernel<<<B_ * NWIN * HEADS, 256, 0, stream>>>(QKVb, BIASb, Ob);
        gemm_addln<<<dim3(ROWS / 64, 1), 256, 0, stream>>>(
            Ob, woT + (size_t)l * 128 * 128, X, LNb, 128);
        ff_fused<<<ROWS / 32, 256, 0, stream>>>(
            LNb, ff1T + (size_t)l * 512 * 128, ff2T + (size_t)l * 128 * 512,
            X, LNb);
    }

    gemm_fin<<<dim3(ROWS / 64, 3), 256, 0, stream>>>(X, woutT, TOKb, DS, DT);
    seg_kernel<<<B_ * NT, 128, 0, stream>>>(TOKb, a2t, out);
}

// Round 11
// 405.587 us; speedup vs baseline: 1.2303x; 1.0934x over previous
//
#include <hip/hip_runtime.h>
#include <hip/hip_bf16.h>

#define QW 64
#define KW 128
#define PADW 32
#define DEPTH 3
#define HEADS 4
#define B_ 2
#define N_ 8192
#define DS 128
#define DP 16
#define DT 384
#define NT 1024
#define NWIN (N_ / QW)   // 128
#define DH (DS / HEADS)  // 32

typedef unsigned short u16;
typedef __attribute__((ext_vector_type(8))) short short8;
typedef __attribute__((ext_vector_type(4))) float f32x4v;
typedef __attribute__((ext_vector_type(4))) unsigned short us4;

__device__ __forceinline__ u16 f2b(float x) {
    union { float f; unsigned u; } v; v.f = x;
    unsigned r = v.u + 0x7fffu + ((v.u >> 16) & 1u);
    return (u16)(r >> 16);
}
__device__ __forceinline__ float b2f(u16 h) {
    union { unsigned u; float f; } v; v.u = ((unsigned)h) << 16; return v.f;
}
__device__ __forceinline__ unsigned f2b2(float a, float b) {
    __hip_bfloat162 h = __float22bfloat162_rn(make_float2(a, b));
    union { __hip_bfloat162 h; unsigned u; } c; c.h = h; return c.u;
}
__device__ __forceinline__ us4 pack4(float a, float b, float c, float d) {
    union { us4 v; unsigned u[2]; } o;
    o.u[0] = f2b2(a, b);
    o.u[1] = f2b2(c, d);
    return o.v;
}

// ---------------------------------------------------------------------------
// Weight prep (unchanged).
// ---------------------------------------------------------------------------
__global__ __launch_bounds__(256) void convw_kernel(
    const float* __restrict__ Wq, const float* __restrict__ Wk,
    const float* __restrict__ Wv, const float* __restrict__ Wo,
    const float* __restrict__ Wff1, const float* __restrict__ Wff2,
    const float* __restrict__ Wout, const float* __restrict__ Wpff1,
    const float* __restrict__ Wpff2, const float* __restrict__ Wb,
    const float* __restrict__ Wsingle, const float* __restrict__ Wouter,
    u16* __restrict__ qkvT, u16* __restrict__ woT, u16* __restrict__ ff1T,
    u16* __restrict__ ff2T, u16* __restrict__ woutT,
    u16* __restrict__ w1T32, u16* __restrict__ wcatT,
    u16* __restrict__ wsT, u16* __restrict__ woutrT)
{
    int idx = blockIdx.x * 256 + threadIdx.x;
    if (idx < 3 * 384 * 128) {
        int l = idx / (384 * 128), r = idx % (384 * 128);
        int n = r / 128, k = r % 128;
        const float* W = (n < 128) ? Wq : (n < 256) ? Wk : Wv;
        qkvT[idx] = f2b(W[(size_t)l * 16384 + k * 128 + (n & 127)]);
    }
    if (idx < 3 * 128 * 128) {
        int l = idx / 16384, r = idx % 16384;
        int n = r / 128, k = r % 128;
        woT[idx] = f2b(Wo[(size_t)l * 16384 + k * 128 + n]);
    }
    if (idx < 3 * 512 * 128) {
        int l = idx / 65536, r = idx % 65536;
        int n = r / 128, k = r % 128;
        ff1T[idx] = f2b(Wff1[(size_t)l * 65536 + k * 512 + n]);
    }
    if (idx < 3 * 128 * 512) {
        int l = idx / 65536, r = idx % 65536;
        int n = r / 512, k = r % 512;
        ff2T[idx] = f2b(Wff2[(size_t)l * 65536 + k * 128 + n]);
    }
    if (idx < 384 * 128) {
        int n = idx / 128, k = idx % 128;
        woutT[idx] = f2b(Wout[(size_t)k * 384 + n]);
    }
    if (idx < 64 * 32) {
        int n = idx >> 5, k = idx & 31;
        w1T32[idx] = (k < 16) ? f2b(Wpff1[k * 64 + n]) : (u16)0;
    }
    if (idx < 16 * 96) {
        int h = idx / 96, k = idx % 96;
        float s = 0.f;
        if (h < 4) {
            if (k < 16) s = Wb[k * 4 + h];
            else if (k < 80) {
                int j = k - 16;
                for (int c = 0; c < 16; ++c) s += Wpff2[j * 16 + c] * Wb[c * 4 + h];
            }
        }
        wcatT[idx] = f2b(s);
    }
    if (idx < 128 * 416) {
        int n = idx / 416, k = idx % 416;
        float v = 0.f;
        if (k < 128)       v = Wsingle[(5 + k) * 128 + n];
        else if (k < 384)  v = Wsingle[(133 + k - 128) * 128 + n];
        else if (k < 387)  v = Wsingle[(k - 384) * 128 + n];
        else if (k == 387) v = Wsingle[3 * 128 + n];
        else if (k == 388) v = Wsingle[4 * 128 + n];
        wsT[idx] = f2b(v);
    }
    if (idx < 32 * 128) {
        int n = idx >> 7, k = idx & 127;
        woutrT[idx] = f2b(Wouter[k * 32 + n]);
    }
}

// ---------------------------------------------------------------------------
// Embed GEMM + fused LN + fused P-GEMM (unchanged).
// ---------------------------------------------------------------------------
__global__ __launch_bounds__(256) void embed_gemm(
    const float* __restrict__ pos, const float* __restrict__ charge,
    const float* __restrict__ mask, const float* __restrict__ elem,
    const float* __restrict__ chars, const u16* __restrict__ wsT,
    const u16* __restrict__ woutrT,
    float* __restrict__ X, u16* __restrict__ LNb, float* __restrict__ P)
{
    __shared__ __align__(16) u16 As[64 * 424];
    __shared__ float redS[64][4];
    int tid = threadIdx.x;
    int row0 = blockIdx.x * 64;

    #pragma unroll
    for (int it = 0; it < 8; ++it) {
        int idx = tid + it * 256;
        int r = idx >> 5, c4 = idx & 31;
        f32x4v v = *(const f32x4v*)(elem + (size_t)(row0 + r) * 128 + c4 * 4);
        *(us4*)&As[r * 424 + c4 * 4] = pack4(v[0], v[1], v[2], v[3]);
    }
    #pragma unroll
    for (int it = 0; it < 16; ++it) {
        int idx = tid + it * 256;
        int r = idx >> 6, c4 = idx & 63;
        f32x4v v = *(const f32x4v*)(chars + (size_t)(row0 + r) * 256 + c4 * 4);
        *(us4*)&As[r * 424 + 128 + c4 * 4] = pack4(v[0], v[1], v[2], v[3]);
    }
    if (tid < 64) {
        int g = row0 + tid;
        As[tid * 424 + 384] = f2b(pos[g * 3]);
        As[tid * 424 + 385] = f2b(pos[g * 3 + 1]);
        As[tid * 424 + 386] = f2b(pos[g * 3 + 2]);
        As[tid * 424 + 387] = f2b(charge[g]);
        As[tid * 424 + 388] = f2b(mask[g]);
        for (int c = 389; c < 416; ++c) As[tid * 424 + c] = 0;
    }
    __syncthreads();

    int wv = tid >> 6, lane = tid & 63, quad = lane >> 4, l16 = lane & 15;
    int wm = (wv & 1) * 32, wn = (wv >> 1) * 64;
    f32x4v acc[2][4];
    #pragma unroll
    for (int i = 0; i < 2; ++i)
        #pragma unroll
        for (int j = 0; j < 4; ++j) acc[i][j] = (f32x4v){0.f, 0.f, 0.f, 0.f};

    #pragma unroll
    for (int kk = 0; kk < 13; ++kk) {
        short8 a0 = *(short8*)&As[(wm + l16) * 424 + kk * 32 + quad * 8];
        short8 a1 = *(short8*)&As[(wm + 16 + l16) * 424 + kk * 32 + quad * 8];
        #pragma unroll
        for (int nt = 0; nt < 4; ++nt) {
            short8 bw = *(const short8*)&wsT[(size_t)(wn + nt * 16 + l16) * 416 +
                                             kk * 32 + quad * 8];
            acc[0][nt] = __builtin_amdgcn_mfma_f32_16x16x32_bf16(a0, bw, acc[0][nt], 0, 0, 0);
            acc[1][nt] = __builtin_amdgcn_mfma_f32_16x16x32_bf16(a1, bw, acc[1][nt], 0, 0, 0);
        }
    }
    __syncthreads();

    #pragma unroll
    for (int mt = 0; mt < 2; ++mt) {
        #pragma unroll
        for (int r = 0; r < 4; ++r) {
            int lrow = wm + mt * 16 + quad * 4 + r;
            int row = row0 + lrow;
            float s = 0.f, ss = 0.f;
            #pragma unroll
            for (int nt = 0; nt < 4; ++nt) {
                float v = acc[mt][nt][r];
                int col = wn + nt * 16 + l16;
                X[(size_t)row * DS + col] = v;
                As[lrow * 136 + col] = f2b(fmaxf(v, 0.f));
                s += v; ss += v * v;
            }
            #pragma unroll
            for (int o = 1; o < 16; o <<= 1) {
                s  += __shfl_xor(s, o);
                ss += __shfl_xor(ss, o);
            }
            if (l16 == 0) {
                redS[lrow][(wv >> 1) * 2]     = s;
                redS[lrow][(wv >> 1) * 2 + 1] = ss;
            }
        }
    }
    __syncthreads();

    #pragma unroll
    for (int mt = 0; mt < 2; ++mt)
        #pragma unroll
        for (int r = 0; r < 4; ++r) {
            int lrow = wm + mt * 16 + quad * 4 + r;
            int row = row0 + lrow;
            f32x4v rv = *(f32x4v*)&redS[lrow][0];
            float s = rv[0] + rv[2], ss = rv[1] + rv[3];
            float m = s * (1.f / 128.f);
            float var = ss * (1.f / 128.f) - m * m;
            float rs = rsqrtf(var + 1e-5f);
            #pragma unroll
            for (int nt = 0; nt < 4; ++nt) {
                int col = wn + nt * 16 + l16;
                LNb[(size_t)row * DS + col] = f2b((acc[mt][nt][r] - m) * rs);
            }
        }

    {
        f32x4v pacc[2];
        pacc[0] = (f32x4v){0.f, 0.f, 0.f, 0.f};
        pacc[1] = (f32x4v){0.f, 0.f, 0.f, 0.f};
        #pragma unroll
        for (int ks = 0; ks < 4; ++ks) {
            short8 a = *(short8*)&As[(wv * 16 + l16) * 136 + ks * 32 + quad * 8];
            #pragma unroll
            for (int nt = 0; nt < 2; ++nt) {
                short8 bw = *(const short8*)&woutrT[(size_t)(nt * 16 + l16) * 128 +
                                                    ks * 32 + quad * 8];
                pacc[nt] = __builtin_amdgcn_mfma_f32_16x16x32_bf16(a, bw, pacc[nt], 0, 0, 0);
            }
        }
        #pragma unroll
        for (int nt = 0; nt < 2; ++nt)
            #pragma unroll
            for (int r = 0; r < 4; ++r) {
                int row = row0 + wv * 16 + quad * 4 + r;
                P[(size_t)row * 32 + nt * 16 + l16] = pacc[nt][r];
            }
    }
}

// ---------------------------------------------------------------------------
// Bias kernel v7 (unchanged).
// ---------------------------------------------------------------------------
__global__ __launch_bounds__(256) void bias_kernel(
    const float* __restrict__ pos, const int* __restrict__ uid,
    const float* __restrict__ P, const float* __restrict__ Wpair,
    const u16* __restrict__ w1T32, const u16* __restrict__ wcatT,
    u16* __restrict__ BIASb)
{
    __shared__ __align__(16) float posjS[128][4];
    __shared__ __align__(16) u16 lpS[4][16 * 24];
    __shared__ __align__(16) u16 A2S[4][16 * 104];

    int tid = threadIdx.x;
    int b  = blockIdx.x >> 11;
    int w  = (blockIdx.x >> 4) & 127;
    int qg = blockIdx.x & 15;

    if (tid < 128) {
        int r = tid;
        int jk = w * QW + r - PADW;
        bool valid = (jk >= 0) && (jk < N_);
        int gk = b * N_ + jk;
        float x = 0.f, y = 0.f, zz = 0.f; int u = 0;
        if (valid) { x = pos[gk * 3]; y = pos[gk * 3 + 1]; zz = pos[gk * 3 + 2]; u = uid[gk]; }
        posjS[r][0] = x; posjS[r][1] = y; posjS[r][2] = zz;
        ((int*)posjS[r])[3] = u;
    }

    int wv = tid >> 6, lane = tid & 63, quad = lane >> 4, l16 = lane & 15;
    int cl = lane >> 2, cg = lane & 3;
    int q = qg * 4 + wv;
    int gq = b * N_ + w * QW + q;

    float xi = pos[gq * 3], yi = pos[gq * 3 + 1], zi = pos[gq * 3 + 2];
    int ui = uid[gq];
    f32x4v pi4 = *(const f32x4v*)(P + (size_t)gq * 32 + cg * 4);
    f32x4v wp[5];
    #pragma unroll
    for (int f = 0; f < 5; ++f)
        wp[f] = *(const f32x4v*)(Wpair + f * 16 + cg * 4);
    short8 w1f[4], wcat[3];
    #pragma unroll
    for (int nt = 0; nt < 4; ++nt)
        w1f[nt] = *(const short8*)&w1T32[(nt * 16 + l16) * 32 + quad * 8];
    #pragma unroll
    for (int ks = 0; ks < 3; ++ks)
        wcat[ks] = *(const short8*)&wcatT[l16 * 96 + ks * 32 + quad * 8];

    f32x4v pjv[8];
    #pragma unroll
    for (int t = 0; t < 8; ++t) {
        int jk = w * QW + t * 16 + cl - PADW;
        bool valid = (jk >= 0) && (jk < N_);
        int gk = b * N_ + jk;
        f32x4v v = (f32x4v){0.f, 0.f, 0.f, 0.f};
        if (valid) v = *(const f32x4v*)(P + (size_t)gk * 32 + 16 + cg * 4);
        pjv[t] = v;
    }

    *(us4*)&A2S[wv][l16 * 104 + 80 + quad * 4] = (us4){0, 0, 0, 0};
    __syncthreads();

    size_t bbase = ((size_t)(b * NWIN + w) * HEADS) * (QW * KW);
    const short8 zero8 = (short8){0, 0, 0, 0, 0, 0, 0, 0};

    for (int t = 0; t < 8; ++t) {
        int kk1 = t * 16 + cl;
        float xj = posjS[kk1][0], yj = posjS[kk1][1], zj = posjS[kk1][2];
        int uj = ((int*)posjS[kk1])[3];
        float dx = xi - xj, dy = yi - yj, dz = zi - zj;
        float inv = 1.f / (1.f + dx * dx + dy * dy + dz * dz);
        float bf = (ui == uj) ? 1.f : 0.f;
        float pr[4];
        #pragma unroll
        for (int j = 0; j < 4; ++j) {
            float s = fmaf(dx, wp[0][j], fmaf(dy, wp[1][j],
                      fmaf(dz, wp[2][j], fmaf(inv, wp[3][j], wp[4][j]))));
            pr[j] = fmaf(bf, s, pi4[j] + pjv[t][j]);
        }
        float sum = pr[0] + pr[1] + pr[2] + pr[3];
        sum += __shfl_xor(sum, 1); sum += __shfl_xor(sum, 2);
        float m = sum * (1.f / 16.f);
        float d0 = pr[0] - m, d1 = pr[1] - m, d2 = pr[2] - m, d3 = pr[3] - m;
        float vs = d0 * d0 + d1 * d1 + d2 * d2 + d3 * d3;
        vs += __shfl_xor(vs, 1); vs += __shfl_xor(vs, 2);
        float rstd = rsqrtf(vs * (1.f / 16.f) + 1e-5f);
        *(us4*)&lpS[wv][cl * 24 + cg * 4] =
            pack4(d0 * rstd, d1 * rstd, d2 * rstd, d3 * rstd);
        *(us4*)&A2S[wv][cl * 104 + cg * 4] = pack4(pr[0], pr[1], pr[2], pr[3]);

        short8 blp = zero8;
        if (quad < 2) blp = *(short8*)&lpS[wv][l16 * 24 + quad * 8];
        #pragma unroll
        for (int nt = 0; nt < 4; ++nt) {
            f32x4v z4 = (f32x4v){0.f, 0.f, 0.f, 0.f};
            z4 = __builtin_amdgcn_mfma_f32_16x16x32_bf16(w1f[nt], blp, z4, 0, 0, 0);
            *(us4*)&A2S[wv][l16 * 104 + 16 + nt * 16 + quad * 4] =
                pack4(fmaxf(z4[0], 0.f), fmaxf(z4[1], 0.f),
                      fmaxf(z4[2], 0.f), fmaxf(z4[3], 0.f));
        }
        f32x4v acc = (f32x4v){0.f, 0.f, 0.f, 0.f};
        #pragma unroll
        for (int ks = 0; ks < 3; ++ks) {
            short8 a2 = *(short8*)&A2S[wv][l16 * 104 + ks * 32 + quad * 8];
            acc = __builtin_amdgcn_mfma_f32_16x16x32_bf16(a2, wcat[ks], acc, 0, 0, 0);
        }
        if (l16 < 4) {
            *(us4*)&BIASb[bbase + (size_t)l16 * (QW * KW) + q * KW +
                          t * 16 + quad * 4] = pack4(acc[0], acc[1], acc[2], acc[3]);
        }
    }
}

// ---------------------------------------------------------------------------
// Plain bf16-A GEMM (K=128), 64-row tile — QKV.
// ---------------------------------------------------------------------------
template <bool RELU>
__global__ __launch_bounds__(256) void gemm_bf(
    const u16* __restrict__ A, const u16* __restrict__ WT,
    u16* __restrict__ OutB, int N)
{
    __shared__ __align__(16) u16 As[64 * 136];
    int tid = threadIdx.x;
    int row0 = blockIdx.x * 64, n0 = blockIdx.y * 128;

    #pragma unroll
    for (int it = 0; it < 4; ++it) {
        int idx = tid + it * 256;
        int r = idx >> 4, c8 = idx & 15;
        *(short8*)&As[r * 136 + c8 * 8] =
            *(const short8*)&A[(size_t)(row0 + r) * 128 + c8 * 8];
    }
    __syncthreads();

    int wv = tid >> 6, lane = tid & 63, quad = lane >> 4, l16 = lane & 15;
    int wm = (wv & 1) * 32, wn = (wv >> 1) * 64;
    f32x4v acc[2][4];
    #pragma unroll
    for (int i = 0; i < 2; ++i)
        #pragma unroll
        for (int j = 0; j < 4; ++j) acc[i][j] = (f32x4v){0.f, 0.f, 0.f, 0.f};

    #pragma unroll
    for (int kk = 0; kk < 4; ++kk) {
        short8 a0 = *(short8*)&As[(wm + l16) * 136 + kk * 32 + quad * 8];
        short8 a1 = *(short8*)&As[(wm + 16 + l16) * 136 + kk * 32 + quad * 8];
        #pragma unroll
        for (int nt = 0; nt < 4; ++nt) {
            short8 bw = *(const short8*)&WT[(size_t)(n0 + wn + nt * 16 + l16) * 128 +
                                            kk * 32 + quad * 8];
            acc[0][nt] = __builtin_amdgcn_mfma_f32_16x16x32_bf16(a0, bw, acc[0][nt], 0, 0, 0);
            acc[1][nt] = __builtin_amdgcn_mfma_f32_16x16x32_bf16(a1, bw, acc[1][nt], 0, 0, 0);
        }
    }
    #pragma unroll
    for (int mt = 0; mt < 2; ++mt)
        #pragma unroll
        for (int nt = 0; nt < 4; ++nt)
            #pragma unroll
            for (int r = 0; r < 4; ++r) {
                int row = row0 + wm + mt * 16 + quad * 4 + r;
                int col = n0 + wn + nt * 16 + l16;
                float v = acc[mt][nt][r];
                if (RELU) v = fmaxf(v, 0.f);
                OutB[(size_t)row * N + col] = f2b(v);
            }
}

// ---------------------------------------------------------------------------
// wo_ff_fused: X += Ob@Wo; h=LN -> (LDS) -> X += relu(h@W1)@W2; LNb=LN(X).
// 32-row blocks (512). One X read, one X write, no intermediate LNb in HBM.
// ---------------------------------------------------------------------------
__global__ __launch_bounds__(256) void wo_ff_fused(
    const u16* __restrict__ Ob, const u16* __restrict__ woT,
    const u16* __restrict__ w1T, const u16* __restrict__ w2T,
    float* __restrict__ X, u16* __restrict__ LNb)
{
    __shared__ __align__(16) u16 As[32 * 136];   // Ob tile, then LN tile
    __shared__ __align__(16) u16 Hs[32 * 520];   // FF hidden
    __shared__ float redS[32][4];
    int tid = threadIdx.x;
    int row0 = blockIdx.x * 32;
    int wv = tid >> 6, lane = tid & 63, quad = lane >> 4, l16 = lane & 15;
    int wm = (wv & 1) * 16, wn = (wv >> 1) * 64;

    // stage Ob
    #pragma unroll
    for (int it = 0; it < 2; ++it) {
        int idx = tid + it * 256;
        int r = idx >> 4, c8 = idx & 15;
        *(short8*)&As[r * 136 + c8 * 8] =
            *(const short8*)&Ob[(size_t)(row0 + r) * 128 + c8 * 8];
    }
    __syncthreads();

    // WO GEMM (K=128)
    f32x4v acc[4];
    #pragma unroll
    for (int j = 0; j < 4; ++j) acc[j] = (f32x4v){0.f, 0.f, 0.f, 0.f};
    #pragma unroll
    for (int ks = 0; ks < 4; ++ks) {
        short8 a = *(short8*)&As[(wm + l16) * 136 + ks * 32 + quad * 8];
        #pragma unroll
        for (int nt = 0; nt < 4; ++nt) {
            short8 b = *(const short8*)&woT[(size_t)(wn + nt * 16 + l16) * 128 +
                                            ks * 32 + quad * 8];
            acc[nt] = __builtin_amdgcn_mfma_f32_16x16x32_bf16(a, b, acc[nt], 0, 0, 0);
        }
    }
    __syncthreads();  // all waves done reading As

    // residual add (X read once; xv stays in acc) + LN partials
    #pragma unroll
    for (int r = 0; r < 4; ++r) {
        int lrow = wm + quad * 4 + r;
        int row = row0 + lrow;
        float s = 0.f, ss = 0.f;
        #pragma unroll
        for (int nt = 0; nt < 4; ++nt) {
            int col = wn + nt * 16 + l16;
            float v = acc[nt][r] + X[(size_t)row * DS + col];
            acc[nt][r] = v;
            s += v; ss += v * v;
        }
        #pragma unroll
        for (int o2 = 1; o2 < 16; o2 <<= 1) {
            s  += __shfl_xor(s, o2);
            ss += __shfl_xor(ss, o2);
        }
        if (l16 == 0) {
            redS[lrow][(wv >> 1) * 2]     = s;
            redS[lrow][(wv >> 1) * 2 + 1] = ss;
        }
    }
    __syncthreads();

    // LN -> As (bf16, in-LDS handoff to FF1; no global write)
    #pragma unroll
    for (int r = 0; r < 4; ++r) {
        int lrow = wm + quad * 4 + r;
        f32x4v rv = *(f32x4v*)&redS[lrow][0];
        float s = rv[0] + rv[2], ss = rv[1] + rv[3];
        float m = s * (1.f / 128.f);
        float var = ss * (1.f / 128.f) - m * m;
        float rs = rsqrtf(var + 1e-5f);
        #pragma unroll
        for (int nt = 0; nt < 4; ++nt) {
            int col = wn + nt * 16 + l16;
            As[lrow * 136 + col] = f2b((acc[nt][r] - m) * rs);
        }
    }
    __syncthreads();

    // FF1 (swapped operands): hidden -> Hs
    {
        short8 brow[2][4];
        #pragma unroll
        for (int nt = 0; nt < 2; ++nt)
            #pragma unroll
            for (int ks = 0; ks < 4; ++ks)
                brow[nt][ks] = *(short8*)&As[(nt * 16 + l16) * 136 + ks * 32 + quad * 8];
        #pragma unroll
        for (int mt = 0; mt < 8; ++mt) {
            int j0 = wv * 128 + mt * 16;
            f32x4v c0 = (f32x4v){0.f, 0.f, 0.f, 0.f};
            f32x4v c1 = (f32x4v){0.f, 0.f, 0.f, 0.f};
            #pragma unroll
            for (int ks = 0; ks < 4; ++ks) {
                short8 aw = *(const short8*)&w1T[(size_t)(j0 + l16) * 128 +
                                                 ks * 32 + quad * 8];
                c0 = __builtin_amdgcn_mfma_f32_16x16x32_bf16(aw, brow[0][ks], c0, 0, 0, 0);
                c1 = __builtin_amdgcn_mfma_f32_16x16x32_bf16(aw, brow[1][ks], c1, 0, 0, 0);
            }
            *(us4*)&Hs[l16 * 520 + j0 + quad * 4] =
                pack4(fmaxf(c0[0], 0.f), fmaxf(c0[1], 0.f),
                      fmaxf(c0[2], 0.f), fmaxf(c0[3], 0.f));
            *(us4*)&Hs[(16 + l16) * 520 + j0 + quad * 4] =
                pack4(fmaxf(c1[0], 0.f), fmaxf(c1[1], 0.f),
                      fmaxf(c1[2], 0.f), fmaxf(c1[3], 0.f));
        }
    }
    __syncthreads();

    // FF2 (K=512 from LDS)
    f32x4v acc2[4];
    #pragma unroll
    for (int j = 0; j < 4; ++j) acc2[j] = (f32x4v){0.f, 0.f, 0.f, 0.f};
    #pragma unroll
    for (int ks = 0; ks < 16; ++ks) {
        short8 a = *(short8*)&Hs[(wm + l16) * 520 + ks * 32 + quad * 8];
        #pragma unroll
        for (int nt = 0; nt < 4; ++nt) {
            short8 b = *(const short8*)&w2T[(size_t)(wn + nt * 16 + l16) * 512 +
                                            ks * 32 + quad * 8];
            acc2[nt] = __builtin_amdgcn_mfma_f32_16x16x32_bf16(a, b, acc2[nt], 0, 0, 0);
        }
    }

    // residual (register-resident xv) + X write + LN partials
    #pragma unroll
    for (int r = 0; r < 4; ++r) {
        int lrow = wm + quad * 4 + r;
        int row = row0 + lrow;
        float s = 0.f, ss = 0.f;
        #pragma unroll
        for (int nt = 0; nt < 4; ++nt) {
            int col = wn + nt * 16 + l16;
            float v = acc2[nt][r] + acc[nt][r];
            acc2[nt][r] = v;
            X[(size_t)row * DS + col] = v;
            s += v; ss += v * v;
        }
        #pragma unroll
        for (int o2 = 1; o2 < 16; o2 <<= 1) {
            s  += __shfl_xor(s, o2);
            ss += __shfl_xor(ss, o2);
        }
        if (l16 == 0) {
            redS[lrow][(wv >> 1) * 2]     = s;
            redS[lrow][(wv >> 1) * 2 + 1] = ss;
        }
    }
    __syncthreads();

    #pragma unroll
    for (int r = 0; r < 4; ++r) {
        int lrow = wm + quad * 4 + r;
        int row = row0 + lrow;
        f32x4v rv = *(f32x4v*)&redS[lrow][0];
        float s = rv[0] + rv[2], ss = rv[1] + rv[3];
        float m = s * (1.f / 128.f);
        float var = ss * (1.f / 128.f) - m * m;
        float rs = rsqrtf(var + 1e-5f);
        #pragma unroll
        for (int nt = 0; nt < 4; ++nt) {
            int col = wn + nt * 16 + l16;
            LNb[(size_t)row * DS + col] = f2b((acc2[nt][r] - m) * rs);
        }
    }
}

// ---------------------------------------------------------------------------
// Final W_out GEMM (fp32 A -> bf16 relu out), 64-row tile.
// ---------------------------------------------------------------------------
__global__ __launch_bounds__(256) void gemm_fin(
    const float* __restrict__ A, const u16* __restrict__ WT,
    u16* __restrict__ OutB, int K, int N)
{
    __shared__ __align__(16) u16 As[64 * 88];
    const int row0 = blockIdx.x * 64, n0 = blockIdx.y * 128;
    const int tid = threadIdx.x;
    const int w = tid >> 6, lane = tid & 63, quad = lane >> 4, l16 = lane & 15;
    const int wm = (w & 1) * 32, wn = (w >> 1) * 64;

    f32x4v acc[2][4];
    #pragma unroll
    for (int i = 0; i < 2; ++i)
        #pragma unroll
        for (int j = 0; j < 4; ++j) acc[i][j] = (f32x4v){0.f, 0.f, 0.f, 0.f};

    for (int k0 = 0; k0 < K; k0 += 64) {
        __syncthreads();
        #pragma unroll
        for (int it = 0; it < 4; ++it) {
            int idx = tid + it * 256;
            int r = idx >> 4, c = idx & 15;
            f32x4v v = *(const f32x4v*)(A + (size_t)(row0 + r) * K + k0 + c * 4);
            *(us4*)&As[r * 88 + c * 4] = pack4(v[0], v[1], v[2], v[3]);
        }
        __syncthreads();
        #pragma unroll
        for (int kk = 0; kk < 64; kk += 32) {
            short8 a0 = *(const short8*)&As[(wm + l16) * 88 + kk + quad * 8];
            short8 a1 = *(const short8*)&As[(wm + 16 + l16) * 88 + kk + quad * 8];
            #pragma unroll
            for (int nt = 0; nt < 4; ++nt) {
                short8 b = *(const short8*)&WT[(size_t)(n0 + wn + nt * 16 + l16) * K + k0 + kk + quad * 8];
                acc[0][nt] = __builtin_amdgcn_mfma_f32_16x16x32_bf16(a0, b, acc[0][nt], 0, 0, 0);
                acc[1][nt] = __builtin_amdgcn_mfma_f32_16x16x32_bf16(a1, b, acc[1][nt], 0, 0, 0);
            }
        }
    }
    #pragma unroll
    for (int mt = 0; mt < 2; ++mt)
        #pragma unroll
        for (int nt = 0; nt < 4; ++nt)
            #pragma unroll
            for (int r = 0; r < 4; ++r) {
                int row = row0 + wm + mt * 16 + quad * 4 + r;
                int col = n0 + wn + nt * 16 + l16;
                OutB[(size_t)row * N + col] = f2b(fmaxf(acc[mt][nt][r], 0.f));
            }
}

// ---------------------------------------------------------------------------
// Windowed attention v6 (unchanged).
// ---------------------------------------------------------------------------
__global__ __launch_bounds__(256) void attn_kernel(
    const u16* __restrict__ QKV, const u16* __restrict__ BIASb,
    u16* __restrict__ O)
{
    __shared__ __align__(16) u16 sQ[64 * 40];
    __shared__ __align__(16) u16 sK[128 * 40];
    __shared__ __align__(16) u16 sVt[32 * 152];
    __shared__ __align__(16) u16 sP[64 * 136];
    __shared__ float pmax[4][64];
    __shared__ float psum[4][64];
    __shared__ float gfac[4][64];

    int tid = threadIdx.x;
    int h = blockIdx.x & 3, w = (blockIdx.x >> 2) & 127, b = blockIdx.x >> 9;
    size_t rowbase = (size_t)b * N_ + w * QW;
    size_t bbase = ((size_t)(b * NWIN + w) * HEADS + h) * (QW * KW);
    const short8 zero8 = (short8){0, 0, 0, 0, 0, 0, 0, 0};

    {
        int r = tid >> 2, d8 = (tid & 3) * 8;
        *(short8*)&sQ[r * 40 + d8] =
            *(const short8*)&QKV[(rowbase + r) * 384 + h * DH + d8];
    }
    #pragma unroll
    for (int i = 0; i < 2; ++i) {
        int idx = tid + i * 256;
        int r = idx >> 2, d8 = (idx & 3) * 8;
        int jk = w * QW + r - PADW;
        short8 v = zero8;
        if (jk >= 0 && jk < N_)
            v = *(const short8*)&QKV[((size_t)b * N_ + jk) * 384 + 128 + h * DH + d8];
        *(short8*)&sK[r * 40 + d8] = v;
    }
    {
        int kk = tid >> 1, d0 = (tid & 1) * 16;
        int jk = w * QW + kk - PADW;
        short8 v0 = zero8, v1 = zero8;
        if (jk >= 0 && jk < N_) {
            const u16* src = &QKV[((size_t)b * N_ + jk) * 384 + 256 + h * DH + d0];
            v0 = *(const short8*)src;
            v1 = *(const short8*)(src + 8);
        }
        #pragma unroll
        for (int j = 0; j < 8; ++j) {
            sVt[(d0 + j) * 152 + kk] = (u16)v0[j];
            sVt[(d0 + 8 + j) * 152 + kk] = (u16)v1[j];
        }
    }
    #pragma unroll
    for (int i = 0; i < 4; ++i) {
        int idx = tid + i * 256;
        int q = idx >> 4, c8 = idx & 15;
        *(short8*)&sP[q * 136 + c8 * 8] =
            *(const short8*)&BIASb[bbase + (size_t)q * KW + c8 * 8];
    }
    __syncthreads();

    int wv = tid >> 6, lane = tid & 63, quad = lane >> 4, l16 = lane & 15;
    const float scale = 0.17677669529663687f;

    short8 aq[4];
    #pragma unroll
    for (int mt = 0; mt < 4; ++mt)
        aq[mt] = *(short8*)&sQ[(mt * 16 + l16) * 40 + quad * 8];
    float e[2][4][4];
    #pragma unroll
    for (int ni = 0; ni < 2; ++ni) {
        int nt = wv * 2 + ni;
        short8 bk = *(short8*)&sK[(nt * 16 + l16) * 40 + quad * 8];
        int kk = nt * 16 + l16;
        int jk = w * QW + kk - PADW;
        float msk = (jk >= 0 && jk < N_) ? 0.f : -1e9f;
        #pragma unroll
        for (int mt = 0; mt < 4; ++mt) {
            f32x4v acc = (f32x4v){0.f, 0.f, 0.f, 0.f};
            acc = __builtin_amdgcn_mfma_f32_16x16x32_bf16(aq[mt], bk, acc, 0, 0, 0);
            #pragma unroll
            for (int r = 0; r < 4; ++r) {
                int q = mt * 16 + quad * 4 + r;
                e[ni][mt][r] = acc[r] * scale + b2f(sP[q * 136 + kk]) + msk;
            }
        }
    }

    #pragma unroll
    for (int mt = 0; mt < 4; ++mt)
        #pragma unroll
        for (int r = 0; r < 4; ++r) {
            float m = fmaxf(e[0][mt][r], e[1][mt][r]);
            m = fmaxf(m, __shfl_xor(m, 1));
            m = fmaxf(m, __shfl_xor(m, 2));
            m = fmaxf(m, __shfl_xor(m, 4));
            m = fmaxf(m, __shfl_xor(m, 8));
            float e0 = __expf(e[0][mt][r] - m);
            float e1 = __expf(e[1][mt][r] - m);
            e[0][mt][r] = e0; e[1][mt][r] = e1;
            float s = e0 + e1;
            s += __shfl_xor(s, 1);
            s += __shfl_xor(s, 2);
            s += __shfl_xor(s, 4);
            s += __shfl_xor(s, 8);
            if (l16 == 0) {
                int q = mt * 16 + quad * 4 + r;
                pmax[wv][q] = m;
                psum[wv][q] = s;
            }
        }
    __syncthreads();

    if (tid < 64) {
        float m0 = pmax[0][tid], m1 = pmax[1][tid], m2 = pmax[2][tid], m3 = pmax[3][tid];
        float M = fmaxf(fmaxf(m0, m1), fmaxf(m2, m3));
        float g0 = __expf(m0 - M), g1 = __expf(m1 - M),
              g2 = __expf(m2 - M), g3 = __expf(m3 - M);
        float T = psum[0][tid] * g0 + psum[1][tid] * g1 +
                  psum[2][tid] * g2 + psum[3][tid] * g3;
        float inv = 1.f / T;
        gfac[0][tid] = g0 * inv; gfac[1][tid] = g1 * inv;
        gfac[2][tid] = g2 * inv; gfac[3][tid] = g3 * inv;
    }
    __syncthreads();

    #pragma unroll
    for (int mt = 0; mt < 4; ++mt)
        #pragma unroll
        for (int r = 0; r < 4; ++r) {
            int q = mt * 16 + quad * 4 + r;
            float f = gfac[wv][q];
            #pragma unroll
            for (int ni = 0; ni < 2; ++ni) {
                int kk = (wv * 2 + ni) * 16 + l16;
                sP[q * 136 + kk] = f2b(e[ni][mt][r] * f);
            }
        }
    __syncthreads();

    {
        int mt = wv;
        short8 ap[4];
        #pragma unroll
        for (int ks = 0; ks < 4; ++ks)
            ap[ks] = *(short8*)&sP[(mt * 16 + l16) * 136 + ks * 32 + quad * 8];
        #pragma unroll
        for (int nt = 0; nt < 2; ++nt) {
            f32x4v acc = (f32x4v){0.f, 0.f, 0.f, 0.f};
            #pragma unroll
            for (int ks = 0; ks < 4; ++ks) {
                short8 bv = *(short8*)&sVt[(nt * 16 + l16) * 152 + ks * 32 + quad * 8];
                acc = __builtin_amdgcn_mfma_f32_16x16x32_bf16(ap[ks], bv, acc, 0, 0, 0);
            }
            int d = nt * 16 + l16;
            #pragma unroll
            for (int r = 0; r < 4; ++r) {
                int q = mt * 16 + quad * 4 + r;
                O[(rowbase + q) * DS + h * DH + d] = f2b(acc[r]);
            }
        }
    }
}

// ---------------------------------------------------------------------------
// Segment mean (unchanged).
// ---------------------------------------------------------------------------
__global__ __launch_bounds__(128) void seg_kernel(
    const u16* __restrict__ TOKb, const int* __restrict__ idx,
    float* __restrict__ out)
{
    int t = blockIdx.x & (NT - 1);
    int b = blockIdx.x >> 10;
    const int* id = idx + (size_t)b * N_;

    int lo = 0, hi = N_;
    while (lo < hi) { int mid = (lo + hi) >> 1; if (id[mid] < t) lo = mid + 1; else hi = mid; }
    int start = lo;
    hi = N_;
    while (lo < hi) { int mid = (lo + hi) >> 1; if (id[mid] < t + 1) lo = mid + 1; else hi = mid; }
    int end = lo;

    float inv = 1.f / fmaxf((float)(end - start), 1.f);
    for (int c = threadIdx.x; c < DT; c += 128) {
        float s = 0.f;
        for (int r = start; r < end; ++r) s += b2f(TOKb[((size_t)b * N_ + r) * DT + c]);
        out[((size_t)b * NT + t) * DT + c] = s * inv;
    }
}

// ---------------------------------------------------------------------------
extern "C" void kernel_launch(void* const* d_in, const int* in_sizes, int n_in,
                              void* d_out, int out_size, void* d_ws, size_t ws_size,
                              hipStream_t stream)
{
    const float* ref_pos    = (const float*)d_in[0];
    const float* ref_charge = (const float*)d_in[1];
    const float* ref_mask   = (const float*)d_in[2];
    const float* ref_elem   = (const float*)d_in[3];
    const float* ref_chars  = (const float*)d_in[4];
    const float* W_single   = (const float*)d_in[5];
    const float* W_pair     = (const float*)d_in[6];
    const float* W_outer    = (const float*)d_in[7];
    const float* Wp_ff1     = (const float*)d_in[8];
    const float* Wp_ff2     = (const float*)d_in[9];
    const float* Wq         = (const float*)d_in[10];
    const float* Wk         = (const float*)d_in[11];
    const float* Wv         = (const float*)d_in[12];
    const float* Wo         = (const float*)d_in[13];
    const float* Wb         = (const float*)d_in[14];
    const float* Wff1       = (const float*)d_in[15];
    const float* Wff2       = (const float*)d_in[16];
    const float* W_out      = (const float*)d_in[17];
    const int*   uid        = (const int*)d_in[18];
    const int*   a2t        = (const int*)d_in[19];
    float* out = (float*)d_out;

    const size_t ROWS = (size_t)B_ * N_;  // 16384
    float* ws = (float*)d_ws;
    float* X    = ws;
    float* P    = X + ROWS * DS;
    u16* QKVb   = (u16*)(P + ROWS * 32);
    u16* Ob     = QKVb + ROWS * 384;
    u16* FFb    = Ob + ROWS * DS;          // unused (layout stability)
    u16* BIASb  = FFb + ROWS * 512;
    u16* TOKb   = BIASb + (size_t)B_ * NWIN * HEADS * QW * KW;
    u16* LNb    = TOKb + ROWS * DT;
    u16* qkvT   = LNb + ROWS * DS;
    u16* woT    = qkvT + 3 * 384 * 128;
    u16* ff1T   = woT + 3 * 128 * 128;
    u16* ff2T   = ff1T + 3 * 512 * 128;
    u16* woutT  = ff2T + 3 * 128 * 512;
    u16* w1T32  = woutT + 384 * 128;
    u16* wcatT  = w1T32 + 64 * 32;
    u16* wsT    = wcatT + 16 * 96;
    u16* woutrT = wsT + 128 * 416;

    convw_kernel<<<768, 256, 0, stream>>>(Wq, Wk, Wv, Wo, Wff1, Wff2, W_out,
                                          Wp_ff1, Wp_ff2, Wb, W_single, W_outer,
                                          qkvT, woT, ff1T, ff2T, woutT,
                                          w1T32, wcatT, wsT, woutrT);
    embed_gemm<<<ROWS / 64, 256, 0, stream>>>(ref_pos, ref_charge, ref_mask,
                                              ref_elem, ref_chars, wsT, woutrT,
                                              X, LNb, P);
    bias_kernel<<<4096, 256, 0, stream>>>(ref_pos, uid, P, W_pair,
                                          w1T32, wcatT, BIASb);

    for (int l = 0; l < DEPTH; ++l) {
        gemm_bf<false><<<dim3(ROWS / 64, 3), 256, 0, stream>>>(
            LNb, qkvT + (size_t)l * 384 * 128, QKVb, 384);
        attn_kernel<<<B_ * NWIN * HEADS, 256, 0, stream>>>(QKVb, BIASb, Ob);
        wo_ff_fused<<<ROWS / 32, 256, 0, stream>>>(
            Ob, woT + (size_t)l * 128 * 128,
            ff1T + (size_t)l * 512 * 128, ff2T + (size_t)l * 128 * 512,
            X, LNb);
    }

    gemm_fin<<<dim3(ROWS / 64, 3), 256, 0, stream>>>(X, woutT, TOKb, DS, DT);
    seg_kernel<<<B_ * NT, 128, 0, stream>>>(TOKb, a2t, out);
}

// Round 12
// 405.091 us; speedup vs baseline: 1.2318x; 1.0012x over previous
//
#include <hip/hip_runtime.h>
#include <hip/hip_bf16.h>

#define QW 64
#define KW 128
#define PADW 32
#define DEPTH 3
#define HEADS 4
#define B_ 2
#define N_ 8192
#define DS 128
#define DP 16
#define DT 384
#define NT 1024
#define NWIN (N_ / QW)   // 128
#define DH (DS / HEADS)  // 32

typedef unsigned short u16;
typedef __attribute__((ext_vector_type(8))) short short8;
typedef __attribute__((ext_vector_type(4))) float f32x4v;
typedef __attribute__((ext_vector_type(4))) unsigned short us4;

__device__ __forceinline__ u16 f2b(float x) {
    union { float f; unsigned u; } v; v.f = x;
    unsigned r = v.u + 0x7fffu + ((v.u >> 16) & 1u);
    return (u16)(r >> 16);
}
__device__ __forceinline__ float b2f(u16 h) {
    union { unsigned u; float f; } v; v.u = ((unsigned)h) << 16; return v.f;
}
__device__ __forceinline__ unsigned f2b2(float a, float b) {
    __hip_bfloat162 h = __float22bfloat162_rn(make_float2(a, b));
    union { __hip_bfloat162 h; unsigned u; } c; c.h = h; return c.u;
}
__device__ __forceinline__ us4 pack4(float a, float b, float c, float d) {
    union { us4 v; unsigned u[2]; } o;
    o.u[0] = f2b2(a, b);
    o.u[1] = f2b2(c, d);
    return o.v;
}

// ---------------------------------------------------------------------------
// Weight prep (unchanged).
// ---------------------------------------------------------------------------
__global__ __launch_bounds__(256) void convw_kernel(
    const float* __restrict__ Wq, const float* __restrict__ Wk,
    const float* __restrict__ Wv, const float* __restrict__ Wo,
    const float* __restrict__ Wff1, const float* __restrict__ Wff2,
    const float* __restrict__ Wout, const float* __restrict__ Wpff1,
    const float* __restrict__ Wpff2, const float* __restrict__ Wb,
    const float* __restrict__ Wsingle, const float* __restrict__ Wouter,
    u16* __restrict__ qkvT, u16* __restrict__ woT, u16* __restrict__ ff1T,
    u16* __restrict__ ff2T, u16* __restrict__ woutT,
    u16* __restrict__ w1T32, u16* __restrict__ wcatT,
    u16* __restrict__ wsT, u16* __restrict__ woutrT)
{
    int idx = blockIdx.x * 256 + threadIdx.x;
    if (idx < 3 * 384 * 128) {
        int l = idx / (384 * 128), r = idx % (384 * 128);
        int n = r / 128, k = r % 128;
        const float* W = (n < 128) ? Wq : (n < 256) ? Wk : Wv;
        qkvT[idx] = f2b(W[(size_t)l * 16384 + k * 128 + (n & 127)]);
    }
    if (idx < 3 * 128 * 128) {
        int l = idx / 16384, r = idx % 16384;
        int n = r / 128, k = r % 128;
        woT[idx] = f2b(Wo[(size_t)l * 16384 + k * 128 + n]);
    }
    if (idx < 3 * 512 * 128) {
        int l = idx / 65536, r = idx % 65536;
        int n = r / 128, k = r % 128;
        ff1T[idx] = f2b(Wff1[(size_t)l * 65536 + k * 512 + n]);
    }
    if (idx < 3 * 128 * 512) {
        int l = idx / 65536, r = idx % 65536;
        int n = r / 512, k = r % 512;
        ff2T[idx] = f2b(Wff2[(size_t)l * 65536 + k * 128 + n]);
    }
    if (idx < 384 * 128) {
        int n = idx / 128, k = idx % 128;
        woutT[idx] = f2b(Wout[(size_t)k * 384 + n]);
    }
    if (idx < 64 * 32) {
        int n = idx >> 5, k = idx & 31;
        w1T32[idx] = (k < 16) ? f2b(Wpff1[k * 64 + n]) : (u16)0;
    }
    if (idx < 16 * 96) {
        int h = idx / 96, k = idx % 96;
        float s = 0.f;
        if (h < 4) {
            if (k < 16) s = Wb[k * 4 + h];
            else if (k < 80) {
                int j = k - 16;
                for (int c = 0; c < 16; ++c) s += Wpff2[j * 16 + c] * Wb[c * 4 + h];
            }
        }
        wcatT[idx] = f2b(s);
    }
    if (idx < 128 * 416) {
        int n = idx / 416, k = idx % 416;
        float v = 0.f;
        if (k < 128)       v = Wsingle[(5 + k) * 128 + n];
        else if (k < 384)  v = Wsingle[(133 + k - 128) * 128 + n];
        else if (k < 387)  v = Wsingle[(k - 384) * 128 + n];
        else if (k == 387) v = Wsingle[3 * 128 + n];
        else if (k == 388) v = Wsingle[4 * 128 + n];
        wsT[idx] = f2b(v);
    }
    if (idx < 32 * 128) {
        int n = idx >> 7, k = idx & 127;
        woutrT[idx] = f2b(Wouter[k * 32 + n]);
    }
}

// ---------------------------------------------------------------------------
// Embed GEMM + fused LN + P-GEMM + layer-0 QKV GEMM (LN tile stays in LDS).
// ---------------------------------------------------------------------------
__global__ __launch_bounds__(256) void embed_gemm(
    const float* __restrict__ pos, const float* __restrict__ charge,
    const float* __restrict__ mask, const float* __restrict__ elem,
    const float* __restrict__ chars, const u16* __restrict__ wsT,
    const u16* __restrict__ woutrT, const u16* __restrict__ qkv0T,
    float* __restrict__ X, float* __restrict__ P, u16* __restrict__ QKVb)
{
    __shared__ __align__(16) u16 As[64 * 424];  // staging; then relu+LN tiles
    __shared__ float redS[64][4];
    const int LNOFF = 64 * 136;                 // LN tile offset (u16 units)
    int tid = threadIdx.x;
    int row0 = blockIdx.x * 64;

    #pragma unroll
    for (int it = 0; it < 8; ++it) {
        int idx = tid + it * 256;
        int r = idx >> 5, c4 = idx & 31;
        f32x4v v = *(const f32x4v*)(elem + (size_t)(row0 + r) * 128 + c4 * 4);
        *(us4*)&As[r * 424 + c4 * 4] = pack4(v[0], v[1], v[2], v[3]);
    }
    #pragma unroll
    for (int it = 0; it < 16; ++it) {
        int idx = tid + it * 256;
        int r = idx >> 6, c4 = idx & 63;
        f32x4v v = *(const f32x4v*)(chars + (size_t)(row0 + r) * 256 + c4 * 4);
        *(us4*)&As[r * 424 + 128 + c4 * 4] = pack4(v[0], v[1], v[2], v[3]);
    }
    if (tid < 64) {
        int g = row0 + tid;
        As[tid * 424 + 384] = f2b(pos[g * 3]);
        As[tid * 424 + 385] = f2b(pos[g * 3 + 1]);
        As[tid * 424 + 386] = f2b(pos[g * 3 + 2]);
        As[tid * 424 + 387] = f2b(charge[g]);
        As[tid * 424 + 388] = f2b(mask[g]);
        for (int c = 389; c < 416; ++c) As[tid * 424 + c] = 0;
    }
    __syncthreads();

    int wv = tid >> 6, lane = tid & 63, quad = lane >> 4, l16 = lane & 15;
    int wm = (wv & 1) * 32, wn = (wv >> 1) * 64;
    f32x4v acc[2][4];
    #pragma unroll
    for (int i = 0; i < 2; ++i)
        #pragma unroll
        for (int j = 0; j < 4; ++j) acc[i][j] = (f32x4v){0.f, 0.f, 0.f, 0.f};

    #pragma unroll
    for (int kk = 0; kk < 13; ++kk) {
        short8 a0 = *(short8*)&As[(wm + l16) * 424 + kk * 32 + quad * 8];
        short8 a1 = *(short8*)&As[(wm + 16 + l16) * 424 + kk * 32 + quad * 8];
        #pragma unroll
        for (int nt = 0; nt < 4; ++nt) {
            short8 bw = *(const short8*)&wsT[(size_t)(wn + nt * 16 + l16) * 416 +
                                             kk * 32 + quad * 8];
            acc[0][nt] = __builtin_amdgcn_mfma_f32_16x16x32_bf16(a0, bw, acc[0][nt], 0, 0, 0);
            acc[1][nt] = __builtin_amdgcn_mfma_f32_16x16x32_bf16(a1, bw, acc[1][nt], 0, 0, 0);
        }
    }
    __syncthreads();

    // X write + relu tile + LN partials
    #pragma unroll
    for (int mt = 0; mt < 2; ++mt) {
        #pragma unroll
        for (int r = 0; r < 4; ++r) {
            int lrow = wm + mt * 16 + quad * 4 + r;
            int row = row0 + lrow;
            float s = 0.f, ss = 0.f;
            #pragma unroll
            for (int nt = 0; nt < 4; ++nt) {
                float v = acc[mt][nt][r];
                int col = wn + nt * 16 + l16;
                X[(size_t)row * DS + col] = v;
                As[lrow * 136 + col] = f2b(fmaxf(v, 0.f));
                s += v; ss += v * v;
            }
            #pragma unroll
            for (int o = 1; o < 16; o <<= 1) {
                s  += __shfl_xor(s, o);
                ss += __shfl_xor(ss, o);
            }
            if (l16 == 0) {
                redS[lrow][(wv >> 1) * 2]     = s;
                redS[lrow][(wv >> 1) * 2 + 1] = ss;
            }
        }
    }
    __syncthreads();

    // LN tile -> LDS (no global LNb)
    #pragma unroll
    for (int mt = 0; mt < 2; ++mt)
        #pragma unroll
        for (int r = 0; r < 4; ++r) {
            int lrow = wm + mt * 16 + quad * 4 + r;
            f32x4v rv = *(f32x4v*)&redS[lrow][0];
            float s = rv[0] + rv[2], ss = rv[1] + rv[3];
            float m = s * (1.f / 128.f);
            float var = ss * (1.f / 128.f) - m * m;
            float rs = rsqrtf(var + 1e-5f);
            #pragma unroll
            for (int nt = 0; nt < 4; ++nt) {
                int col = wn + nt * 16 + l16;
                As[LNOFF + lrow * 136 + col] = f2b((acc[mt][nt][r] - m) * rs);
            }
        }

    // P-GEMM from relu tile
    {
        f32x4v pacc[2];
        pacc[0] = (f32x4v){0.f, 0.f, 0.f, 0.f};
        pacc[1] = (f32x4v){0.f, 0.f, 0.f, 0.f};
        #pragma unroll
        for (int ks = 0; ks < 4; ++ks) {
            short8 a = *(short8*)&As[(wv * 16 + l16) * 136 + ks * 32 + quad * 8];
            #pragma unroll
            for (int nt = 0; nt < 2; ++nt) {
                short8 bw = *(const short8*)&woutrT[(size_t)(nt * 16 + l16) * 128 +
                                                    ks * 32 + quad * 8];
                pacc[nt] = __builtin_amdgcn_mfma_f32_16x16x32_bf16(a, bw, pacc[nt], 0, 0, 0);
            }
        }
        #pragma unroll
        for (int nt = 0; nt < 2; ++nt)
            #pragma unroll
            for (int r = 0; r < 4; ++r) {
                int row = row0 + wv * 16 + quad * 4 + r;
                P[(size_t)row * 32 + nt * 16 + l16] = pacc[nt][r];
            }
    }
    __syncthreads();

    // layer-0 QKV GEMM from LN tile: N=384 in 3 chunks of 128
    for (int c = 0; c < 3; ++c) {
        int n0c = c * 128;
        f32x4v qa[2][4];
        #pragma unroll
        for (int i = 0; i < 2; ++i)
            #pragma unroll
            for (int j = 0; j < 4; ++j) qa[i][j] = (f32x4v){0.f, 0.f, 0.f, 0.f};
        #pragma unroll
        for (int ks = 0; ks < 4; ++ks) {
            short8 a0 = *(short8*)&As[LNOFF + (wm + l16) * 136 + ks * 32 + quad * 8];
            short8 a1 = *(short8*)&As[LNOFF + (wm + 16 + l16) * 136 + ks * 32 + quad * 8];
            #pragma unroll
            for (int nt = 0; nt < 4; ++nt) {
                short8 bw = *(const short8*)&qkv0T[(size_t)(n0c + wn + nt * 16 + l16) * 128 +
                                                   ks * 32 + quad * 8];
                qa[0][nt] = __builtin_amdgcn_mfma_f32_16x16x32_bf16(a0, bw, qa[0][nt], 0, 0, 0);
                qa[1][nt] = __builtin_amdgcn_mfma_f32_16x16x32_bf16(a1, bw, qa[1][nt], 0, 0, 0);
            }
        }
        #pragma unroll
        for (int mt = 0; mt < 2; ++mt)
            #pragma unroll
            for (int nt = 0; nt < 4; ++nt)
                #pragma unroll
                for (int r = 0; r < 4; ++r) {
                    int row = row0 + wm + mt * 16 + quad * 4 + r;
                    int col = n0c + wn + nt * 16 + l16;
                    QKVb[(size_t)row * 384 + col] = f2b(qa[mt][nt][r]);
                }
    }
}

// ---------------------------------------------------------------------------
// Bias kernel v7 (unchanged).
// ---------------------------------------------------------------------------
__global__ __launch_bounds__(256) void bias_kernel(
    const float* __restrict__ pos, const int* __restrict__ uid,
    const float* __restrict__ P, const float* __restrict__ Wpair,
    const u16* __restrict__ w1T32, const u16* __restrict__ wcatT,
    u16* __restrict__ BIASb)
{
    __shared__ __align__(16) float posjS[128][4];
    __shared__ __align__(16) u16 lpS[4][16 * 24];
    __shared__ __align__(16) u16 A2S[4][16 * 104];

    int tid = threadIdx.x;
    int b  = blockIdx.x >> 11;
    int w  = (blockIdx.x >> 4) & 127;
    int qg = blockIdx.x & 15;

    if (tid < 128) {
        int r = tid;
        int jk = w * QW + r - PADW;
        bool valid = (jk >= 0) && (jk < N_);
        int gk = b * N_ + jk;
        float x = 0.f, y = 0.f, zz = 0.f; int u = 0;
        if (valid) { x = pos[gk * 3]; y = pos[gk * 3 + 1]; zz = pos[gk * 3 + 2]; u = uid[gk]; }
        posjS[r][0] = x; posjS[r][1] = y; posjS[r][2] = zz;
        ((int*)posjS[r])[3] = u;
    }

    int wv = tid >> 6, lane = tid & 63, quad = lane >> 4, l16 = lane & 15;
    int cl = lane >> 2, cg = lane & 3;
    int q = qg * 4 + wv;
    int gq = b * N_ + w * QW + q;

    float xi = pos[gq * 3], yi = pos[gq * 3 + 1], zi = pos[gq * 3 + 2];
    int ui = uid[gq];
    f32x4v pi4 = *(const f32x4v*)(P + (size_t)gq * 32 + cg * 4);
    f32x4v wp[5];
    #pragma unroll
    for (int f = 0; f < 5; ++f)
        wp[f] = *(const f32x4v*)(Wpair + f * 16 + cg * 4);
    short8 w1f[4], wcat[3];
    #pragma unroll
    for (int nt = 0; nt < 4; ++nt)
        w1f[nt] = *(const short8*)&w1T32[(nt * 16 + l16) * 32 + quad * 8];
    #pragma unroll
    for (int ks = 0; ks < 3; ++ks)
        wcat[ks] = *(const short8*)&wcatT[l16 * 96 + ks * 32 + quad * 8];

    f32x4v pjv[8];
    #pragma unroll
    for (int t = 0; t < 8; ++t) {
        int jk = w * QW + t * 16 + cl - PADW;
        bool valid = (jk >= 0) && (jk < N_);
        int gk = b * N_ + jk;
        f32x4v v = (f32x4v){0.f, 0.f, 0.f, 0.f};
        if (valid) v = *(const f32x4v*)(P + (size_t)gk * 32 + 16 + cg * 4);
        pjv[t] = v;
    }

    *(us4*)&A2S[wv][l16 * 104 + 80 + quad * 4] = (us4){0, 0, 0, 0};
    __syncthreads();

    size_t bbase = ((size_t)(b * NWIN + w) * HEADS) * (QW * KW);
    const short8 zero8 = (short8){0, 0, 0, 0, 0, 0, 0, 0};

    for (int t = 0; t < 8; ++t) {
        int kk1 = t * 16 + cl;
        float xj = posjS[kk1][0], yj = posjS[kk1][1], zj = posjS[kk1][2];
        int uj = ((int*)posjS[kk1])[3];
        float dx = xi - xj, dy = yi - yj, dz = zi - zj;
        float inv = 1.f / (1.f + dx * dx + dy * dy + dz * dz);
        float bf = (ui == uj) ? 1.f : 0.f;
        float pr[4];
        #pragma unroll
        for (int j = 0; j < 4; ++j) {
            float s = fmaf(dx, wp[0][j], fmaf(dy, wp[1][j],
                      fmaf(dz, wp[2][j], fmaf(inv, wp[3][j], wp[4][j]))));
            pr[j] = fmaf(bf, s, pi4[j] + pjv[t][j]);
        }
        float sum = pr[0] + pr[1] + pr[2] + pr[3];
        sum += __shfl_xor(sum, 1); sum += __shfl_xor(sum, 2);
        float m = sum * (1.f / 16.f);
        float d0 = pr[0] - m, d1 = pr[1] - m, d2 = pr[2] - m, d3 = pr[3] - m;
        float vs = d0 * d0 + d1 * d1 + d2 * d2 + d3 * d3;
        vs += __shfl_xor(vs, 1); vs += __shfl_xor(vs, 2);
        float rstd = rsqrtf(vs * (1.f / 16.f) + 1e-5f);
        *(us4*)&lpS[wv][cl * 24 + cg * 4] =
            pack4(d0 * rstd, d1 * rstd, d2 * rstd, d3 * rstd);
        *(us4*)&A2S[wv][cl * 104 + cg * 4] = pack4(pr[0], pr[1], pr[2], pr[3]);

        short8 blp = zero8;
        if (quad < 2) blp = *(short8*)&lpS[wv][l16 * 24 + quad * 8];
        #pragma unroll
        for (int nt = 0; nt < 4; ++nt) {
            f32x4v z4 = (f32x4v){0.f, 0.f, 0.f, 0.f};
            z4 = __builtin_amdgcn_mfma_f32_16x16x32_bf16(w1f[nt], blp, z4, 0, 0, 0);
            *(us4*)&A2S[wv][l16 * 104 + 16 + nt * 16 + quad * 4] =
                pack4(fmaxf(z4[0], 0.f), fmaxf(z4[1], 0.f),
                      fmaxf(z4[2], 0.f), fmaxf(z4[3], 0.f));
        }
        f32x4v acc = (f32x4v){0.f, 0.f, 0.f, 0.f};
        #pragma unroll
        for (int ks = 0; ks < 3; ++ks) {
            short8 a2 = *(short8*)&A2S[wv][l16 * 104 + ks * 32 + quad * 8];
            acc = __builtin_amdgcn_mfma_f32_16x16x32_bf16(a2, wcat[ks], acc, 0, 0, 0);
        }
        if (l16 < 4) {
            *(us4*)&BIASb[bbase + (size_t)l16 * (QW * KW) + q * KW +
                          t * 16 + quad * 4] = pack4(acc[0], acc[1], acc[2], acc[3]);
        }
    }
}

// ---------------------------------------------------------------------------
// wo_ff_fused<LAST>: X += Ob@Wo; LN -> FF1 -> FF2 -> X; then
//   !LAST: QKV(next) = LN(X) @ auxT -> OutB (bf16, N=384)
//   LAST:  TOK = relu(X @ auxT)     -> OutB (bf16, N=384)
// 32-row blocks (512). No LNb in HBM at all.
// ---------------------------------------------------------------------------
template <bool LAST>
__global__ __launch_bounds__(256) void wo_ff_fused(
    const u16* __restrict__ Ob, const u16* __restrict__ woT,
    const u16* __restrict__ w1T, const u16* __restrict__ w2T,
    const u16* __restrict__ auxT, float* __restrict__ X,
    u16* __restrict__ OutB)
{
    __shared__ __align__(16) u16 As[32 * 136];
    __shared__ __align__(16) u16 Hs[32 * 520];
    __shared__ float redS[32][4];
    int tid = threadIdx.x;
    int row0 = blockIdx.x * 32;
    int wv = tid >> 6, lane = tid & 63, quad = lane >> 4, l16 = lane & 15;
    int wm = (wv & 1) * 16, wn = (wv >> 1) * 64;

    // stage Ob
    #pragma unroll
    for (int it = 0; it < 2; ++it) {
        int idx = tid + it * 256;
        int r = idx >> 4, c8 = idx & 15;
        *(short8*)&As[r * 136 + c8 * 8] =
            *(const short8*)&Ob[(size_t)(row0 + r) * 128 + c8 * 8];
    }
    __syncthreads();

    // WO GEMM (K=128)
    f32x4v acc[4];
    #pragma unroll
    for (int j = 0; j < 4; ++j) acc[j] = (f32x4v){0.f, 0.f, 0.f, 0.f};
    #pragma unroll
    for (int ks = 0; ks < 4; ++ks) {
        short8 a = *(short8*)&As[(wm + l16) * 136 + ks * 32 + quad * 8];
        #pragma unroll
        for (int nt = 0; nt < 4; ++nt) {
            short8 b = *(const short8*)&woT[(size_t)(wn + nt * 16 + l16) * 128 +
                                            ks * 32 + quad * 8];
            acc[nt] = __builtin_amdgcn_mfma_f32_16x16x32_bf16(a, b, acc[nt], 0, 0, 0);
        }
    }
    __syncthreads();

    // residual add (X read once) + LN partials
    #pragma unroll
    for (int r = 0; r < 4; ++r) {
        int lrow = wm + quad * 4 + r;
        int row = row0 + lrow;
        float s = 0.f, ss = 0.f;
        #pragma unroll
        for (int nt = 0; nt < 4; ++nt) {
            int col = wn + nt * 16 + l16;
            float v = acc[nt][r] + X[(size_t)row * DS + col];
            acc[nt][r] = v;
            s += v; ss += v * v;
        }
        #pragma unroll
        for (int o2 = 1; o2 < 16; o2 <<= 1) {
            s  += __shfl_xor(s, o2);
            ss += __shfl_xor(ss, o2);
        }
        if (l16 == 0) {
            redS[lrow][(wv >> 1) * 2]     = s;
            redS[lrow][(wv >> 1) * 2 + 1] = ss;
        }
    }
    __syncthreads();

    // LN -> As tile
    #pragma unroll
    for (int r = 0; r < 4; ++r) {
        int lrow = wm + quad * 4 + r;
        f32x4v rv = *(f32x4v*)&redS[lrow][0];
        float s = rv[0] + rv[2], ss = rv[1] + rv[3];
        float m = s * (1.f / 128.f);
        float var = ss * (1.f / 128.f) - m * m;
        float rs = rsqrtf(var + 1e-5f);
        #pragma unroll
        for (int nt = 0; nt < 4; ++nt) {
            int col = wn + nt * 16 + l16;
            As[lrow * 136 + col] = f2b((acc[nt][r] - m) * rs);
        }
    }
    __syncthreads();

    // FF1 (swapped operands): hidden -> Hs
    {
        short8 brow[2][4];
        #pragma unroll
        for (int nt = 0; nt < 2; ++nt)
            #pragma unroll
            for (int ks = 0; ks < 4; ++ks)
                brow[nt][ks] = *(short8*)&As[(nt * 16 + l16) * 136 + ks * 32 + quad * 8];
        #pragma unroll
        for (int mt = 0; mt < 8; ++mt) {
            int j0 = wv * 128 + mt * 16;
            f32x4v c0 = (f32x4v){0.f, 0.f, 0.f, 0.f};
            f32x4v c1 = (f32x4v){0.f, 0.f, 0.f, 0.f};
            #pragma unroll
            for (int ks = 0; ks < 4; ++ks) {
                short8 aw = *(const short8*)&w1T[(size_t)(j0 + l16) * 128 +
                                                 ks * 32 + quad * 8];
                c0 = __builtin_amdgcn_mfma_f32_16x16x32_bf16(aw, brow[0][ks], c0, 0, 0, 0);
                c1 = __builtin_amdgcn_mfma_f32_16x16x32_bf16(aw, brow[1][ks], c1, 0, 0, 0);
            }
            *(us4*)&Hs[l16 * 520 + j0 + quad * 4] =
                pack4(fmaxf(c0[0], 0.f), fmaxf(c0[1], 0.f),
                      fmaxf(c0[2], 0.f), fmaxf(c0[3], 0.f));
            *(us4*)&Hs[(16 + l16) * 520 + j0 + quad * 4] =
                pack4(fmaxf(c1[0], 0.f), fmaxf(c1[1], 0.f),
                      fmaxf(c1[2], 0.f), fmaxf(c1[3], 0.f));
        }
    }
    __syncthreads();

    // FF2 (K=512 from LDS)
    f32x4v acc2[4];
    #pragma unroll
    for (int j = 0; j < 4; ++j) acc2[j] = (f32x4v){0.f, 0.f, 0.f, 0.f};
    #pragma unroll
    for (int ks = 0; ks < 16; ++ks) {
        short8 a = *(short8*)&Hs[(wm + l16) * 520 + ks * 32 + quad * 8];
        #pragma unroll
        for (int nt = 0; nt < 4; ++nt) {
            short8 b = *(const short8*)&w2T[(size_t)(wn + nt * 16 + l16) * 512 +
                                            ks * 32 + quad * 8];
            acc2[nt] = __builtin_amdgcn_mfma_f32_16x16x32_bf16(a, b, acc2[nt], 0, 0, 0);
        }
    }

    // residual + X write + LN partials
    #pragma unroll
    for (int r = 0; r < 4; ++r) {
        int lrow = wm + quad * 4 + r;
        int row = row0 + lrow;
        float s = 0.f, ss = 0.f;
        #pragma unroll
        for (int nt = 0; nt < 4; ++nt) {
            int col = wn + nt * 16 + l16;
            float v = acc2[nt][r] + acc[nt][r];
            acc2[nt][r] = v;
            X[(size_t)row * DS + col] = v;
            s += v; ss += v * v;
        }
        #pragma unroll
        for (int o2 = 1; o2 < 16; o2 <<= 1) {
            s  += __shfl_xor(s, o2);
            ss += __shfl_xor(ss, o2);
        }
        if (l16 == 0) {
            redS[lrow][(wv >> 1) * 2]     = s;
            redS[lrow][(wv >> 1) * 2 + 1] = ss;
        }
    }
    __syncthreads();

    // build input tile for the fused output GEMM
    #pragma unroll
    for (int r = 0; r < 4; ++r) {
        int lrow = wm + quad * 4 + r;
        float m = 0.f, rs = 1.f;
        if (!LAST) {
            f32x4v rv = *(f32x4v*)&redS[lrow][0];
            float s = rv[0] + rv[2], ss = rv[1] + rv[3];
            m = s * (1.f / 128.f);
            float var = ss * (1.f / 128.f) - m * m;
            rs = rsqrtf(var + 1e-5f);
        }
        #pragma unroll
        for (int nt = 0; nt < 4; ++nt) {
            int col = wn + nt * 16 + l16;
            float v = acc2[nt][r];
            As[lrow * 136 + col] = f2b(LAST ? v : (v - m) * rs);
        }
    }
    __syncthreads();

    // fused output GEMM: N=384 in 3 chunks of 128
    for (int c = 0; c < 3; ++c) {
        int n0c = c * 128;
        f32x4v qa[4];
        #pragma unroll
        for (int j = 0; j < 4; ++j) qa[j] = (f32x4v){0.f, 0.f, 0.f, 0.f};
        #pragma unroll
        for (int ks = 0; ks < 4; ++ks) {
            short8 a = *(short8*)&As[(wm + l16) * 136 + ks * 32 + quad * 8];
            #pragma unroll
            for (int nt = 0; nt < 4; ++nt) {
                short8 b = *(const short8*)&auxT[(size_t)(n0c + wn + nt * 16 + l16) * 128 +
                                                 ks * 32 + quad * 8];
                qa[nt] = __builtin_amdgcn_mfma_f32_16x16x32_bf16(a, b, qa[nt], 0, 0, 0);
            }
        }
        #pragma unroll
        for (int nt = 0; nt < 4; ++nt)
            #pragma unroll
            for (int r = 0; r < 4; ++r) {
                int row = row0 + wm + quad * 4 + r;
                int col = n0c + wn + nt * 16 + l16;
                float v = qa[nt][r];
                if (LAST) v = fmaxf(v, 0.f);
                OutB[(size_t)row * 384 + col] = f2b(v);
            }
    }
}

// ---------------------------------------------------------------------------
// Windowed attention v6 (unchanged).
// ---------------------------------------------------------------------------
__global__ __launch_bounds__(256) void attn_kernel(
    const u16* __restrict__ QKV, const u16* __restrict__ BIASb,
    u16* __restrict__ O)
{
    __shared__ __align__(16) u16 sQ[64 * 40];
    __shared__ __align__(16) u16 sK[128 * 40];
    __shared__ __align__(16) u16 sVt[32 * 152];
    __shared__ __align__(16) u16 sP[64 * 136];
    __shared__ float pmax[4][64];
    __shared__ float psum[4][64];
    __shared__ float gfac[4][64];

    int tid = threadIdx.x;
    int h = blockIdx.x & 3, w = (blockIdx.x >> 2) & 127, b = blockIdx.x >> 9;
    size_t rowbase = (size_t)b * N_ + w * QW;
    size_t bbase = ((size_t)(b * NWIN + w) * HEADS + h) * (QW * KW);
    const short8 zero8 = (short8){0, 0, 0, 0, 0, 0, 0, 0};

    {
        int r = tid >> 2, d8 = (tid & 3) * 8;
        *(short8*)&sQ[r * 40 + d8] =
            *(const short8*)&QKV[(rowbase + r) * 384 + h * DH + d8];
    }
    #pragma unroll
    for (int i = 0; i < 2; ++i) {
        int idx = tid + i * 256;
        int r = idx >> 2, d8 = (idx & 3) * 8;
        int jk = w * QW + r - PADW;
        short8 v = zero8;
        if (jk >= 0 && jk < N_)
            v = *(const short8*)&QKV[((size_t)b * N_ + jk) * 384 + 128 + h * DH + d8];
        *(short8*)&sK[r * 40 + d8] = v;
    }
    {
        int kk = tid >> 1, d0 = (tid & 1) * 16;
        int jk = w * QW + kk - PADW;
        short8 v0 = zero8, v1 = zero8;
        if (jk >= 0 && jk < N_) {
            const u16* src = &QKV[((size_t)b * N_ + jk) * 384 + 256 + h * DH + d0];
            v0 = *(const short8*)src;
            v1 = *(const short8*)(src + 8);
        }
        #pragma unroll
        for (int j = 0; j < 8; ++j) {
            sVt[(d0 + j) * 152 + kk] = (u16)v0[j];
            sVt[(d0 + 8 + j) * 152 + kk] = (u16)v1[j];
        }
    }
    #pragma unroll
    for (int i = 0; i < 4; ++i) {
        int idx = tid + i * 256;
        int q = idx >> 4, c8 = idx & 15;
        *(short8*)&sP[q * 136 + c8 * 8] =
            *(const short8*)&BIASb[bbase + (size_t)q * KW + c8 * 8];
    }
    __syncthreads();

    int wv = tid >> 6, lane = tid & 63, quad = lane >> 4, l16 = lane & 15;
    const float scale = 0.17677669529663687f;

    short8 aq[4];
    #pragma unroll
    for (int mt = 0; mt < 4; ++mt)
        aq[mt] = *(short8*)&sQ[(mt * 16 + l16) * 40 + quad * 8];
    float e[2][4][4];
    #pragma unroll
    for (int ni = 0; ni < 2; ++ni) {
        int nt = wv * 2 + ni;
        short8 bk = *(short8*)&sK[(nt * 16 + l16) * 40 + quad * 8];
        int kk = nt * 16 + l16;
        int jk = w * QW + kk - PADW;
        float msk = (jk >= 0 && jk < N_) ? 0.f : -1e9f;
        #pragma unroll
        for (int mt = 0; mt < 4; ++mt) {
            f32x4v acc = (f32x4v){0.f, 0.f, 0.f, 0.f};
            acc = __builtin_amdgcn_mfma_f32_16x16x32_bf16(aq[mt], bk, acc, 0, 0, 0);
            #pragma unroll
            for (int r = 0; r < 4; ++r) {
                int q = mt * 16 + quad * 4 + r;
                e[ni][mt][r] = acc[r] * scale + b2f(sP[q * 136 + kk]) + msk;
            }
        }
    }

    #pragma unroll
    for (int mt = 0; mt < 4; ++mt)
        #pragma unroll
        for (int r = 0; r < 4; ++r) {
            float m = fmaxf(e[0][mt][r], e[1][mt][r]);
            m = fmaxf(m, __shfl_xor(m, 1));
            m = fmaxf(m, __shfl_xor(m, 2));
            m = fmaxf(m, __shfl_xor(m, 4));
            m = fmaxf(m, __shfl_xor(m, 8));
            float e0 = __expf(e[0][mt][r] - m);
            float e1 = __expf(e[1][mt][r] - m);
            e[0][mt][r] = e0; e[1][mt][r] = e1;
            float s = e0 + e1;
            s += __shfl_xor(s, 1);
            s += __shfl_xor(s, 2);
            s += __shfl_xor(s, 4);
            s += __shfl_xor(s, 8);
            if (l16 == 0) {
                int q = mt * 16 + quad * 4 + r;
                pmax[wv][q] = m;
                psum[wv][q] = s;
            }
        }
    __syncthreads();

    if (tid < 64) {
        float m0 = pmax[0][tid], m1 = pmax[1][tid], m2 = pmax[2][tid], m3 = pmax[3][tid];
        float M = fmaxf(fmaxf(m0, m1), fmaxf(m2, m3));
        float g0 = __expf(m0 - M), g1 = __expf(m1 - M),
              g2 = __expf(m2 - M), g3 = __expf(m3 - M);
        float T = psum[0][tid] * g0 + psum[1][tid] * g1 +
                  psum[2][tid] * g2 + psum[3][tid] * g3;
        float inv = 1.f / T;
        gfac[0][tid] = g0 * inv; gfac[1][tid] = g1 * inv;
        gfac[2][tid] = g2 * inv; gfac[3][tid] = g3 * inv;
    }
    __syncthreads();

    #pragma unroll
    for (int mt = 0; mt < 4; ++mt)
        #pragma unroll
        for (int r = 0; r < 4; ++r) {
            int q = mt * 16 + quad * 4 + r;
            float f = gfac[wv][q];
            #pragma unroll
            for (int ni = 0; ni < 2; ++ni) {
                int kk = (wv * 2 + ni) * 16 + l16;
                sP[q * 136 + kk] = f2b(e[ni][mt][r] * f);
            }
        }
    __syncthreads();

    {
        int mt = wv;
        short8 ap[4];
        #pragma unroll
        for (int ks = 0; ks < 4; ++ks)
            ap[ks] = *(short8*)&sP[(mt * 16 + l16) * 136 + ks * 32 + quad * 8];
        #pragma unroll
        for (int nt = 0; nt < 2; ++nt) {
            f32x4v acc = (f32x4v){0.f, 0.f, 0.f, 0.f};
            #pragma unroll
            for (int ks = 0; ks < 4; ++ks) {
                short8 bv = *(short8*)&sVt[(nt * 16 + l16) * 152 + ks * 32 + quad * 8];
                acc = __builtin_amdgcn_mfma_f32_16x16x32_bf16(ap[ks], bv, acc, 0, 0, 0);
            }
            int d = nt * 16 + l16;
            #pragma unroll
            for (int r = 0; r < 4; ++r) {
                int q = mt * 16 + quad * 4 + r;
                O[(rowbase + q) * DS + h * DH + d] = f2b(acc[r]);
            }
        }
    }
}

// ---------------------------------------------------------------------------
// Segment mean (unchanged).
// ---------------------------------------------------------------------------
__global__ __launch_bounds__(128) void seg_kernel(
    const u16* __restrict__ TOKb, const int* __restrict__ idx,
    float* __restrict__ out)
{
    int t = blockIdx.x & (NT - 1);
    int b = blockIdx.x >> 10;
    const int* id = idx + (size_t)b * N_;

    int lo = 0, hi = N_;
    while (lo < hi) { int mid = (lo + hi) >> 1; if (id[mid] < t) lo = mid + 1; else hi = mid; }
    int start = lo;
    hi = N_;
    while (lo < hi) { int mid = (lo + hi) >> 1; if (id[mid] < t + 1) lo = mid + 1; else hi = mid; }
    int end = lo;

    float inv = 1.f / fmaxf((float)(end - start), 1.f);
    for (int c = threadIdx.x; c < DT; c += 128) {
        float s = 0.f;
        for (int r = start; r < end; ++r) s += b2f(TOKb[((size_t)b * N_ + r) * DT + c]);
        out[((size_t)b * NT + t) * DT + c] = s * inv;
    }
}

// ---------------------------------------------------------------------------
extern "C" void kernel_launch(void* const* d_in, const int* in_sizes, int n_in,
                              void* d_out, int out_size, void* d_ws, size_t ws_size,
                              hipStream_t stream)
{
    const float* ref_pos    = (const float*)d_in[0];
    const float* ref_charge = (const float*)d_in[1];
    const float* ref_mask   = (const float*)d_in[2];
    const float* ref_elem   = (const float*)d_in[3];
    const float* ref_chars  = (const float*)d_in[4];
    const float* W_single   = (const float*)d_in[5];
    const float* W_pair     = (const float*)d_in[6];
    const float* W_outer    = (const float*)d_in[7];
    const float* Wp_ff1     = (const float*)d_in[8];
    const float* Wp_ff2     = (const float*)d_in[9];
    const float* Wq         = (const float*)d_in[10];
    const float* Wk         = (const float*)d_in[11];
    const float* Wv         = (const float*)d_in[12];
    const float* Wo         = (const float*)d_in[13];
    const float* Wb         = (const float*)d_in[14];
    const float* Wff1       = (const float*)d_in[15];
    const float* Wff2       = (const float*)d_in[16];
    const float* W_out      = (const float*)d_in[17];
    const int*   uid        = (const int*)d_in[18];
    const int*   a2t        = (const int*)d_in[19];
    float* out = (float*)d_out;

    const size_t ROWS = (size_t)B_ * N_;  // 16384
    float* ws = (float*)d_ws;
    float* X    = ws;
    float* P    = X + ROWS * DS;
    u16* QKVb   = (u16*)(P + ROWS * 32);
    u16* Ob     = QKVb + ROWS * 384;
    u16* FFb    = Ob + ROWS * DS;          // unused (layout stability)
    u16* BIASb  = FFb + ROWS * 512;
    u16* TOKb   = BIASb + (size_t)B_ * NWIN * HEADS * QW * KW;
    u16* LNb    = TOKb + ROWS * DT;        // unused now
    u16* qkvT   = LNb + ROWS * DS;
    u16* woT    = qkvT + 3 * 384 * 128;
    u16* ff1T   = woT + 3 * 128 * 128;
    u16* ff2T   = ff1T + 3 * 512 * 128;
    u16* woutT  = ff2T + 3 * 128 * 512;
    u16* w1T32  = woutT + 384 * 128;
    u16* wcatT  = w1T32 + 64 * 32;
    u16* wsT    = wcatT + 16 * 96;
    u16* woutrT = wsT + 128 * 416;

    convw_kernel<<<768, 256, 0, stream>>>(Wq, Wk, Wv, Wo, Wff1, Wff2, W_out,
                                          Wp_ff1, Wp_ff2, Wb, W_single, W_outer,
                                          qkvT, woT, ff1T, ff2T, woutT,
                                          w1T32, wcatT, wsT, woutrT);
    embed_gemm<<<ROWS / 64, 256, 0, stream>>>(ref_pos, ref_charge, ref_mask,
                                              ref_elem, ref_chars, wsT, woutrT,
                                              qkvT, X, P, QKVb);
    bias_kernel<<<4096, 256, 0, stream>>>(ref_pos, uid, P, W_pair,
                                          w1T32, wcatT, BIASb);

    for (int l = 0; l < DEPTH; ++l) {
        attn_kernel<<<B_ * NWIN * HEADS, 256, 0, stream>>>(QKVb, BIASb, Ob);
        if (l < DEPTH - 1) {
            wo_ff_fused<false><<<ROWS / 32, 256, 0, stream>>>(
                Ob, woT + (size_t)l * 128 * 128,
                ff1T + (size_t)l * 512 * 128, ff2T + (size_t)l * 128 * 512,
                qkvT + (size_t)(l + 1) * 384 * 128, X, QKVb);
        } else {
            wo_ff_fused<true><<<ROWS / 32, 256, 0, stream>>>(
                Ob, woT + (size_t)l * 128 * 128,
                ff1T + (size_t)l * 512 * 128, ff2T + (size_t)l * 128 * 512,
                woutT, X, TOKb);
        }
    }

    seg_kernel<<<B_ * NT, 128, 0, stream>>>(TOKb, a2t, out);
}

// Round 13
// 376.059 us; speedup vs baseline: 1.3269x; 1.0772x over previous
//
#include <hip/hip_runtime.h>
#include <hip/hip_bf16.h>

#define QW 64
#define KW 128
#define PADW 32
#define DEPTH 3
#define HEADS 4
#define B_ 2
#define N_ 8192
#define DS 128
#define DP 16
#define DT 384
#define NT 1024
#define NWIN (N_ / QW)   // 128
#define DH (DS / HEADS)  // 32

typedef unsigned short u16;
typedef __attribute__((ext_vector_type(8))) short short8;
typedef __attribute__((ext_vector_type(4))) float f32x4v;
typedef __attribute__((ext_vector_type(4))) unsigned short us4;

__device__ __forceinline__ u16 f2b(float x) {
    union { float f; unsigned u; } v; v.f = x;
    unsigned r = v.u + 0x7fffu + ((v.u >> 16) & 1u);
    return (u16)(r >> 16);
}
__device__ __forceinline__ float b2f(u16 h) {
    union { unsigned u; float f; } v; v.u = ((unsigned)h) << 16; return v.f;
}
__device__ __forceinline__ unsigned f2b2(float a, float b) {
    __hip_bfloat162 h = __float22bfloat162_rn(make_float2(a, b));
    union { __hip_bfloat162 h; unsigned u; } c; c.h = h; return c.u;
}
__device__ __forceinline__ us4 pack4(float a, float b, float c, float d) {
    union { us4 v; unsigned u[2]; } o;
    o.u[0] = f2b2(a, b);
    o.u[1] = f2b2(c, d);
    return o.v;
}

// ---------------------------------------------------------------------------
// Weight prep (unchanged).
// ---------------------------------------------------------------------------
__global__ __launch_bounds__(256) void convw_kernel(
    const float* __restrict__ Wq, const float* __restrict__ Wk,
    const float* __restrict__ Wv, const float* __restrict__ Wo,
    const float* __restrict__ Wff1, const float* __restrict__ Wff2,
    const float* __restrict__ Wout, const float* __restrict__ Wpff1,
    const float* __restrict__ Wpff2, const float* __restrict__ Wb,
    const float* __restrict__ Wsingle, const float* __restrict__ Wouter,
    u16* __restrict__ qkvT, u16* __restrict__ woT, u16* __restrict__ ff1T,
    u16* __restrict__ ff2T, u16* __restrict__ woutT,
    u16* __restrict__ w1T32, u16* __restrict__ wcatT,
    u16* __restrict__ wsT, u16* __restrict__ woutrT)
{
    int idx = blockIdx.x * 256 + threadIdx.x;
    if (idx < 3 * 384 * 128) {
        int l = idx / (384 * 128), r = idx % (384 * 128);
        int n = r / 128, k = r % 128;
        const float* W = (n < 128) ? Wq : (n < 256) ? Wk : Wv;
        qkvT[idx] = f2b(W[(size_t)l * 16384 + k * 128 + (n & 127)]);
    }
    if (idx < 3 * 128 * 128) {
        int l = idx / 16384, r = idx % 16384;
        int n = r / 128, k = r % 128;
        woT[idx] = f2b(Wo[(size_t)l * 16384 + k * 128 + n]);
    }
    if (idx < 3 * 512 * 128) {
        int l = idx / 65536, r = idx % 65536;
        int n = r / 128, k = r % 128;
        ff1T[idx] = f2b(Wff1[(size_t)l * 65536 + k * 512 + n]);
    }
    if (idx < 3 * 128 * 512) {
        int l = idx / 65536, r = idx % 65536;
        int n = r / 512, k = r % 512;
        ff2T[idx] = f2b(Wff2[(size_t)l * 65536 + k * 128 + n]);
    }
    if (idx < 384 * 128) {
        int n = idx / 128, k = idx % 128;
        woutT[idx] = f2b(Wout[(size_t)k * 384 + n]);
    }
    if (idx < 64 * 32) {
        int n = idx >> 5, k = idx & 31;
        w1T32[idx] = (k < 16) ? f2b(Wpff1[k * 64 + n]) : (u16)0;
    }
    if (idx < 16 * 96) {
        int h = idx / 96, k = idx % 96;
        float s = 0.f;
        if (h < 4) {
            if (k < 16) s = Wb[k * 4 + h];
            else if (k < 80) {
                int j = k - 16;
                for (int c = 0; c < 16; ++c) s += Wpff2[j * 16 + c] * Wb[c * 4 + h];
            }
        }
        wcatT[idx] = f2b(s);
    }
    if (idx < 128 * 416) {
        int n = idx / 416, k = idx % 416;
        float v = 0.f;
        if (k < 128)       v = Wsingle[(5 + k) * 128 + n];
        else if (k < 384)  v = Wsingle[(133 + k - 128) * 128 + n];
        else if (k < 387)  v = Wsingle[(k - 384) * 128 + n];
        else if (k == 387) v = Wsingle[3 * 128 + n];
        else if (k == 388) v = Wsingle[4 * 128 + n];
        wsT[idx] = f2b(v);
    }
    if (idx < 32 * 128) {
        int n = idx >> 7, k = idx & 127;
        woutrT[idx] = f2b(Wouter[k * 32 + n]);
    }
}

// ---------------------------------------------------------------------------
// Embed GEMM + fused LN + P-GEMM + layer-0 QKV GEMM (unchanged from r12).
// ---------------------------------------------------------------------------
__global__ __launch_bounds__(256) void embed_gemm(
    const float* __restrict__ pos, const float* __restrict__ charge,
    const float* __restrict__ mask, const float* __restrict__ elem,
    const float* __restrict__ chars, const u16* __restrict__ wsT,
    const u16* __restrict__ woutrT, const u16* __restrict__ qkv0T,
    float* __restrict__ X, float* __restrict__ P, u16* __restrict__ QKVb)
{
    __shared__ __align__(16) u16 As[64 * 424];
    __shared__ float redS[64][4];
    const int LNOFF = 64 * 136;
    int tid = threadIdx.x;
    int row0 = blockIdx.x * 64;

    #pragma unroll
    for (int it = 0; it < 8; ++it) {
        int idx = tid + it * 256;
        int r = idx >> 5, c4 = idx & 31;
        f32x4v v = *(const f32x4v*)(elem + (size_t)(row0 + r) * 128 + c4 * 4);
        *(us4*)&As[r * 424 + c4 * 4] = pack4(v[0], v[1], v[2], v[3]);
    }
    #pragma unroll
    for (int it = 0; it < 16; ++it) {
        int idx = tid + it * 256;
        int r = idx >> 6, c4 = idx & 63;
        f32x4v v = *(const f32x4v*)(chars + (size_t)(row0 + r) * 256 + c4 * 4);
        *(us4*)&As[r * 424 + 128 + c4 * 4] = pack4(v[0], v[1], v[2], v[3]);
    }
    if (tid < 64) {
        int g = row0 + tid;
        As[tid * 424 + 384] = f2b(pos[g * 3]);
        As[tid * 424 + 385] = f2b(pos[g * 3 + 1]);
        As[tid * 424 + 386] = f2b(pos[g * 3 + 2]);
        As[tid * 424 + 387] = f2b(charge[g]);
        As[tid * 424 + 388] = f2b(mask[g]);
        for (int c = 389; c < 416; ++c) As[tid * 424 + c] = 0;
    }
    __syncthreads();

    int wv = tid >> 6, lane = tid & 63, quad = lane >> 4, l16 = lane & 15;
    int wm = (wv & 1) * 32, wn = (wv >> 1) * 64;
    f32x4v acc[2][4];
    #pragma unroll
    for (int i = 0; i < 2; ++i)
        #pragma unroll
        for (int j = 0; j < 4; ++j) acc[i][j] = (f32x4v){0.f, 0.f, 0.f, 0.f};

    #pragma unroll
    for (int kk = 0; kk < 13; ++kk) {
        short8 a0 = *(short8*)&As[(wm + l16) * 424 + kk * 32 + quad * 8];
        short8 a1 = *(short8*)&As[(wm + 16 + l16) * 424 + kk * 32 + quad * 8];
        #pragma unroll
        for (int nt = 0; nt < 4; ++nt) {
            short8 bw = *(const short8*)&wsT[(size_t)(wn + nt * 16 + l16) * 416 +
                                             kk * 32 + quad * 8];
            acc[0][nt] = __builtin_amdgcn_mfma_f32_16x16x32_bf16(a0, bw, acc[0][nt], 0, 0, 0);
            acc[1][nt] = __builtin_amdgcn_mfma_f32_16x16x32_bf16(a1, bw, acc[1][nt], 0, 0, 0);
        }
    }
    __syncthreads();

    #pragma unroll
    for (int mt = 0; mt < 2; ++mt) {
        #pragma unroll
        for (int r = 0; r < 4; ++r) {
            int lrow = wm + mt * 16 + quad * 4 + r;
            int row = row0 + lrow;
            float s = 0.f, ss = 0.f;
            #pragma unroll
            for (int nt = 0; nt < 4; ++nt) {
                float v = acc[mt][nt][r];
                int col = wn + nt * 16 + l16;
                X[(size_t)row * DS + col] = v;
                As[lrow * 136 + col] = f2b(fmaxf(v, 0.f));
                s += v; ss += v * v;
            }
            #pragma unroll
            for (int o = 1; o < 16; o <<= 1) {
                s  += __shfl_xor(s, o);
                ss += __shfl_xor(ss, o);
            }
            if (l16 == 0) {
                redS[lrow][(wv >> 1) * 2]     = s;
                redS[lrow][(wv >> 1) * 2 + 1] = ss;
            }
        }
    }
    __syncthreads();

    #pragma unroll
    for (int mt = 0; mt < 2; ++mt)
        #pragma unroll
        for (int r = 0; r < 4; ++r) {
            int lrow = wm + mt * 16 + quad * 4 + r;
            f32x4v rv = *(f32x4v*)&redS[lrow][0];
            float s = rv[0] + rv[2], ss = rv[1] + rv[3];
            float m = s * (1.f / 128.f);
            float var = ss * (1.f / 128.f) - m * m;
            float rs = rsqrtf(var + 1e-5f);
            #pragma unroll
            for (int nt = 0; nt < 4; ++nt) {
                int col = wn + nt * 16 + l16;
                As[LNOFF + lrow * 136 + col] = f2b((acc[mt][nt][r] - m) * rs);
            }
        }

    {
        f32x4v pacc[2];
        pacc[0] = (f32x4v){0.f, 0.f, 0.f, 0.f};
        pacc[1] = (f32x4v){0.f, 0.f, 0.f, 0.f};
        #pragma unroll
        for (int ks = 0; ks < 4; ++ks) {
            short8 a = *(short8*)&As[(wv * 16 + l16) * 136 + ks * 32 + quad * 8];
            #pragma unroll
            for (int nt = 0; nt < 2; ++nt) {
                short8 bw = *(const short8*)&woutrT[(size_t)(nt * 16 + l16) * 128 +
                                                    ks * 32 + quad * 8];
                pacc[nt] = __builtin_amdgcn_mfma_f32_16x16x32_bf16(a, bw, pacc[nt], 0, 0, 0);
            }
        }
        #pragma unroll
        for (int nt = 0; nt < 2; ++nt)
            #pragma unroll
            for (int r = 0; r < 4; ++r) {
                int row = row0 + wv * 16 + quad * 4 + r;
                P[(size_t)row * 32 + nt * 16 + l16] = pacc[nt][r];
            }
    }
    __syncthreads();

    for (int c = 0; c < 3; ++c) {
        int n0c = c * 128;
        f32x4v qa[2][4];
        #pragma unroll
        for (int i = 0; i < 2; ++i)
            #pragma unroll
            for (int j = 0; j < 4; ++j) qa[i][j] = (f32x4v){0.f, 0.f, 0.f, 0.f};
        #pragma unroll
        for (int ks = 0; ks < 4; ++ks) {
            short8 a0 = *(short8*)&As[LNOFF + (wm + l16) * 136 + ks * 32 + quad * 8];
            short8 a1 = *(short8*)&As[LNOFF + (wm + 16 + l16) * 136 + ks * 32 + quad * 8];
            #pragma unroll
            for (int nt = 0; nt < 4; ++nt) {
                short8 bw = *(const short8*)&qkv0T[(size_t)(n0c + wn + nt * 16 + l16) * 128 +
                                                   ks * 32 + quad * 8];
                qa[0][nt] = __builtin_amdgcn_mfma_f32_16x16x32_bf16(a0, bw, qa[0][nt], 0, 0, 0);
                qa[1][nt] = __builtin_amdgcn_mfma_f32_16x16x32_bf16(a1, bw, qa[1][nt], 0, 0, 0);
            }
        }
        #pragma unroll
        for (int mt = 0; mt < 2; ++mt)
            #pragma unroll
            for (int nt = 0; nt < 4; ++nt)
                #pragma unroll
                for (int r = 0; r < 4; ++r) {
                    int row = row0 + wm + mt * 16 + quad * 4 + r;
                    int col = n0c + wn + nt * 16 + l16;
                    QKVb[(size_t)row * 384 + col] = f2b(qa[mt][nt][r]);
                }
    }
}

// ---------------------------------------------------------------------------
// Bias kernel v7 (unchanged).
// ---------------------------------------------------------------------------
__global__ __launch_bounds__(256) void bias_kernel(
    const float* __restrict__ pos, const int* __restrict__ uid,
    const float* __restrict__ P, const float* __restrict__ Wpair,
    const u16* __restrict__ w1T32, const u16* __restrict__ wcatT,
    u16* __restrict__ BIASb)
{
    __shared__ __align__(16) float posjS[128][4];
    __shared__ __align__(16) u16 lpS[4][16 * 24];
    __shared__ __align__(16) u16 A2S[4][16 * 104];

    int tid = threadIdx.x;
    int b  = blockIdx.x >> 11;
    int w  = (blockIdx.x >> 4) & 127;
    int qg = blockIdx.x & 15;

    if (tid < 128) {
        int r = tid;
        int jk = w * QW + r - PADW;
        bool valid = (jk >= 0) && (jk < N_);
        int gk = b * N_ + jk;
        float x = 0.f, y = 0.f, zz = 0.f; int u = 0;
        if (valid) { x = pos[gk * 3]; y = pos[gk * 3 + 1]; zz = pos[gk * 3 + 2]; u = uid[gk]; }
        posjS[r][0] = x; posjS[r][1] = y; posjS[r][2] = zz;
        ((int*)posjS[r])[3] = u;
    }

    int wv = tid >> 6, lane = tid & 63, quad = lane >> 4, l16 = lane & 15;
    int cl = lane >> 2, cg = lane & 3;
    int q = qg * 4 + wv;
    int gq = b * N_ + w * QW + q;

    float xi = pos[gq * 3], yi = pos[gq * 3 + 1], zi = pos[gq * 3 + 2];
    int ui = uid[gq];
    f32x4v pi4 = *(const f32x4v*)(P + (size_t)gq * 32 + cg * 4);
    f32x4v wp[5];
    #pragma unroll
    for (int f = 0; f < 5; ++f)
        wp[f] = *(const f32x4v*)(Wpair + f * 16 + cg * 4);
    short8 w1f[4], wcat[3];
    #pragma unroll
    for (int nt = 0; nt < 4; ++nt)
        w1f[nt] = *(const short8*)&w1T32[(nt * 16 + l16) * 32 + quad * 8];
    #pragma unroll
    for (int ks = 0; ks < 3; ++ks)
        wcat[ks] = *(const short8*)&wcatT[l16 * 96 + ks * 32 + quad * 8];

    f32x4v pjv[8];
    #pragma unroll
    for (int t = 0; t < 8; ++t) {
        int jk = w * QW + t * 16 + cl - PADW;
        bool valid = (jk >= 0) && (jk < N_);
        int gk = b * N_ + jk;
        f32x4v v = (f32x4v){0.f, 0.f, 0.f, 0.f};
        if (valid) v = *(const f32x4v*)(P + (size_t)gk * 32 + 16 + cg * 4);
        pjv[t] = v;
    }

    *(us4*)&A2S[wv][l16 * 104 + 80 + quad * 4] = (us4){0, 0, 0, 0};
    __syncthreads();

    size_t bbase = ((size_t)(b * NWIN + w) * HEADS) * (QW * KW);
    const short8 zero8 = (short8){0, 0, 0, 0, 0, 0, 0, 0};

    for (int t = 0; t < 8; ++t) {
        int kk1 = t * 16 + cl;
        float xj = posjS[kk1][0], yj = posjS[kk1][1], zj = posjS[kk1][2];
        int uj = ((int*)posjS[kk1])[3];
        float dx = xi - xj, dy = yi - yj, dz = zi - zj;
        float inv = 1.f / (1.f + dx * dx + dy * dy + dz * dz);
        float bf = (ui == uj) ? 1.f : 0.f;
        float pr[4];
        #pragma unroll
        for (int j = 0; j < 4; ++j) {
            float s = fmaf(dx, wp[0][j], fmaf(dy, wp[1][j],
                      fmaf(dz, wp[2][j], fmaf(inv, wp[3][j], wp[4][j]))));
            pr[j] = fmaf(bf, s, pi4[j] + pjv[t][j]);
        }
        float sum = pr[0] + pr[1] + pr[2] + pr[3];
        sum += __shfl_xor(sum, 1); sum += __shfl_xor(sum, 2);
        float m = sum * (1.f / 16.f);
        float d0 = pr[0] - m, d1 = pr[1] - m, d2 = pr[2] - m, d3 = pr[3] - m;
        float vs = d0 * d0 + d1 * d1 + d2 * d2 + d3 * d3;
        vs += __shfl_xor(vs, 1); vs += __shfl_xor(vs, 2);
        float rstd = rsqrtf(vs * (1.f / 16.f) + 1e-5f);
        *(us4*)&lpS[wv][cl * 24 + cg * 4] =
            pack4(d0 * rstd, d1 * rstd, d2 * rstd, d3 * rstd);
        *(us4*)&A2S[wv][cl * 104 + cg * 4] = pack4(pr[0], pr[1], pr[2], pr[3]);

        short8 blp = zero8;
        if (quad < 2) blp = *(short8*)&lpS[wv][l16 * 24 + quad * 8];
        #pragma unroll
        for (int nt = 0; nt < 4; ++nt) {
            f32x4v z4 = (f32x4v){0.f, 0.f, 0.f, 0.f};
            z4 = __builtin_amdgcn_mfma_f32_16x16x32_bf16(w1f[nt], blp, z4, 0, 0, 0);
            *(us4*)&A2S[wv][l16 * 104 + 16 + nt * 16 + quad * 4] =
                pack4(fmaxf(z4[0], 0.f), fmaxf(z4[1], 0.f),
                      fmaxf(z4[2], 0.f), fmaxf(z4[3], 0.f));
        }
        f32x4v acc = (f32x4v){0.f, 0.f, 0.f, 0.f};
        #pragma unroll
        for (int ks = 0; ks < 3; ++ks) {
            short8 a2 = *(short8*)&A2S[wv][l16 * 104 + ks * 32 + quad * 8];
            acc = __builtin_amdgcn_mfma_f32_16x16x32_bf16(a2, wcat[ks], acc, 0, 0, 0);
        }
        if (l16 < 4) {
            *(us4*)&BIASb[bbase + (size_t)l16 * (QW * KW) + q * KW +
                          t * 16 + quad * 4] = pack4(acc[0], acc[1], acc[2], acc[3]);
        }
    }
}

// ---------------------------------------------------------------------------
// wo_ff_fused<LAST> (unchanged from r12).
// ---------------------------------------------------------------------------
template <bool LAST>
__global__ __launch_bounds__(256) void wo_ff_fused(
    const u16* __restrict__ Ob, const u16* __restrict__ woT,
    const u16* __restrict__ w1T, const u16* __restrict__ w2T,
    const u16* __restrict__ auxT, float* __restrict__ X,
    u16* __restrict__ OutB)
{
    __shared__ __align__(16) u16 As[32 * 136];
    __shared__ __align__(16) u16 Hs[32 * 520];
    __shared__ float redS[32][4];
    int tid = threadIdx.x;
    int row0 = blockIdx.x * 32;
    int wv = tid >> 6, lane = tid & 63, quad = lane >> 4, l16 = lane & 15;
    int wm = (wv & 1) * 16, wn = (wv >> 1) * 64;

    #pragma unroll
    for (int it = 0; it < 2; ++it) {
        int idx = tid + it * 256;
        int r = idx >> 4, c8 = idx & 15;
        *(short8*)&As[r * 136 + c8 * 8] =
            *(const short8*)&Ob[(size_t)(row0 + r) * 128 + c8 * 8];
    }
    __syncthreads();

    f32x4v acc[4];
    #pragma unroll
    for (int j = 0; j < 4; ++j) acc[j] = (f32x4v){0.f, 0.f, 0.f, 0.f};
    #pragma unroll
    for (int ks = 0; ks < 4; ++ks) {
        short8 a = *(short8*)&As[(wm + l16) * 136 + ks * 32 + quad * 8];
        #pragma unroll
        for (int nt = 0; nt < 4; ++nt) {
            short8 b = *(const short8*)&woT[(size_t)(wn + nt * 16 + l16) * 128 +
                                            ks * 32 + quad * 8];
            acc[nt] = __builtin_amdgcn_mfma_f32_16x16x32_bf16(a, b, acc[nt], 0, 0, 0);
        }
    }
    __syncthreads();

    #pragma unroll
    for (int r = 0; r < 4; ++r) {
        int lrow = wm + quad * 4 + r;
        int row = row0 + lrow;
        float s = 0.f, ss = 0.f;
        #pragma unroll
        for (int nt = 0; nt < 4; ++nt) {
            int col = wn + nt * 16 + l16;
            float v = acc[nt][r] + X[(size_t)row * DS + col];
            acc[nt][r] = v;
            s += v; ss += v * v;
        }
        #pragma unroll
        for (int o2 = 1; o2 < 16; o2 <<= 1) {
            s  += __shfl_xor(s, o2);
            ss += __shfl_xor(ss, o2);
        }
        if (l16 == 0) {
            redS[lrow][(wv >> 1) * 2]     = s;
            redS[lrow][(wv >> 1) * 2 + 1] = ss;
        }
    }
    __syncthreads();

    #pragma unroll
    for (int r = 0; r < 4; ++r) {
        int lrow = wm + quad * 4 + r;
        f32x4v rv = *(f32x4v*)&redS[lrow][0];
        float s = rv[0] + rv[2], ss = rv[1] + rv[3];
        float m = s * (1.f / 128.f);
        float var = ss * (1.f / 128.f) - m * m;
        float rs = rsqrtf(var + 1e-5f);
        #pragma unroll
        for (int nt = 0; nt < 4; ++nt) {
            int col = wn + nt * 16 + l16;
            As[lrow * 136 + col] = f2b((acc[nt][r] - m) * rs);
        }
    }
    __syncthreads();

    {
        short8 brow[2][4];
        #pragma unroll
        for (int nt = 0; nt < 2; ++nt)
            #pragma unroll
            for (int ks = 0; ks < 4; ++ks)
                brow[nt][ks] = *(short8*)&As[(nt * 16 + l16) * 136 + ks * 32 + quad * 8];
        #pragma unroll
        for (int mt = 0; mt < 8; ++mt) {
            int j0 = wv * 128 + mt * 16;
            f32x4v c0 = (f32x4v){0.f, 0.f, 0.f, 0.f};
            f32x4v c1 = (f32x4v){0.f, 0.f, 0.f, 0.f};
            #pragma unroll
            for (int ks = 0; ks < 4; ++ks) {
                short8 aw = *(const short8*)&w1T[(size_t)(j0 + l16) * 128 +
                                                 ks * 32 + quad * 8];
                c0 = __builtin_amdgcn_mfma_f32_16x16x32_bf16(aw, brow[0][ks], c0, 0, 0, 0);
                c1 = __builtin_amdgcn_mfma_f32_16x16x32_bf16(aw, brow[1][ks], c1, 0, 0, 0);
            }
            *(us4*)&Hs[l16 * 520 + j0 + quad * 4] =
                pack4(fmaxf(c0[0], 0.f), fmaxf(c0[1], 0.f),
                      fmaxf(c0[2], 0.f), fmaxf(c0[3], 0.f));
            *(us4*)&Hs[(16 + l16) * 520 + j0 + quad * 4] =
                pack4(fmaxf(c1[0], 0.f), fmaxf(c1[1], 0.f),
                      fmaxf(c1[2], 0.f), fmaxf(c1[3], 0.f));
        }
    }
    __syncthreads();

    f32x4v acc2[4];
    #pragma unroll
    for (int j = 0; j < 4; ++j) acc2[j] = (f32x4v){0.f, 0.f, 0.f, 0.f};
    #pragma unroll
    for (int ks = 0; ks < 16; ++ks) {
        short8 a = *(short8*)&Hs[(wm + l16) * 520 + ks * 32 + quad * 8];
        #pragma unroll
        for (int nt = 0; nt < 4; ++nt) {
            short8 b = *(const short8*)&w2T[(size_t)(wn + nt * 16 + l16) * 512 +
                                            ks * 32 + quad * 8];
            acc2[nt] = __builtin_amdgcn_mfma_f32_16x16x32_bf16(a, b, acc2[nt], 0, 0, 0);
        }
    }

    #pragma unroll
    for (int r = 0; r < 4; ++r) {
        int lrow = wm + quad * 4 + r;
        int row = row0 + lrow;
        float s = 0.f, ss = 0.f;
        #pragma unroll
        for (int nt = 0; nt < 4; ++nt) {
            int col = wn + nt * 16 + l16;
            float v = acc2[nt][r] + acc[nt][r];
            acc2[nt][r] = v;
            X[(size_t)row * DS + col] = v;
            s += v; ss += v * v;
        }
        #pragma unroll
        for (int o2 = 1; o2 < 16; o2 <<= 1) {
            s  += __shfl_xor(s, o2);
            ss += __shfl_xor(ss, o2);
        }
        if (l16 == 0) {
            redS[lrow][(wv >> 1) * 2]     = s;
            redS[lrow][(wv >> 1) * 2 + 1] = ss;
        }
    }
    __syncthreads();

    #pragma unroll
    for (int r = 0; r < 4; ++r) {
        int lrow = wm + quad * 4 + r;
        float m = 0.f, rs = 1.f;
        if (!LAST) {
            f32x4v rv = *(f32x4v*)&redS[lrow][0];
            float s = rv[0] + rv[2], ss = rv[1] + rv[3];
            m = s * (1.f / 128.f);
            float var = ss * (1.f / 128.f) - m * m;
            rs = rsqrtf(var + 1e-5f);
        }
        #pragma unroll
        for (int nt = 0; nt < 4; ++nt) {
            int col = wn + nt * 16 + l16;
            float v = acc2[nt][r];
            As[lrow * 136 + col] = f2b(LAST ? v : (v - m) * rs);
        }
    }
    __syncthreads();

    for (int c = 0; c < 3; ++c) {
        int n0c = c * 128;
        f32x4v qa[4];
        #pragma unroll
        for (int j = 0; j < 4; ++j) qa[j] = (f32x4v){0.f, 0.f, 0.f, 0.f};
        #pragma unroll
        for (int ks = 0; ks < 4; ++ks) {
            short8 a = *(short8*)&As[(wm + l16) * 136 + ks * 32 + quad * 8];
            #pragma unroll
            for (int nt = 0; nt < 4; ++nt) {
                short8 b = *(const short8*)&auxT[(size_t)(n0c + wn + nt * 16 + l16) * 128 +
                                                 ks * 32 + quad * 8];
                qa[nt] = __builtin_amdgcn_mfma_f32_16x16x32_bf16(a, b, qa[nt], 0, 0, 0);
            }
        }
        #pragma unroll
        for (int nt = 0; nt < 4; ++nt)
            #pragma unroll
            for (int r = 0; r < 4; ++r) {
                int row = row0 + wm + quad * 4 + r;
                int col = n0c + wn + nt * 16 + l16;
                float v = qa[nt][r];
                if (LAST) v = fmaxf(v, 0.f);
                OutB[(size_t)row * 384 + col] = f2b(v);
            }
    }
}

// ---------------------------------------------------------------------------
// Windowed attention v7: wave-autonomous softmax, ONE barrier.
// Wave wv owns q rows [wv*16, wv*16+16) x full KW=128.
// ---------------------------------------------------------------------------
__global__ __launch_bounds__(256) void attn_kernel(
    const u16* __restrict__ QKV, const u16* __restrict__ BIASb,
    u16* __restrict__ O)
{
    __shared__ __align__(16) u16 sQ[64 * 40];    // 5 KB
    __shared__ __align__(16) u16 sK[128 * 40];   // 10 KB
    __shared__ __align__(16) u16 sVt[32 * 152];  // 9.5 KB
    __shared__ __align__(16) u16 sP[64 * 136];   // bias tile, then P (17 KB)

    int tid = threadIdx.x;
    int h = blockIdx.x & 3, w = (blockIdx.x >> 2) & 127, b = blockIdx.x >> 9;
    size_t rowbase = (size_t)b * N_ + w * QW;
    size_t bbase = ((size_t)(b * NWIN + w) * HEADS + h) * (QW * KW);
    const short8 zero8 = (short8){0, 0, 0, 0, 0, 0, 0, 0};

    {   // Q
        int r = tid >> 2, d8 = (tid & 3) * 8;
        *(short8*)&sQ[r * 40 + d8] =
            *(const short8*)&QKV[(rowbase + r) * 384 + h * DH + d8];
    }
    #pragma unroll
    for (int i = 0; i < 2; ++i) {  // K
        int idx = tid + i * 256;
        int r = idx >> 2, d8 = (idx & 3) * 8;
        int jk = w * QW + r - PADW;
        short8 v = zero8;
        if (jk >= 0 && jk < N_)
            v = *(const short8*)&QKV[((size_t)b * N_ + jk) * 384 + 128 + h * DH + d8];
        *(short8*)&sK[r * 40 + d8] = v;
    }
    {   // V transposed
        int kk = tid >> 1, d0 = (tid & 1) * 16;
        int jk = w * QW + kk - PADW;
        short8 v0 = zero8, v1 = zero8;
        if (jk >= 0 && jk < N_) {
            const u16* src = &QKV[((size_t)b * N_ + jk) * 384 + 256 + h * DH + d0];
            v0 = *(const short8*)src;
            v1 = *(const short8*)(src + 8);
        }
        #pragma unroll
        for (int j = 0; j < 8; ++j) {
            sVt[(d0 + j) * 152 + kk] = (u16)v0[j];
            sVt[(d0 + 8 + j) * 152 + kk] = (u16)v1[j];
        }
    }
    #pragma unroll
    for (int i = 0; i < 4; ++i) {  // bias tile -> sP
        int idx = tid + i * 256;
        int q = idx >> 4, c8 = idx & 15;
        *(short8*)&sP[q * 136 + c8 * 8] =
            *(const short8*)&BIASb[bbase + (size_t)q * KW + c8 * 8];
    }
    __syncthreads();  // the ONLY barrier

    int wv = tid >> 6, lane = tid & 63, quad = lane >> 4, l16 = lane & 15;
    const float scale = 0.17677669529663687f;  // 1/sqrt(32)

    // ---- QK^T: wave's 16 q rows x full 128 kk ----
    short8 aq = *(short8*)&sQ[(wv * 16 + l16) * 40 + quad * 8];
    float e[8][4];
    #pragma unroll
    for (int nt = 0; nt < 8; ++nt) {
        short8 bk = *(short8*)&sK[(nt * 16 + l16) * 40 + quad * 8];
        f32x4v acc = (f32x4v){0.f, 0.f, 0.f, 0.f};
        acc = __builtin_amdgcn_mfma_f32_16x16x32_bf16(aq, bk, acc, 0, 0, 0);
        int kk = nt * 16 + l16;
        int jk = w * QW + kk - PADW;
        float msk = (jk >= 0 && jk < N_) ? 0.f : -1e9f;
        #pragma unroll
        for (int r = 0; r < 4; ++r) {
            int q = wv * 16 + quad * 4 + r;
            e[nt][r] = acc[r] * scale + b2f(sP[q * 136 + kk]) + msk;
        }
    }

    // ---- softmax fully within the wave ----
    #pragma unroll
    for (int r = 0; r < 4; ++r) {
        float m = e[0][r];
        #pragma unroll
        for (int nt = 1; nt < 8; ++nt) m = fmaxf(m, e[nt][r]);
        m = fmaxf(m, __shfl_xor(m, 1));
        m = fmaxf(m, __shfl_xor(m, 2));
        m = fmaxf(m, __shfl_xor(m, 4));
        m = fmaxf(m, __shfl_xor(m, 8));
        float s = 0.f;
        #pragma unroll
        for (int nt = 0; nt < 8; ++nt) {
            float ev = __expf(e[nt][r] - m);
            e[nt][r] = ev;
            s += ev;
        }
        s += __shfl_xor(s, 1);
        s += __shfl_xor(s, 2);
        s += __shfl_xor(s, 4);
        s += __shfl_xor(s, 8);
        float inv = 1.f / s;
        #pragma unroll
        for (int nt = 0; nt < 8; ++nt) e[nt][r] *= inv;
    }

    // ---- write P into the wave's OWN sP rows (in-wave ordering only) ----
    #pragma unroll
    for (int nt = 0; nt < 8; ++nt) {
        int kk = nt * 16 + l16;
        #pragma unroll
        for (int r = 0; r < 4; ++r) {
            int q = wv * 16 + quad * 4 + r;
            sP[q * 136 + kk] = f2b(e[nt][r]);
        }
    }

    // ---- P @ V (reads the wave's own rows; lgkmcnt-ordered, no barrier) ----
    short8 ap[4];
    #pragma unroll
    for (int ks = 0; ks < 4; ++ks)
        ap[ks] = *(short8*)&sP[(wv * 16 + l16) * 136 + ks * 32 + quad * 8];
    #pragma unroll
    for (int nt = 0; nt < 2; ++nt) {
        f32x4v acc = (f32x4v){0.f, 0.f, 0.f, 0.f};
        #pragma unroll
        for (int ks = 0; ks < 4; ++ks) {
            short8 bv = *(short8*)&sVt[(nt * 16 + l16) * 152 + ks * 32 + quad * 8];
            acc = __builtin_amdgcn_mfma_f32_16x16x32_bf16(ap[ks], bv, acc, 0, 0, 0);
        }
        int d = nt * 16 + l16;
        #pragma unroll
        for (int r = 0; r < 4; ++r) {
            int q = wv * 16 + quad * 4 + r;
            O[(rowbase + q) * DS + h * DH + d] = f2b(acc[r]);
        }
    }
}

// ---------------------------------------------------------------------------
// Segment mean (unchanged).
// ---------------------------------------------------------------------------
__global__ __launch_bounds__(128) void seg_kernel(
    const u16* __restrict__ TOKb, const int* __restrict__ idx,
    float* __restrict__ out)
{
    int t = blockIdx.x & (NT - 1);
    int b = blockIdx.x >> 10;
    const int* id = idx + (size_t)b * N_;

    int lo = 0, hi = N_;
    while (lo < hi) { int mid = (lo + hi) >> 1; if (id[mid] < t) lo = mid + 1; else hi = mid; }
    int start = lo;
    hi = N_;
    while (lo < hi) { int mid = (lo + hi) >> 1; if (id[mid] < t + 1) lo = mid + 1; else hi = mid; }
    int end = lo;

    float inv = 1.f / fmaxf((float)(end - start), 1.f);
    for (int c = threadIdx.x; c < DT; c += 128) {
        float s = 0.f;
        for (int r = start; r < end; ++r) s += b2f(TOKb[((size_t)b * N_ + r) * DT + c]);
        out[((size_t)b * NT + t) * DT + c] = s * inv;
    }
}

// ---------------------------------------------------------------------------
extern "C" void kernel_launch(void* const* d_in, const int* in_sizes, int n_in,
                              void* d_out, int out_size, void* d_ws, size_t ws_size,
                              hipStream_t stream)
{
    const float* ref_pos    = (const float*)d_in[0];
    const float* ref_charge = (const float*)d_in[1];
    const float* ref_mask   = (const float*)d_in[2];
    const float* ref_elem   = (const float*)d_in[3];
    const float* ref_chars  = (const float*)d_in[4];
    const float* W_single   = (const float*)d_in[5];
    const float* W_pair     = (const float*)d_in[6];
    const float* W_outer    = (const float*)d_in[7];
    const float* Wp_ff1     = (const float*)d_in[8];
    const float* Wp_ff2     = (const float*)d_in[9];
    const float* Wq         = (const float*)d_in[10];
    const float* Wk         = (const float*)d_in[11];
    const float* Wv         = (const float*)d_in[12];
    const float* Wo         = (const float*)d_in[13];
    const float* Wb         = (const float*)d_in[14];
    const float* Wff1       = (const float*)d_in[15];
    const float* Wff2       = (const float*)d_in[16];
    const float* W_out      = (const float*)d_in[17];
    const int*   uid        = (const int*)d_in[18];
    const int*   a2t        = (const int*)d_in[19];
    float* out = (float*)d_out;

    const size_t ROWS = (size_t)B_ * N_;  // 16384
    float* ws = (float*)d_ws;
    float* X    = ws;
    float* P    = X + ROWS * DS;
    u16* QKVb   = (u16*)(P + ROWS * 32);
    u16* Ob     = QKVb + ROWS * 384;
    u16* FFb    = Ob + ROWS * DS;          // unused (layout stability)
    u16* BIASb  = FFb + ROWS * 512;
    u16* TOKb   = BIASb + (size_t)B_ * NWIN * HEADS * QW * KW;
    u16* LNb    = TOKb + ROWS * DT;        // unused
    u16* qkvT   = LNb + ROWS * DS;
    u16* woT    = qkvT + 3 * 384 * 128;
    u16* ff1T   = woT + 3 * 128 * 128;
    u16* ff2T   = ff1T + 3 * 512 * 128;
    u16* woutT  = ff2T + 3 * 128 * 512;
    u16* w1T32  = woutT + 384 * 128;
    u16* wcatT  = w1T32 + 64 * 32;
    u16* wsT    = wcatT + 16 * 96;
    u16* woutrT = wsT + 128 * 416;

    convw_kernel<<<768, 256, 0, stream>>>(Wq, Wk, Wv, Wo, Wff1, Wff2, W_out,
                                          Wp_ff1, Wp_ff2, Wb, W_single, W_outer,
                                          qkvT, woT, ff1T, ff2T, woutT,
                                          w1T32, wcatT, wsT, woutrT);
    embed_gemm<<<ROWS / 64, 256, 0, stream>>>(ref_pos, ref_charge, ref_mask,
                                              ref_elem, ref_chars, wsT, woutrT,
                                              qkvT, X, P, QKVb);
    bias_kernel<<<4096, 256, 0, stream>>>(ref_pos, uid, P, W_pair,
                                          w1T32, wcatT, BIASb);

    for (int l = 0; l < DEPTH; ++l) {
        attn_kernel<<<B_ * NWIN * HEADS, 256, 0, stream>>>(QKVb, BIASb, Ob);
        if (l < DEPTH - 1) {
            wo_ff_fused<false><<<ROWS / 32, 256, 0, stream>>>(
                Ob, woT + (size_t)l * 128 * 128,
                ff1T + (size_t)l * 512 * 128, ff2T + (size_t)l * 128 * 512,
                qkvT + (size_t)(l + 1) * 384 * 128, X, QKVb);
        } else {
            wo_ff_fused<true><<<ROWS / 32, 256, 0, stream>>>(
                Ob, woT + (size_t)l * 128 * 128,
                ff1T + (size_t)l * 512 * 128, ff2T + (size_t)l * 128 * 512,
                woutT, X, TOKb);
        }
    }

    seg_kernel<<<B_ * NT, 128, 0, stream>>>(TOKb, a2t, out);
}